// Round 9
// baseline (153.936 us; speedup 1.0000x reference)
//
#include <hip/hip_runtime.h>

// GCN forward: two GCNConv layers + linear head.
// Round 9: round-6 split GEMMs (fusion regressed twice; settled). CSR build
// reduced to 3 kernels: chunk-major hist; bucket/csr self-compute totals +
// prefixes from the hist matrix (no scan kernel, no bucketTot). agg1 unroll 16.
// 7 dispatches:
//   k_hist -> k_bucket -> k_csr(+dinv+prescale) ->
//   k_agg1 -> k_gemm1 -> k_gemm2 -> k_agg2h
// out = dinv[d] * sum_{s in N(d)+self} (dinv[s]*h[s]) per layer.
// Layer1 aggregates BEFORE GEMM (64 feats), layer2 AFTER its GEMM (32 feats).

static constexpr int N  = 50000;
static constexpr int E  = 800000;
static constexpr int F0 = 64;    // input feats
static constexpr int F1 = 128;   // hidden
static constexpr int F2 = 32;    // classes

static constexpr int NBUK   = 196;   // ceil(N/256) buckets of 256 nodes (dst>>8)
static constexpr int CHUNK  = 4096;  // edges per histogram chunk
static constexpr int NCHUNK = 196;   // ceil(E/CHUNK)

// ---- B1: per-chunk LDS histogram over dst buckets (chunk-major out) ----
__global__ __launch_bounds__(256) void k_hist(const int* __restrict__ dst,
                                              int* __restrict__ hist) {
  __shared__ int hl[NBUK];
  int tid = threadIdx.x, c = blockIdx.x;
  for (int t = tid; t < NBUK; t += 256) hl[t] = 0;
  __syncthreads();
  int e0 = c * CHUNK, m = min(CHUNK, E - e0);
  for (int i = tid; i < m; i += 256)
    atomicAdd(&hl[dst[e0 + i] >> 8], 1);
  __syncthreads();
  for (int t = tid; t < NBUK; t += 256) hist[c * NBUK + t] = hl[t];
}

// ---- B2: scatter edges into bucket-grouped order (packed (dlocal<<16)|src) ----
// Self-computes bucket bases (scan of totals) and this chunk's prefix from the
// full hist matrix (150 KB, L2-broadcast across blocks).
__global__ __launch_bounds__(256) void k_bucket(const int* __restrict__ src,
    const int* __restrict__ dst, const int* __restrict__ hist,
    unsigned int* __restrict__ ebuf) {
  __shared__ int sA[256], startL[NBUK];
  int t = threadIdx.x, c = blockIdx.x;
  int accAll = 0, accPre = 0;
  if (t < NBUK) {
    #pragma unroll 4
    for (int cp = 0; cp < NCHUNK; ++cp) {
      int v = hist[cp * NBUK + t];
      accAll += v;
      if (cp < c) accPre += v;
    }
  }
  int v = (t < NBUK) ? accAll : 0;
  sA[t] = v; __syncthreads();
  for (int off = 1; off < 256; off <<= 1) {
    int u = (t >= off) ? sA[t - off] : 0;
    __syncthreads(); sA[t] += u; __syncthreads();
  }
  if (t < NBUK) startL[t] = (sA[t] - v) + accPre;     // bucketBase + chunk prefix
  __syncthreads();
  int e0 = c * CHUNK, m = min(CHUNK, E - e0);
  for (int i = t; i < m; i += 256) {
    int e = e0 + i;
    int d = dst[e], s = src[e];
    int pos = atomicAdd(&startL[d >> 8], 1);           // LDS atomic
    ebuf[pos] = (unsigned int)s | ((unsigned int)(d & 255) << 16);
  }
}

// ---- B3: per-bucket CSR finalize (cnt/rowend/dinv + in-bucket sort) + xs prescale ----
__global__ __launch_bounds__(256) void k_csr(const unsigned int* __restrict__ ebuf,
    const int* __restrict__ hist, const float* __restrict__ x,
    int* __restrict__ cnt, int* __restrict__ rowend, float* __restrict__ dinv,
    int* __restrict__ ssrc, float* __restrict__ xs) {
  __shared__ int sA[256], cl[256], sc[256], cur[256];
  __shared__ float dl[256];
  __shared__ int baseSh, mSh;
  int t = threadIdx.x, b = blockIdx.x;
  // self-compute bucket totals and scan for this bucket's base/size
  int accAll = 0;
  if (t < NBUK) {
    #pragma unroll 4
    for (int cp = 0; cp < NCHUNK; ++cp)
      accAll += hist[cp * NBUK + t];
  }
  int v0 = (t < NBUK) ? accAll : 0;
  sA[t] = v0; __syncthreads();
  for (int off = 1; off < 256; off <<= 1) {
    int u = (t >= off) ? sA[t - off] : 0;
    __syncthreads(); sA[t] += u; __syncthreads();
  }
  if (t == b) { baseSh = sA[t] - v0; mSh = v0; }
  __syncthreads();
  int base = baseSh, m = mSh;
  int node0 = b << 8;
  cl[t] = 0;
  __syncthreads();
  for (int i = t; i < m; i += 256)
    atomicAdd(&cl[(ebuf[base + i] >> 16) & 255], 1);
  __syncthreads();
  int v = cl[t];
  sc[t] = v; __syncthreads();
  for (int off = 1; off < 256; off <<= 1) {
    int u = (t >= off) ? sc[t - off] : 0;
    __syncthreads(); sc[t] += u; __syncthreads();
  }
  int excl = sc[t] - v;
  cur[t] = excl;
  float dv = rsqrtf((float)(v + 1));                  // +1 self-loop
  dl[t] = dv;
  int g = node0 + t;
  if (g < N) {
    cnt[g]    = v;
    rowend[g] = base + excl + v;
    dinv[g]   = dv;
  }
  __syncthreads();
  for (int i = t; i < m; i += 256) {
    unsigned int p = ebuf[base + i];
    int d = (p >> 16) & 255;
    int r = atomicAdd(&cur[d], 1);                     // LDS atomic
    ssrc[base + r] = (int)(p & 0xFFFFu);
  }
  // fused prescale: xs[n] = x[n] * dinv[n] for this bucket's 256 nodes
  for (int i = t; i < 256 * (F0 / 4); i += 256) {
    int nl = i >> 4;                                   // local node
    int n = node0 + nl;
    if (n < N) {
      float4 w = reinterpret_cast<const float4*>(x)[n * (F0 / 4) + (i & 15)];
      float d = dl[nl];
      w.x *= d; w.y *= d; w.z *= d; w.w *= d;
      reinterpret_cast<float4*>(xs)[n * (F0 / 4) + (i & 15)] = w;
    }
  }
}

// ---- layer-1 aggregation: AX[n] = dinv[n] * (xs[n] + sum_s xs[s]) ----
__global__ __launch_bounds__(256) void k_agg1(const int* __restrict__ rowend,
    const int* __restrict__ cnt, const int* __restrict__ ssrc,
    const float* __restrict__ xs, const float* __restrict__ dinv,
    float* __restrict__ AX) {
  int gw = (blockIdx.x * 256 + threadIdx.x) >> 6;   // node (one wave each)
  int lane = threadIdx.x & 63;                      // feature
  if (gw >= N) return;
  int end   = __builtin_amdgcn_readfirstlane(rowend[gw]);
  int deg   = __builtin_amdgcn_readfirstlane(cnt[gw]);
  int start = end - deg;
  float a0 = xs[(size_t)gw * F0 + lane];            // self loop (already *dinv)
  float a1 = 0.f, a2 = 0.f, a3 = 0.f;
  for (int e0 = start; e0 < end; e0 += 16) {
    #pragma unroll
    for (int u = 0; u < 16; ++u) {
      int j  = e0 + u;
      int jc = (j < end) ? j : start;               // uniform clamp (dup line -> L1)
      int s  = ssrc[jc];                            // wave-uniform -> s_load
      float v = xs[(size_t)s * F0 + lane];
      v = (j < end) ? v : 0.f;                      // uniform mask
      if ((u & 3) == 0) a0 += v;
      else if ((u & 3) == 1) a1 += v;
      else if ((u & 3) == 2) a2 += v;
      else a3 += v;
    }
  }
  AX[(size_t)gw * F0 + lane] = ((a0 + a2) + (a1 + a3)) * dinv[gw];
}

// ---- GEMM1: H1r = relu(AX @ W1 + b1), 64x128 tile, 4r x 8c per thread ----
// W1 in LDS with XOR float4-slot swizzle (slot p = s ^ (s>>2)) so the 16
// column-groups' stride-8-slot reads spread 2-way across bank quads (free).
__global__ __launch_bounds__(256) void k_gemm1(const float* __restrict__ AX,
    const float* __restrict__ W1, const float* __restrict__ b1,
    float* __restrict__ H1r) {
  __shared__ float Ws[F0 * F1];      // 32 KB, [64][32 float4-slots] swizzled
  __shared__ float Xs[64][F0 + 4];   // 17.4 KB, stride 68 -> clean broadcast
  const int tid = threadIdx.x;
  const int row0 = blockIdx.x * 64;
  float4* Wsf4 = reinterpret_cast<float4*>(Ws);
  for (int i = tid; i < F0 * F1 / 4; i += 256) {
    int k = i >> 5, s = i & 31;
    int p = s ^ (s >> 2);
    Wsf4[k * 32 + p] = reinterpret_cast<const float4*>(W1)[i];
  }
  for (int i = tid; i < 64 * 16; i += 256) {
    int r = i >> 4, c4 = i & 15;
    int n = row0 + r;
    float4 v = make_float4(0.f, 0.f, 0.f, 0.f);
    if (n < N) v = reinterpret_cast<const float4*>(AX)[n * 16 + c4];
    *reinterpret_cast<float4*>(&Xs[r][c4 * 4]) = v;
  }
  __syncthreads();
  const int cg = tid & 15, rg = tid >> 4;
  const int c0 = cg * 8;
  const int s0 = 2 * cg, s1 = 2 * cg + 1;
  const int p0 = s0 ^ (s0 >> 2), p1 = s1 ^ (s1 >> 2);
  float acc[4][8];
  #pragma unroll
  for (int i = 0; i < 4; ++i)
    #pragma unroll
    for (int j = 0; j < 8; ++j) acc[i][j] = 0.f;
  for (int k0 = 0; k0 < F0; k0 += 4) {
    float x0[4], x1[4], x2[4], x3[4];
    *reinterpret_cast<float4*>(x0) = *reinterpret_cast<const float4*>(&Xs[rg * 4 + 0][k0]);
    *reinterpret_cast<float4*>(x1) = *reinterpret_cast<const float4*>(&Xs[rg * 4 + 1][k0]);
    *reinterpret_cast<float4*>(x2) = *reinterpret_cast<const float4*>(&Xs[rg * 4 + 2][k0]);
    *reinterpret_cast<float4*>(x3) = *reinterpret_cast<const float4*>(&Xs[rg * 4 + 3][k0]);
    #pragma unroll
    for (int kk = 0; kk < 4; ++kk) {
      float w[8];
      *reinterpret_cast<float4*>(w)     = Wsf4[(k0 + kk) * 32 + p0];
      *reinterpret_cast<float4*>(w + 4) = Wsf4[(k0 + kk) * 32 + p1];
      #pragma unroll
      for (int j = 0; j < 8; ++j) {
        acc[0][j] = fmaf(x0[kk], w[j], acc[0][j]);
        acc[1][j] = fmaf(x1[kk], w[j], acc[1][j]);
        acc[2][j] = fmaf(x2[kk], w[j], acc[2][j]);
        acc[3][j] = fmaf(x3[kk], w[j], acc[3][j]);
      }
    }
  }
  float bb[8];
  *reinterpret_cast<float4*>(bb)     = *reinterpret_cast<const float4*>(&b1[c0]);
  *reinterpret_cast<float4*>(bb + 4) = *reinterpret_cast<const float4*>(&b1[c0 + 4]);
  #pragma unroll
  for (int i = 0; i < 4; ++i) {
    int n = row0 + rg * 4 + i;
    if (n < N) {
      float o[8];
      #pragma unroll
      for (int j = 0; j < 8; ++j) o[j] = fmaxf(acc[i][j] + bb[j], 0.f);
      *reinterpret_cast<float4*>(&H1r[(size_t)n * F1 + c0])     = *reinterpret_cast<float4*>(o);
      *reinterpret_cast<float4*>(&H1r[(size_t)n * F1 + c0 + 4]) = *reinterpret_cast<float4*>(o + 4);
    }
  }
}

// ---- GEMM2: H2s = (H1r @ W2) * dinv, 128-row tile, 2r x 8c per thread ----
// H1 rows read directly from global (4x redundancy, L2/L3-served); only W2 in LDS.
__global__ __launch_bounds__(256) void k_gemm2(const float* __restrict__ H1r,
    const float* __restrict__ dinv, const float* __restrict__ W2,
    float* __restrict__ H2s) {
  __shared__ float Ws[F1 * F2];      // 16 KB
  const int tid = threadIdx.x;
  const int row0 = blockIdx.x * 128;
  float4* Wsf4 = reinterpret_cast<float4*>(Ws);
  for (int i = tid; i < F1 * F2 / 4; i += 256)
    Wsf4[i] = reinterpret_cast<const float4*>(W2)[i];
  __syncthreads();
  const int cg = tid & 3, rg = tid >> 2;           // cols cg*8.. ; rows rg*2..
  const int c0 = cg * 8;
  const int n0 = row0 + rg * 2, n1 = n0 + 1;
  const int na = (n0 < N) ? n0 : 0, nb = (n1 < N) ? n1 : 0;
  const float4* X0 = reinterpret_cast<const float4*>(H1r + (size_t)na * F1);
  const float4* X1 = reinterpret_cast<const float4*>(H1r + (size_t)nb * F1);
  float acc[2][8];
  #pragma unroll
  for (int i = 0; i < 2; ++i)
    #pragma unroll
    for (int j = 0; j < 8; ++j) acc[i][j] = 0.f;
  for (int k0 = 0; k0 < F1; k0 += 4) {
    float x0[4], x1[4];
    *reinterpret_cast<float4*>(x0) = X0[k0 >> 2];
    *reinterpret_cast<float4*>(x1) = X1[k0 >> 2];
    #pragma unroll
    for (int kk = 0; kk < 4; ++kk) {
      float w[8];
      *reinterpret_cast<float4*>(w)     = Wsf4[(k0 + kk) * 8 + cg * 2];
      *reinterpret_cast<float4*>(w + 4) = Wsf4[(k0 + kk) * 8 + cg * 2 + 1];
      #pragma unroll
      for (int j = 0; j < 8; ++j) {
        acc[0][j] = fmaf(x0[kk], w[j], acc[0][j]);
        acc[1][j] = fmaf(x1[kk], w[j], acc[1][j]);
      }
    }
  }
  #pragma unroll
  for (int i = 0; i < 2; ++i) {
    int n = n0 + i;
    if (n < N) {
      float d = dinv[n];
      float o[8];
      #pragma unroll
      for (int j = 0; j < 8; ++j) o[j] = acc[i][j] * d;
      *reinterpret_cast<float4*>(&H2s[(size_t)n * F2 + c0])     = *reinterpret_cast<float4*>(o);
      *reinterpret_cast<float4*>(&H2s[(size_t)n * F2 + c0 + 4]) = *reinterpret_cast<float4*>(o + 4);
    }
  }
}

// ---- fused layer-2 aggregation + bias + head ----
// h2[n] = dinv[n]*(H2s[n] + sum_s H2s[s]) + b2 ; out[n] = h2[n] @ Wc + bc
__global__ __launch_bounds__(256) void k_agg2h(const int* __restrict__ rowend,
    const int* __restrict__ cnt, const int* __restrict__ ssrc,
    const float* __restrict__ H2s, const float* __restrict__ dinv,
    const float* __restrict__ b2, const float* __restrict__ Wc,
    const float* __restrict__ bc, float* __restrict__ h2,
    float* __restrict__ out) {
  __shared__ float Wcs[F2][F2];  // 4 KB
  const int tid = threadIdx.x;
  for (int i = tid; i < F2 * F2; i += 256) Wcs[i >> 5][i & 31] = Wc[i];
  __syncthreads();
  int gw = (blockIdx.x * 256 + tid) >> 6;           // node (one wave each)
  int lane = tid & 63;
  int f = lane & 31, half = lane >> 5;
  if (gw >= N) return;
  int end   = __builtin_amdgcn_readfirstlane(rowend[gw]);
  int deg   = __builtin_amdgcn_readfirstlane(cnt[gw]);
  int start = end - deg;
  float a0 = (half == 0) ? H2s[(size_t)gw * F2 + f] : 0.f;  // self loop
  float a1 = 0.f, a2 = 0.f, a3 = 0.f;
  for (int e0 = start; e0 < end; e0 += 8) {
    #pragma unroll
    for (int u = 0; u < 4; ++u) {
      int ja = e0 + 2 * u, jb = ja + 1;
      int sa = ssrc[(ja < end) ? ja : start];       // uniform -> s_load
      int sb = ssrc[(jb < end) ? jb : start];
      int s  = half ? sb : sa;
      int j  = half ? jb : ja;
      float v = H2s[(size_t)s * F2 + f];
      v = (j < end) ? v : 0.f;
      if (u == 0) a0 += v;
      else if (u == 1) a1 += v;
      else if (u == 2) a2 += v;
      else a3 += v;
    }
  }
  float acc = (a0 + a2) + (a1 + a3);
  acc += __shfl_xor(acc, 32);
  float h2v = dinv[gw] * acc + b2[f];               // valid in all 64 lanes
  if (half == 0) h2[(size_t)gw * F2 + f] = h2v;
  // head: out[gw][f] = bc[f] + sum_k h2v(k) * Wc[k][f]; halves split k range
  float acco = 0.f;
  #pragma unroll
  for (int kk = 0; kk < 16; ++kk) {
    int k = kk + 16 * half;
    float hk = __shfl(h2v, k);                      // lane k holds feature k
    acco += hk * Wcs[k][f];
  }
  acco += __shfl_xor(acco, 32);
  if (half == 0) out[(size_t)gw * F2 + f] = acco + bc[f];
}

extern "C" void kernel_launch(void* const* d_in, const int* in_sizes, int n_in,
                              void* d_out, int out_size, void* d_ws, size_t ws_size,
                              hipStream_t stream) {
  const float* x  = (const float*)d_in[0];
  const int*   ei = (const int*)d_in[1];
  const int*   src = ei;                 // edge_index[0]
  const int*   dst = ei + E;             // edge_index[1]
  const float* W1 = (const float*)d_in[2];
  const float* b1 = (const float*)d_in[3];
  const float* W2 = (const float*)d_in[4];
  const float* b2 = (const float*)d_in[5];
  const float* Wc = (const float*)d_in[6];
  const float* bc = (const float*)d_in[7];

  float* out = (float*)d_out;                    // [N, 32] logits
  float* h2  = out + (size_t)N * F2;             // [N, 32] hidden output

  // workspace layout (~66 MB of 256 MB) — all disjoint, no aliasing
  int*   cnt        = (int*)d_ws;                // N
  int*   rowend     = cnt + N;                   // N
  float* dinv       = (float*)(rowend + N);      // N
  int*   ssrc       = (int*)(dinv + N);          // E
  unsigned int* ebuf = (unsigned int*)(ssrc + E);// E
  int*   hist       = (int*)(ebuf + E);          // NCHUNK*NBUK (chunk-major)
  float* xs         = (float*)(hist + NCHUNK * NBUK + 64); // N*64
  float* AX         = xs + (size_t)N * F0;       // N*64
  float* H1r        = AX + (size_t)N * F0;       // N*128
  float* H2s        = H1r + (size_t)N * F1;      // N*32

  k_hist  <<<NCHUNK, 256, 0, stream>>>(dst, hist);
  k_bucket<<<NCHUNK, 256, 0, stream>>>(src, dst, hist, ebuf);
  k_csr   <<<NBUK,   256, 0, stream>>>(ebuf, hist, x, cnt, rowend, dinv, ssrc, xs);

  k_agg1 <<<(N + 3) / 4, 256, 0, stream>>>(rowend, cnt, ssrc, xs, dinv, AX);
  k_gemm1<<<(N + 63) / 64, 256, 0, stream>>>(AX, W1, b1, H1r);
  k_gemm2<<<(N + 127) / 128, 256, 0, stream>>>(H1r, dinv, W2, H2s);
  k_agg2h<<<(N + 3) / 4, 256, 0, stream>>>(rowend, cnt, ssrc, H2s, dinv, b2, Wc, bc, h2, out);
}

// Round 10
// 136.783 us; speedup vs baseline: 1.1254x; 1.1254x over previous
//
#include <hip/hip_runtime.h>

// GCN forward: two GCNConv layers + linear head.
// Round 10: round-6 structure; CSR build re-parallelized: 128-node buckets
// (dst>>7, NBUK=392 blocks) + 512-thread build kernels. Fixes k_csr's
// 1-wave/SIMD latency binding (41us @ 196 blocks -> ~13us @ 392x8waves).
// 8 dispatches:
//   k_hist -> k_scanbk -> k_bucket -> k_csr(+dinv+prescale) ->
//   k_agg1 -> k_gemm1 -> k_gemm2 -> k_agg2h
// out = dinv[d] * sum_{s in N(d)+self} (dinv[s]*h[s]) per layer.
// Layer1 aggregates BEFORE GEMM (64 feats), layer2 AFTER its GEMM (32 feats).

static constexpr int N  = 50000;
static constexpr int E  = 800000;
static constexpr int F0 = 64;    // input feats
static constexpr int F1 = 128;   // hidden
static constexpr int F2 = 32;    // classes

static constexpr int BSH    = 7;     // bucket = dst>>7 (128 nodes)
static constexpr int BNODES = 128;
static constexpr int BMASK  = 127;
static constexpr int NBUK   = 392;   // ceil(N/128)
static constexpr int CHUNK  = 4096;  // edges per histogram chunk
static constexpr int NCHUNK = 196;   // ceil(E/CHUNK)

// ---- B1: per-chunk LDS histogram over dst buckets (bucket-major out) ----
__global__ __launch_bounds__(512) void k_hist(const int* __restrict__ dst,
                                              int* __restrict__ hist) {
  __shared__ int hl[NBUK];
  int tid = threadIdx.x, c = blockIdx.x;
  for (int t = tid; t < NBUK; t += 512) hl[t] = 0;
  __syncthreads();
  int e0 = c * CHUNK, m = min(CHUNK, E - e0);
  for (int i = tid; i < m; i += 512)
    atomicAdd(&hl[dst[e0 + i] >> BSH], 1);
  __syncthreads();
  for (int t = tid; t < NBUK; t += 512) hist[t * NCHUNK + c] = hl[t];
}

// ---- S1: per-bucket exclusive scan over chunks (in place); bucket totals out ----
__global__ __launch_bounds__(256) void k_scanbk(int* __restrict__ hist,
                                                int* __restrict__ bucketTot) {
  __shared__ int s[256];
  int t = threadIdx.x, b = blockIdx.x;
  int v = (t < NCHUNK) ? hist[b * NCHUNK + t] : 0;
  s[t] = v; __syncthreads();
  for (int off = 1; off < 256; off <<= 1) {
    int u = (t >= off) ? s[t - off] : 0;
    __syncthreads(); s[t] += u; __syncthreads();
  }
  if (t < NCHUNK) hist[b * NCHUNK + t] = s[t] - v;
  if (t == 255) bucketTot[b] = s[255];
}

// ---- B2: scatter edges into bucket-grouped order (packed (dlocal<<16)|src) ----
__global__ __launch_bounds__(512) void k_bucket(const int* __restrict__ src,
    const int* __restrict__ dst, const int* __restrict__ hist,
    const int* __restrict__ bucketTot, unsigned int* __restrict__ ebuf) {
  __shared__ int tl[512], sl[512], startL[NBUK];
  int t = threadIdx.x, c = blockIdx.x;
  int v = (t < NBUK) ? bucketTot[t] : 0;
  tl[t] = v; sl[t] = v; __syncthreads();
  for (int off = 1; off < 512; off <<= 1) {
    int u = (t >= off) ? sl[t - off] : 0;
    __syncthreads(); sl[t] += u; __syncthreads();
  }
  for (int i = t; i < NBUK; i += 512)
    startL[i] = (sl[i] - tl[i]) + hist[i * NCHUNK + c];
  __syncthreads();
  int e0 = c * CHUNK, m = min(CHUNK, E - e0);
  for (int i = t; i < m; i += 512) {
    int e = e0 + i;
    int d = dst[e], s = src[e];
    int pos = atomicAdd(&startL[d >> BSH], 1);         // LDS atomic
    ebuf[pos] = (unsigned int)s | ((unsigned int)(d & BMASK) << 16);
  }
}

// ---- B3: per-bucket CSR finalize (cnt/rowend/dinv + in-bucket sort) + xs prescale ----
__global__ __launch_bounds__(512) void k_csr(const unsigned int* __restrict__ ebuf,
    const int* __restrict__ bucketTot, const float* __restrict__ x,
    int* __restrict__ cnt, int* __restrict__ rowend, float* __restrict__ dinv,
    int* __restrict__ ssrc, float* __restrict__ xs) {
  __shared__ int tl[512], sl[512], cl[BNODES], sc[BNODES], cur[BNODES];
  __shared__ float dl[BNODES];
  int t = threadIdx.x, b = blockIdx.x;
  // scan bucket totals to get this bucket's base
  int v0 = (t < NBUK) ? bucketTot[t] : 0;
  tl[t] = v0; sl[t] = v0; __syncthreads();
  for (int off = 1; off < 512; off <<= 1) {
    int u = (t >= off) ? sl[t - off] : 0;
    __syncthreads(); sl[t] += u; __syncthreads();
  }
  int base = sl[b] - tl[b];
  int m    = tl[b];
  int node0 = b << BSH;
  if (t < BNODES) cl[t] = 0;
  __syncthreads();
  for (int i = t; i < m; i += 512)
    atomicAdd(&cl[(ebuf[base + i] >> 16) & BMASK], 1);
  __syncthreads();
  int v = 0;
  if (t < BNODES) { v = cl[t]; sc[t] = v; }
  __syncthreads();
  for (int off = 1; off < BNODES; off <<= 1) {
    int u = (t >= off && t < BNODES) ? sc[t - off] : 0;
    __syncthreads();
    if (t < BNODES) sc[t] += u;
    __syncthreads();
  }
  if (t < BNODES) {
    int excl = sc[t] - v;
    cur[t] = excl;
    float dv = rsqrtf((float)(v + 1));                // +1 self-loop
    dl[t] = dv;
    int g = node0 + t;
    if (g < N) {
      cnt[g]    = v;
      rowend[g] = base + excl + v;
      dinv[g]   = dv;
    }
  }
  __syncthreads();
  for (int i = t; i < m; i += 512) {
    unsigned int p = ebuf[base + i];
    int d = (p >> 16) & BMASK;
    int r = atomicAdd(&cur[d], 1);                     // LDS atomic
    ssrc[base + r] = (int)(p & 0xFFFFu);
  }
  // fused prescale: xs[n] = x[n] * dinv[n] for this bucket's 128 nodes
  for (int i = t; i < BNODES * (F0 / 4); i += 512) {
    int nl = i >> 4;                                   // local node
    int n = node0 + nl;
    if (n < N) {
      float4 w = reinterpret_cast<const float4*>(x)[n * (F0 / 4) + (i & 15)];
      float d = dl[nl];
      w.x *= d; w.y *= d; w.z *= d; w.w *= d;
      reinterpret_cast<float4*>(xs)[n * (F0 / 4) + (i & 15)] = w;
    }
  }
}

// ---- layer-1 aggregation: AX[n] = dinv[n] * (xs[n] + sum_s xs[s]) ----
__global__ __launch_bounds__(256) void k_agg1(const int* __restrict__ rowend,
    const int* __restrict__ cnt, const int* __restrict__ ssrc,
    const float* __restrict__ xs, const float* __restrict__ dinv,
    float* __restrict__ AX) {
  int gw = (blockIdx.x * 256 + threadIdx.x) >> 6;   // node (one wave each)
  int lane = threadIdx.x & 63;                      // feature
  if (gw >= N) return;
  int end   = __builtin_amdgcn_readfirstlane(rowend[gw]);
  int deg   = __builtin_amdgcn_readfirstlane(cnt[gw]);
  int start = end - deg;
  float a0 = xs[(size_t)gw * F0 + lane];            // self loop (already *dinv)
  float a1 = 0.f, a2 = 0.f, a3 = 0.f;
  for (int e0 = start; e0 < end; e0 += 8) {
    #pragma unroll
    for (int u = 0; u < 8; ++u) {
      int j  = e0 + u;
      int jc = (j < end) ? j : start;               // uniform clamp
      int s  = ssrc[jc];                            // wave-uniform -> s_load
      float v = xs[(size_t)s * F0 + lane];
      v = (j < end) ? v : 0.f;                      // uniform mask
      if ((u & 3) == 0) a0 += v;
      else if ((u & 3) == 1) a1 += v;
      else if ((u & 3) == 2) a2 += v;
      else a3 += v;
    }
  }
  AX[(size_t)gw * F0 + lane] = ((a0 + a2) + (a1 + a3)) * dinv[gw];
}

// ---- GEMM1: H1r = relu(AX @ W1 + b1), 64x128 tile, 4r x 8c per thread ----
// W1 in LDS with XOR float4-slot swizzle (slot p = s ^ (s>>2)) so the 16
// column-groups' stride-8-slot reads spread 2-way across bank quads (free).
__global__ __launch_bounds__(256) void k_gemm1(const float* __restrict__ AX,
    const float* __restrict__ W1, const float* __restrict__ b1,
    float* __restrict__ H1r) {
  __shared__ float Ws[F0 * F1];      // 32 KB, [64][32 float4-slots] swizzled
  __shared__ float Xs[64][F0 + 4];   // 17.4 KB, stride 68 -> clean broadcast
  const int tid = threadIdx.x;
  const int row0 = blockIdx.x * 64;
  float4* Wsf4 = reinterpret_cast<float4*>(Ws);
  for (int i = tid; i < F0 * F1 / 4; i += 256) {
    int k = i >> 5, s = i & 31;
    int p = s ^ (s >> 2);
    Wsf4[k * 32 + p] = reinterpret_cast<const float4*>(W1)[i];
  }
  for (int i = tid; i < 64 * 16; i += 256) {
    int r = i >> 4, c4 = i & 15;
    int n = row0 + r;
    float4 v = make_float4(0.f, 0.f, 0.f, 0.f);
    if (n < N) v = reinterpret_cast<const float4*>(AX)[n * 16 + c4];
    *reinterpret_cast<float4*>(&Xs[r][c4 * 4]) = v;
  }
  __syncthreads();
  const int cg = tid & 15, rg = tid >> 4;
  const int c0 = cg * 8;
  const int s0 = 2 * cg, s1 = 2 * cg + 1;
  const int p0 = s0 ^ (s0 >> 2), p1 = s1 ^ (s1 >> 2);
  float acc[4][8];
  #pragma unroll
  for (int i = 0; i < 4; ++i)
    #pragma unroll
    for (int j = 0; j < 8; ++j) acc[i][j] = 0.f;
  for (int k0 = 0; k0 < F0; k0 += 4) {
    float x0[4], x1[4], x2[4], x3[4];
    *reinterpret_cast<float4*>(x0) = *reinterpret_cast<const float4*>(&Xs[rg * 4 + 0][k0]);
    *reinterpret_cast<float4*>(x1) = *reinterpret_cast<const float4*>(&Xs[rg * 4 + 1][k0]);
    *reinterpret_cast<float4*>(x2) = *reinterpret_cast<const float4*>(&Xs[rg * 4 + 2][k0]);
    *reinterpret_cast<float4*>(x3) = *reinterpret_cast<const float4*>(&Xs[rg * 4 + 3][k0]);
    #pragma unroll
    for (int kk = 0; kk < 4; ++kk) {
      float w[8];
      *reinterpret_cast<float4*>(w)     = Wsf4[(k0 + kk) * 32 + p0];
      *reinterpret_cast<float4*>(w + 4) = Wsf4[(k0 + kk) * 32 + p1];
      #pragma unroll
      for (int j = 0; j < 8; ++j) {
        acc[0][j] = fmaf(x0[kk], w[j], acc[0][j]);
        acc[1][j] = fmaf(x1[kk], w[j], acc[1][j]);
        acc[2][j] = fmaf(x2[kk], w[j], acc[2][j]);
        acc[3][j] = fmaf(x3[kk], w[j], acc[3][j]);
      }
    }
  }
  float bb[8];
  *reinterpret_cast<float4*>(bb)     = *reinterpret_cast<const float4*>(&b1[c0]);
  *reinterpret_cast<float4*>(bb + 4) = *reinterpret_cast<const float4*>(&b1[c0 + 4]);
  #pragma unroll
  for (int i = 0; i < 4; ++i) {
    int n = row0 + rg * 4 + i;
    if (n < N) {
      float o[8];
      #pragma unroll
      for (int j = 0; j < 8; ++j) o[j] = fmaxf(acc[i][j] + bb[j], 0.f);
      *reinterpret_cast<float4*>(&H1r[(size_t)n * F1 + c0])     = *reinterpret_cast<float4*>(o);
      *reinterpret_cast<float4*>(&H1r[(size_t)n * F1 + c0 + 4]) = *reinterpret_cast<float4*>(o + 4);
    }
  }
}

// ---- GEMM2: H2s = (H1r @ W2) * dinv, 128-row tile, 2r x 8c per thread ----
// H1 rows read directly from global (4x redundancy, L2/L3-served); only W2 in LDS.
__global__ __launch_bounds__(256) void k_gemm2(const float* __restrict__ H1r,
    const float* __restrict__ dinv, const float* __restrict__ W2,
    float* __restrict__ H2s) {
  __shared__ float Ws[F1 * F2];      // 16 KB
  const int tid = threadIdx.x;
  const int row0 = blockIdx.x * 128;
  float4* Wsf4 = reinterpret_cast<float4*>(Ws);
  for (int i = tid; i < F1 * F2 / 4; i += 256)
    Wsf4[i] = reinterpret_cast<const float4*>(W2)[i];
  __syncthreads();
  const int cg = tid & 3, rg = tid >> 2;           // cols cg*8.. ; rows rg*2..
  const int c0 = cg * 8;
  const int n0 = row0 + rg * 2, n1 = n0 + 1;
  const int na = (n0 < N) ? n0 : 0, nb = (n1 < N) ? n1 : 0;
  const float4* X0 = reinterpret_cast<const float4*>(H1r + (size_t)na * F1);
  const float4* X1 = reinterpret_cast<const float4*>(H1r + (size_t)nb * F1);
  float acc[2][8];
  #pragma unroll
  for (int i = 0; i < 2; ++i)
    #pragma unroll
    for (int j = 0; j < 8; ++j) acc[i][j] = 0.f;
  for (int k0 = 0; k0 < F1; k0 += 4) {
    float x0[4], x1[4];
    *reinterpret_cast<float4*>(x0) = X0[k0 >> 2];
    *reinterpret_cast<float4*>(x1) = X1[k0 >> 2];
    #pragma unroll
    for (int kk = 0; kk < 4; ++kk) {
      float w[8];
      *reinterpret_cast<float4*>(w)     = Wsf4[(k0 + kk) * 8 + cg * 2];
      *reinterpret_cast<float4*>(w + 4) = Wsf4[(k0 + kk) * 8 + cg * 2 + 1];
      #pragma unroll
      for (int j = 0; j < 8; ++j) {
        acc[0][j] = fmaf(x0[kk], w[j], acc[0][j]);
        acc[1][j] = fmaf(x1[kk], w[j], acc[1][j]);
      }
    }
  }
  #pragma unroll
  for (int i = 0; i < 2; ++i) {
    int n = n0 + i;
    if (n < N) {
      float d = dinv[n];
      float o[8];
      #pragma unroll
      for (int j = 0; j < 8; ++j) o[j] = acc[i][j] * d;
      *reinterpret_cast<float4*>(&H2s[(size_t)n * F2 + c0])     = *reinterpret_cast<float4*>(o);
      *reinterpret_cast<float4*>(&H2s[(size_t)n * F2 + c0 + 4]) = *reinterpret_cast<float4*>(o + 4);
    }
  }
}

// ---- fused layer-2 aggregation + bias + head ----
// h2[n] = dinv[n]*(H2s[n] + sum_s H2s[s]) + b2 ; out[n] = h2[n] @ Wc + bc
__global__ __launch_bounds__(256) void k_agg2h(const int* __restrict__ rowend,
    const int* __restrict__ cnt, const int* __restrict__ ssrc,
    const float* __restrict__ H2s, const float* __restrict__ dinv,
    const float* __restrict__ b2, const float* __restrict__ Wc,
    const float* __restrict__ bc, float* __restrict__ h2,
    float* __restrict__ out) {
  __shared__ float Wcs[F2][F2];  // 4 KB
  const int tid = threadIdx.x;
  for (int i = tid; i < F2 * F2; i += 256) Wcs[i >> 5][i & 31] = Wc[i];
  __syncthreads();
  int gw = (blockIdx.x * 256 + tid) >> 6;           // node (one wave each)
  int lane = tid & 63;
  int f = lane & 31, half = lane >> 5;
  if (gw >= N) return;
  int end   = __builtin_amdgcn_readfirstlane(rowend[gw]);
  int deg   = __builtin_amdgcn_readfirstlane(cnt[gw]);
  int start = end - deg;
  float a0 = (half == 0) ? H2s[(size_t)gw * F2 + f] : 0.f;  // self loop
  float a1 = 0.f, a2 = 0.f, a3 = 0.f;
  for (int e0 = start; e0 < end; e0 += 8) {
    #pragma unroll
    for (int u = 0; u < 4; ++u) {
      int ja = e0 + 2 * u, jb = ja + 1;
      int sa = ssrc[(ja < end) ? ja : start];       // uniform -> s_load
      int sb = ssrc[(jb < end) ? jb : start];
      int s  = half ? sb : sa;
      int j  = half ? jb : ja;
      float v = H2s[(size_t)s * F2 + f];
      v = (j < end) ? v : 0.f;
      if (u == 0) a0 += v;
      else if (u == 1) a1 += v;
      else if (u == 2) a2 += v;
      else a3 += v;
    }
  }
  float acc = (a0 + a2) + (a1 + a3);
  acc += __shfl_xor(acc, 32);
  float h2v = dinv[gw] * acc + b2[f];               // valid in all 64 lanes
  if (half == 0) h2[(size_t)gw * F2 + f] = h2v;
  // head: out[gw][f] = bc[f] + sum_k h2v(k) * Wc[k][f]; halves split k range
  float acco = 0.f;
  #pragma unroll
  for (int kk = 0; kk < 16; ++kk) {
    int k = kk + 16 * half;
    float hk = __shfl(h2v, k);                      // lane k holds feature k
    acco += hk * Wcs[k][f];
  }
  acco += __shfl_xor(acco, 32);
  if (half == 0) out[(size_t)gw * F2 + f] = acco + bc[f];
}

extern "C" void kernel_launch(void* const* d_in, const int* in_sizes, int n_in,
                              void* d_out, int out_size, void* d_ws, size_t ws_size,
                              hipStream_t stream) {
  const float* x  = (const float*)d_in[0];
  const int*   ei = (const int*)d_in[1];
  const int*   src = ei;                 // edge_index[0]
  const int*   dst = ei + E;             // edge_index[1]
  const float* W1 = (const float*)d_in[2];
  const float* b1 = (const float*)d_in[3];
  const float* W2 = (const float*)d_in[4];
  const float* b2 = (const float*)d_in[5];
  const float* Wc = (const float*)d_in[6];
  const float* bc = (const float*)d_in[7];

  float* out = (float*)d_out;                    // [N, 32] logits
  float* h2  = out + (size_t)N * F2;             // [N, 32] hidden output

  // workspace layout (~66 MB of 256 MB) — all disjoint, no aliasing
  int*   cnt        = (int*)d_ws;                // N
  int*   rowend     = cnt + N;                   // N
  int*   bucketTot  = rowend + N;                // NBUK (pad to 512)
  float* dinv       = (float*)(bucketTot + 512); // N
  int*   ssrc       = (int*)(dinv + N);          // E
  unsigned int* ebuf = (unsigned int*)(ssrc + E);// E
  int*   hist       = (int*)(ebuf + E);          // NBUK*NCHUNK (bucket-major)
  float* xs         = (float*)(hist + NBUK * NCHUNK + 64); // N*64
  float* AX         = xs + (size_t)N * F0;       // N*64
  float* H1r        = AX + (size_t)N * F0;       // N*128
  float* H2s        = H1r + (size_t)N * F1;      // N*32

  k_hist  <<<NCHUNK, 512, 0, stream>>>(dst, hist);
  k_scanbk<<<NBUK,   256, 0, stream>>>(hist, bucketTot);
  k_bucket<<<NCHUNK, 512, 0, stream>>>(src, dst, hist, bucketTot, ebuf);
  k_csr   <<<NBUK,   512, 0, stream>>>(ebuf, bucketTot, x, cnt, rowend, dinv, ssrc, xs);

  k_agg1 <<<(N + 3) / 4, 256, 0, stream>>>(rowend, cnt, ssrc, xs, dinv, AX);
  k_gemm1<<<(N + 63) / 64, 256, 0, stream>>>(AX, W1, b1, H1r);
  k_gemm2<<<(N + 127) / 128, 256, 0, stream>>>(H1r, dinv, W2, H2s);
  k_agg2h<<<(N + 3) / 4, 256, 0, stream>>>(rowend, cnt, ssrc, H2s, dinv, b2, Wc, bc, h2, out);
}

// Round 11
// 134.855 us; speedup vs baseline: 1.1415x; 1.0143x over previous
//
#include <hip/hip_runtime.h>

// GCN forward: two GCNConv layers + linear head.
// Round 11: R10 structure; agg kernels rewritten for wide gathers:
//   agg1: float4/lane, 4 edges per VMEM instr (16-lane groups), 16-edge steps
//   agg2h: float2/lane, 4 edges per VMEM instr, head via per-wave LDS row
// 8 dispatches:
//   k_hist -> k_scanbk -> k_bucket -> k_csr(+dinv+prescale) ->
//   k_agg1 -> k_gemm1 -> k_gemm2 -> k_agg2h
// out = dinv[d] * sum_{s in N(d)+self} (dinv[s]*h[s]) per layer.
// Layer1 aggregates BEFORE GEMM (64 feats), layer2 AFTER its GEMM (32 feats).

static constexpr int N  = 50000;
static constexpr int E  = 800000;
static constexpr int F0 = 64;    // input feats
static constexpr int F1 = 128;   // hidden
static constexpr int F2 = 32;    // classes

static constexpr int BSH    = 7;     // bucket = dst>>7 (128 nodes)
static constexpr int BNODES = 128;
static constexpr int BMASK  = 127;
static constexpr int NBUK   = 392;   // ceil(N/128)
static constexpr int CHUNK  = 4096;  // edges per histogram chunk
static constexpr int NCHUNK = 196;   // ceil(E/CHUNK)

// ---- B1: per-chunk LDS histogram over dst buckets (bucket-major out) ----
__global__ __launch_bounds__(512) void k_hist(const int* __restrict__ dst,
                                              int* __restrict__ hist) {
  __shared__ int hl[NBUK];
  int tid = threadIdx.x, c = blockIdx.x;
  for (int t = tid; t < NBUK; t += 512) hl[t] = 0;
  __syncthreads();
  int e0 = c * CHUNK, m = min(CHUNK, E - e0);
  for (int i = tid; i < m; i += 512)
    atomicAdd(&hl[dst[e0 + i] >> BSH], 1);
  __syncthreads();
  for (int t = tid; t < NBUK; t += 512) hist[t * NCHUNK + c] = hl[t];
}

// ---- S1: per-bucket exclusive scan over chunks (in place); bucket totals out ----
__global__ __launch_bounds__(256) void k_scanbk(int* __restrict__ hist,
                                                int* __restrict__ bucketTot) {
  __shared__ int s[256];
  int t = threadIdx.x, b = blockIdx.x;
  int v = (t < NCHUNK) ? hist[b * NCHUNK + t] : 0;
  s[t] = v; __syncthreads();
  for (int off = 1; off < 256; off <<= 1) {
    int u = (t >= off) ? s[t - off] : 0;
    __syncthreads(); s[t] += u; __syncthreads();
  }
  if (t < NCHUNK) hist[b * NCHUNK + t] = s[t] - v;
  if (t == 255) bucketTot[b] = s[255];
}

// ---- B2: scatter edges into bucket-grouped order (packed (dlocal<<16)|src) ----
__global__ __launch_bounds__(512) void k_bucket(const int* __restrict__ src,
    const int* __restrict__ dst, const int* __restrict__ hist,
    const int* __restrict__ bucketTot, unsigned int* __restrict__ ebuf) {
  __shared__ int tl[512], sl[512], startL[NBUK];
  int t = threadIdx.x, c = blockIdx.x;
  int v = (t < NBUK) ? bucketTot[t] : 0;
  tl[t] = v; sl[t] = v; __syncthreads();
  for (int off = 1; off < 512; off <<= 1) {
    int u = (t >= off) ? sl[t - off] : 0;
    __syncthreads(); sl[t] += u; __syncthreads();
  }
  for (int i = t; i < NBUK; i += 512)
    startL[i] = (sl[i] - tl[i]) + hist[i * NCHUNK + c];
  __syncthreads();
  int e0 = c * CHUNK, m = min(CHUNK, E - e0);
  for (int i = t; i < m; i += 512) {
    int e = e0 + i;
    int d = dst[e], s = src[e];
    int pos = atomicAdd(&startL[d >> BSH], 1);         // LDS atomic
    ebuf[pos] = (unsigned int)s | ((unsigned int)(d & BMASK) << 16);
  }
}

// ---- B3: per-bucket CSR finalize (cnt/rowend/dinv + in-bucket sort) + xs prescale ----
__global__ __launch_bounds__(512) void k_csr(const unsigned int* __restrict__ ebuf,
    const int* __restrict__ bucketTot, const float* __restrict__ x,
    int* __restrict__ cnt, int* __restrict__ rowend, float* __restrict__ dinv,
    int* __restrict__ ssrc, float* __restrict__ xs) {
  __shared__ int tl[512], sl[512], cl[BNODES], sc[BNODES], cur[BNODES];
  __shared__ float dl[BNODES];
  int t = threadIdx.x, b = blockIdx.x;
  // scan bucket totals to get this bucket's base
  int v0 = (t < NBUK) ? bucketTot[t] : 0;
  tl[t] = v0; sl[t] = v0; __syncthreads();
  for (int off = 1; off < 512; off <<= 1) {
    int u = (t >= off) ? sl[t - off] : 0;
    __syncthreads(); sl[t] += u; __syncthreads();
  }
  int base = sl[b] - tl[b];
  int m    = tl[b];
  int node0 = b << BSH;
  if (t < BNODES) cl[t] = 0;
  __syncthreads();
  for (int i = t; i < m; i += 512)
    atomicAdd(&cl[(ebuf[base + i] >> 16) & BMASK], 1);
  __syncthreads();
  int v = 0;
  if (t < BNODES) { v = cl[t]; sc[t] = v; }
  __syncthreads();
  for (int off = 1; off < BNODES; off <<= 1) {
    int u = (t >= off && t < BNODES) ? sc[t - off] : 0;
    __syncthreads();
    if (t < BNODES) sc[t] += u;
    __syncthreads();
  }
  if (t < BNODES) {
    int excl = sc[t] - v;
    cur[t] = excl;
    float dv = rsqrtf((float)(v + 1));                // +1 self-loop
    dl[t] = dv;
    int g = node0 + t;
    if (g < N) {
      cnt[g]    = v;
      rowend[g] = base + excl + v;
      dinv[g]   = dv;
    }
  }
  __syncthreads();
  for (int i = t; i < m; i += 512) {
    unsigned int p = ebuf[base + i];
    int d = (p >> 16) & BMASK;
    int r = atomicAdd(&cur[d], 1);                     // LDS atomic
    ssrc[base + r] = (int)(p & 0xFFFFu);
  }
  // fused prescale: xs[n] = x[n] * dinv[n] for this bucket's 128 nodes
  for (int i = t; i < BNODES * (F0 / 4); i += 512) {
    int nl = i >> 4;                                   // local node
    int n = node0 + nl;
    if (n < N) {
      float4 w = reinterpret_cast<const float4*>(x)[n * (F0 / 4) + (i & 15)];
      float d = dl[nl];
      w.x *= d; w.y *= d; w.z *= d; w.w *= d;
      reinterpret_cast<float4*>(xs)[n * (F0 / 4) + (i & 15)] = w;
    }
  }
}

// ---- layer-1 aggregation: AX[n] = dinv[n] * (xs[n] + sum_s xs[s]) ----
// Wide-gather form: 4x 16-lane groups, each lane float4 -> 4 edges per VMEM
// instruction. 16 edges per outer step (4 gathers in flight).
__global__ __launch_bounds__(256) void k_agg1(const int* __restrict__ rowend,
    const int* __restrict__ cnt, const int* __restrict__ ssrc,
    const float* __restrict__ xs, const float* __restrict__ dinv,
    float* __restrict__ AX) {
  int gw = (blockIdx.x * 256 + threadIdx.x) >> 6;   // node (one wave each)
  int lane = threadIdx.x & 63;
  if (gw >= N) return;
  int end   = __builtin_amdgcn_readfirstlane(rowend[gw]);
  int deg   = __builtin_amdgcn_readfirstlane(cnt[gw]);
  int start = end - deg;
  const int g = lane >> 4, fl = lane & 15;
  float ax = 0.f, ay = 0.f, az = 0.f, aw = 0.f;
  for (int e0 = start; e0 < end; e0 += 16) {
    if (e0 + 16 <= end) {
      // full step: no masks; consecutive uniform ssrc loads (mergeable)
      #pragma unroll
      for (int u = 0; u < 4; ++u) {
        int j0 = e0 + 4 * u;
        int s0 = ssrc[j0], s1 = ssrc[j0 + 1], s2 = ssrc[j0 + 2], s3 = ssrc[j0 + 3];
        int sA = (g & 1) ? s1 : s0;
        int sB = (g & 1) ? s3 : s2;
        int s  = (g & 2) ? sB : sA;
        float4 v = *reinterpret_cast<const float4*>(&xs[(size_t)s * F0 + fl * 4]);
        ax += v.x; ay += v.y; az += v.z; aw += v.w;
      }
    } else {
      #pragma unroll
      for (int u = 0; u < 4; ++u) {
        int j0 = e0 + 4 * u, j1 = j0 + 1, j2 = j0 + 2, j3 = j0 + 3;
        int s0 = ssrc[(j0 < end) ? j0 : start];
        int s1 = ssrc[(j1 < end) ? j1 : start];
        int s2 = ssrc[(j2 < end) ? j2 : start];
        int s3 = ssrc[(j3 < end) ? j3 : start];
        float m0 = (j0 < end) ? 1.f : 0.f, m1 = (j1 < end) ? 1.f : 0.f;
        float m2 = (j2 < end) ? 1.f : 0.f, m3 = (j3 < end) ? 1.f : 0.f;
        int sA = (g & 1) ? s1 : s0;
        int sB = (g & 1) ? s3 : s2;
        int s  = (g & 2) ? sB : sA;
        float mA = (g & 1) ? m1 : m0;
        float mB = (g & 1) ? m3 : m2;
        float mm = (g & 2) ? mB : mA;
        float4 v = *reinterpret_cast<const float4*>(&xs[(size_t)s * F0 + fl * 4]);
        ax = fmaf(v.x, mm, ax); ay = fmaf(v.y, mm, ay);
        az = fmaf(v.z, mm, az); aw = fmaf(v.w, mm, aw);
      }
    }
  }
  // combine the 4 groups
  ax += __shfl_xor(ax, 16); ay += __shfl_xor(ay, 16);
  az += __shfl_xor(az, 16); aw += __shfl_xor(aw, 16);
  ax += __shfl_xor(ax, 32); ay += __shfl_xor(ay, 32);
  az += __shfl_xor(az, 32); aw += __shfl_xor(aw, 32);
  if (lane < 16) {
    float4 self = *reinterpret_cast<const float4*>(&xs[(size_t)gw * F0 + fl * 4]);
    float dv = dinv[gw];
    float4 o;
    o.x = (ax + self.x) * dv; o.y = (ay + self.y) * dv;
    o.z = (az + self.z) * dv; o.w = (aw + self.w) * dv;
    *reinterpret_cast<float4*>(&AX[(size_t)gw * F0 + fl * 4]) = o;
  }
}

// ---- GEMM1: H1r = relu(AX @ W1 + b1), 64x128 tile, 4r x 8c per thread ----
__global__ __launch_bounds__(256) void k_gemm1(const float* __restrict__ AX,
    const float* __restrict__ W1, const float* __restrict__ b1,
    float* __restrict__ H1r) {
  __shared__ float Ws[F0 * F1];      // 32 KB, [64][32 float4-slots] swizzled
  __shared__ float Xs[64][F0 + 4];   // 17.4 KB, stride 68 -> clean broadcast
  const int tid = threadIdx.x;
  const int row0 = blockIdx.x * 64;
  float4* Wsf4 = reinterpret_cast<float4*>(Ws);
  for (int i = tid; i < F0 * F1 / 4; i += 256) {
    int k = i >> 5, s = i & 31;
    int p = s ^ (s >> 2);
    Wsf4[k * 32 + p] = reinterpret_cast<const float4*>(W1)[i];
  }
  for (int i = tid; i < 64 * 16; i += 256) {
    int r = i >> 4, c4 = i & 15;
    int n = row0 + r;
    float4 v = make_float4(0.f, 0.f, 0.f, 0.f);
    if (n < N) v = reinterpret_cast<const float4*>(AX)[n * 16 + c4];
    *reinterpret_cast<float4*>(&Xs[r][c4 * 4]) = v;
  }
  __syncthreads();
  const int cg = tid & 15, rg = tid >> 4;
  const int c0 = cg * 8;
  const int s0 = 2 * cg, s1 = 2 * cg + 1;
  const int p0 = s0 ^ (s0 >> 2), p1 = s1 ^ (s1 >> 2);
  float acc[4][8];
  #pragma unroll
  for (int i = 0; i < 4; ++i)
    #pragma unroll
    for (int j = 0; j < 8; ++j) acc[i][j] = 0.f;
  for (int k0 = 0; k0 < F0; k0 += 4) {
    float x0[4], x1[4], x2[4], x3[4];
    *reinterpret_cast<float4*>(x0) = *reinterpret_cast<const float4*>(&Xs[rg * 4 + 0][k0]);
    *reinterpret_cast<float4*>(x1) = *reinterpret_cast<const float4*>(&Xs[rg * 4 + 1][k0]);
    *reinterpret_cast<float4*>(x2) = *reinterpret_cast<const float4*>(&Xs[rg * 4 + 2][k0]);
    *reinterpret_cast<float4*>(x3) = *reinterpret_cast<const float4*>(&Xs[rg * 4 + 3][k0]);
    #pragma unroll
    for (int kk = 0; kk < 4; ++kk) {
      float w[8];
      *reinterpret_cast<float4*>(w)     = Wsf4[(k0 + kk) * 32 + p0];
      *reinterpret_cast<float4*>(w + 4) = Wsf4[(k0 + kk) * 32 + p1];
      #pragma unroll
      for (int j = 0; j < 8; ++j) {
        acc[0][j] = fmaf(x0[kk], w[j], acc[0][j]);
        acc[1][j] = fmaf(x1[kk], w[j], acc[1][j]);
        acc[2][j] = fmaf(x2[kk], w[j], acc[2][j]);
        acc[3][j] = fmaf(x3[kk], w[j], acc[3][j]);
      }
    }
  }
  float bb[8];
  *reinterpret_cast<float4*>(bb)     = *reinterpret_cast<const float4*>(&b1[c0]);
  *reinterpret_cast<float4*>(bb + 4) = *reinterpret_cast<const float4*>(&b1[c0 + 4]);
  #pragma unroll
  for (int i = 0; i < 4; ++i) {
    int n = row0 + rg * 4 + i;
    if (n < N) {
      float o[8];
      #pragma unroll
      for (int j = 0; j < 8; ++j) o[j] = fmaxf(acc[i][j] + bb[j], 0.f);
      *reinterpret_cast<float4*>(&H1r[(size_t)n * F1 + c0])     = *reinterpret_cast<float4*>(o);
      *reinterpret_cast<float4*>(&H1r[(size_t)n * F1 + c0 + 4]) = *reinterpret_cast<float4*>(o + 4);
    }
  }
}

// ---- GEMM2: H2s = (H1r @ W2) * dinv, 128-row tile, 2r x 8c per thread ----
__global__ __launch_bounds__(256) void k_gemm2(const float* __restrict__ H1r,
    const float* __restrict__ dinv, const float* __restrict__ W2,
    float* __restrict__ H2s) {
  __shared__ float Ws[F1 * F2];      // 16 KB
  const int tid = threadIdx.x;
  const int row0 = blockIdx.x * 128;
  float4* Wsf4 = reinterpret_cast<float4*>(Ws);
  for (int i = tid; i < F1 * F2 / 4; i += 256)
    Wsf4[i] = reinterpret_cast<const float4*>(W2)[i];
  __syncthreads();
  const int cg = tid & 3, rg = tid >> 2;           // cols cg*8.. ; rows rg*2..
  const int c0 = cg * 8;
  const int n0 = row0 + rg * 2, n1 = n0 + 1;
  const int na = (n0 < N) ? n0 : 0, nb = (n1 < N) ? n1 : 0;
  const float4* X0 = reinterpret_cast<const float4*>(H1r + (size_t)na * F1);
  const float4* X1 = reinterpret_cast<const float4*>(H1r + (size_t)nb * F1);
  float acc[2][8];
  #pragma unroll
  for (int i = 0; i < 2; ++i)
    #pragma unroll
    for (int j = 0; j < 8; ++j) acc[i][j] = 0.f;
  for (int k0 = 0; k0 < F1; k0 += 4) {
    float x0[4], x1[4];
    *reinterpret_cast<float4*>(x0) = X0[k0 >> 2];
    *reinterpret_cast<float4*>(x1) = X1[k0 >> 2];
    #pragma unroll
    for (int kk = 0; kk < 4; ++kk) {
      float w[8];
      *reinterpret_cast<float4*>(w)     = Wsf4[(k0 + kk) * 8 + cg * 2];
      *reinterpret_cast<float4*>(w + 4) = Wsf4[(k0 + kk) * 8 + cg * 2 + 1];
      #pragma unroll
      for (int j = 0; j < 8; ++j) {
        acc[0][j] = fmaf(x0[kk], w[j], acc[0][j]);
        acc[1][j] = fmaf(x1[kk], w[j], acc[1][j]);
      }
    }
  }
  #pragma unroll
  for (int i = 0; i < 2; ++i) {
    int n = n0 + i;
    if (n < N) {
      float d = dinv[n];
      float o[8];
      #pragma unroll
      for (int j = 0; j < 8; ++j) o[j] = acc[i][j] * d;
      *reinterpret_cast<float4*>(&H2s[(size_t)n * F2 + c0])     = *reinterpret_cast<float4*>(o);
      *reinterpret_cast<float4*>(&H2s[(size_t)n * F2 + c0 + 4]) = *reinterpret_cast<float4*>(o + 4);
    }
  }
}

// ---- fused layer-2 aggregation + bias + head (wide-gather form) ----
// h2[n] = dinv[n]*(H2s[n] + sum_s H2s[s]) + b2 ; out[n] = h2[n] @ Wc + bc
// Gather: 4x 16-lane groups, each lane float2 -> 4 edges per VMEM instruction.
__global__ __launch_bounds__(256) void k_agg2h(const int* __restrict__ rowend,
    const int* __restrict__ cnt, const int* __restrict__ ssrc,
    const float* __restrict__ H2s, const float* __restrict__ dinv,
    const float* __restrict__ b2, const float* __restrict__ Wc,
    const float* __restrict__ bc, float* __restrict__ h2,
    float* __restrict__ out) {
  __shared__ float Wcs[F2][F2];   // 4 KB
  __shared__ float h2row[4][F2];  // per-wave h2 row
  const int tid = threadIdx.x;
  for (int i = tid; i < F2 * F2; i += 256) Wcs[i >> 5][i & 31] = Wc[i];
  __syncthreads();
  int gw = (blockIdx.x * 256 + tid) >> 6;           // node (one wave each)
  int lane = tid & 63;
  int w = tid >> 6;                                 // wave slot in block
  if (gw >= N) return;
  int end   = __builtin_amdgcn_readfirstlane(rowend[gw]);
  int deg   = __builtin_amdgcn_readfirstlane(cnt[gw]);
  int start = end - deg;
  const int g = lane >> 4, fl = lane & 15;
  float ax = 0.f, ay = 0.f;
  for (int e0 = start; e0 < end; e0 += 16) {
    if (e0 + 16 <= end) {
      #pragma unroll
      for (int u = 0; u < 4; ++u) {
        int j0 = e0 + 4 * u;
        int s0 = ssrc[j0], s1 = ssrc[j0 + 1], s2 = ssrc[j0 + 2], s3 = ssrc[j0 + 3];
        int sA = (g & 1) ? s1 : s0;
        int sB = (g & 1) ? s3 : s2;
        int s  = (g & 2) ? sB : sA;
        float2 v = *reinterpret_cast<const float2*>(&H2s[(size_t)s * F2 + fl * 2]);
        ax += v.x; ay += v.y;
      }
    } else {
      #pragma unroll
      for (int u = 0; u < 4; ++u) {
        int j0 = e0 + 4 * u, j1 = j0 + 1, j2 = j0 + 2, j3 = j0 + 3;
        int s0 = ssrc[(j0 < end) ? j0 : start];
        int s1 = ssrc[(j1 < end) ? j1 : start];
        int s2 = ssrc[(j2 < end) ? j2 : start];
        int s3 = ssrc[(j3 < end) ? j3 : start];
        float m0 = (j0 < end) ? 1.f : 0.f, m1 = (j1 < end) ? 1.f : 0.f;
        float m2 = (j2 < end) ? 1.f : 0.f, m3 = (j3 < end) ? 1.f : 0.f;
        int sA = (g & 1) ? s1 : s0;
        int sB = (g & 1) ? s3 : s2;
        int s  = (g & 2) ? sB : sA;
        float mA = (g & 1) ? m1 : m0;
        float mB = (g & 1) ? m3 : m2;
        float mm = (g & 2) ? mB : mA;
        float2 v = *reinterpret_cast<const float2*>(&H2s[(size_t)s * F2 + fl * 2]);
        ax = fmaf(v.x, mm, ax); ay = fmaf(v.y, mm, ay);
      }
    }
  }
  ax += __shfl_xor(ax, 16); ay += __shfl_xor(ay, 16);
  ax += __shfl_xor(ax, 32); ay += __shfl_xor(ay, 32);
  float dv = dinv[gw];
  if (lane < 16) {
    float2 self = *reinterpret_cast<const float2*>(&H2s[(size_t)gw * F2 + fl * 2]);
    float hx = dv * (ax + self.x) + b2[2 * fl];
    float hy = dv * (ay + self.y) + b2[2 * fl + 1];
    float2 hv; hv.x = hx; hv.y = hy;
    *reinterpret_cast<float2*>(&h2[(size_t)gw * F2 + fl * 2]) = hv;
    h2row[w][2 * fl]     = hx;
    h2row[w][2 * fl + 1] = hy;
  }
  // head (within-wave LDS visibility; no block barrier needed)
  int f = lane & 31, half = lane >> 5;
  float acco = 0.f;
  #pragma unroll
  for (int kk = 0; kk < 16; ++kk) {
    int k = kk + 16 * half;
    acco = fmaf(h2row[w][k], Wcs[k][f], acco);
  }
  acco += __shfl_xor(acco, 32);
  if (half == 0) out[(size_t)gw * F2 + f] = acco + bc[f];
}

extern "C" void kernel_launch(void* const* d_in, const int* in_sizes, int n_in,
                              void* d_out, int out_size, void* d_ws, size_t ws_size,
                              hipStream_t stream) {
  const float* x  = (const float*)d_in[0];
  const int*   ei = (const int*)d_in[1];
  const int*   src = ei;                 // edge_index[0]
  const int*   dst = ei + E;             // edge_index[1]
  const float* W1 = (const float*)d_in[2];
  const float* b1 = (const float*)d_in[3];
  const float* W2 = (const float*)d_in[4];
  const float* b2 = (const float*)d_in[5];
  const float* Wc = (const float*)d_in[6];
  const float* bc = (const float*)d_in[7];

  float* out = (float*)d_out;                    // [N, 32] logits
  float* h2  = out + (size_t)N * F2;             // [N, 32] hidden output

  // workspace layout (~66 MB of 256 MB) — all disjoint, no aliasing
  int*   cnt        = (int*)d_ws;                // N
  int*   rowend     = cnt + N;                   // N
  int*   bucketTot  = rowend + N;                // NBUK (pad to 512)
  float* dinv       = (float*)(bucketTot + 512); // N
  int*   ssrc       = (int*)(dinv + N);          // E
  unsigned int* ebuf = (unsigned int*)(ssrc + E);// E
  int*   hist       = (int*)(ebuf + E);          // NBUK*NCHUNK (bucket-major)
  float* xs         = (float*)(hist + NBUK * NCHUNK + 64); // N*64
  float* AX         = xs + (size_t)N * F0;       // N*64
  float* H1r        = AX + (size_t)N * F0;       // N*128
  float* H2s        = H1r + (size_t)N * F1;      // N*32

  k_hist  <<<NCHUNK, 512, 0, stream>>>(dst, hist);
  k_scanbk<<<NBUK,   256, 0, stream>>>(hist, bucketTot);
  k_bucket<<<NCHUNK, 512, 0, stream>>>(src, dst, hist, bucketTot, ebuf);
  k_csr   <<<NBUK,   512, 0, stream>>>(ebuf, bucketTot, x, cnt, rowend, dinv, ssrc, xs);

  k_agg1 <<<(N + 3) / 4, 256, 0, stream>>>(rowend, cnt, ssrc, xs, dinv, AX);
  k_gemm1<<<(N + 63) / 64, 256, 0, stream>>>(AX, W1, b1, H1r);
  k_gemm2<<<(N + 127) / 128, 256, 0, stream>>>(H1r, dinv, W2, H2s);
  k_agg2h<<<(N + 3) / 4, 256, 0, stream>>>(rowend, cnt, ssrc, H2s, dinv, b2, Wc, bc, h2, out);
}

// Round 12
// 124.967 us; speedup vs baseline: 1.2318x; 1.0791x over previous
//
#include <hip/hip_runtime.h>

// GCN forward: two GCNConv layers + linear head.
// Round 12: bf16 gather arrays. xs and H2s stored as bf16 (halves the
// L2/L3 gather traffic that pinned rounds 6-11 at ~135us); all GEMM inputs,
// accumulation, and outputs stay f32. agg1: 8 edges/VMEM-instr (8 lanes/row);
// agg2h: 16 edges/VMEM-instr (4 lanes/row).
// 8 dispatches:
//   k_hist -> k_scanbk -> k_bucket -> k_csr(+dinv+bf16 prescale) ->
//   k_agg1 -> k_gemm1 -> k_gemm2(bf16 store) -> k_agg2h
// out = dinv[d] * sum_{s in N(d)+self} (dinv[s]*h[s]) per layer.

static constexpr int N  = 50000;
static constexpr int E  = 800000;
static constexpr int F0 = 64;    // input feats
static constexpr int F1 = 128;   // hidden
static constexpr int F2 = 32;    // classes

static constexpr int BSH    = 7;     // bucket = dst>>7 (128 nodes)
static constexpr int BNODES = 128;
static constexpr int BMASK  = 127;
static constexpr int NBUK   = 392;   // ceil(N/128)
static constexpr int CHUNK  = 4096;  // edges per histogram chunk
static constexpr int NCHUNK = 196;   // ceil(E/CHUNK)

__device__ __forceinline__ unsigned int f2bf(float f) {
  unsigned int u = __float_as_uint(f);
  return (u + 0x7fffu + ((u >> 16) & 1u)) >> 16;     // RNE
}
__device__ __forceinline__ float bflo(unsigned int u) {
  return __uint_as_float(u << 16);
}
__device__ __forceinline__ float bfhi(unsigned int u) {
  return __uint_as_float(u & 0xffff0000u);
}

// ---- B1: per-chunk LDS histogram over dst buckets (bucket-major out) ----
__global__ __launch_bounds__(512) void k_hist(const int* __restrict__ dst,
                                              int* __restrict__ hist) {
  __shared__ int hl[NBUK];
  int tid = threadIdx.x, c = blockIdx.x;
  for (int t = tid; t < NBUK; t += 512) hl[t] = 0;
  __syncthreads();
  int e0 = c * CHUNK, m = min(CHUNK, E - e0);
  for (int i = tid; i < m; i += 512)
    atomicAdd(&hl[dst[e0 + i] >> BSH], 1);
  __syncthreads();
  for (int t = tid; t < NBUK; t += 512) hist[t * NCHUNK + c] = hl[t];
}

// ---- S1: per-bucket exclusive scan over chunks (in place); bucket totals out ----
__global__ __launch_bounds__(256) void k_scanbk(int* __restrict__ hist,
                                                int* __restrict__ bucketTot) {
  __shared__ int s[256];
  int t = threadIdx.x, b = blockIdx.x;
  int v = (t < NCHUNK) ? hist[b * NCHUNK + t] : 0;
  s[t] = v; __syncthreads();
  for (int off = 1; off < 256; off <<= 1) {
    int u = (t >= off) ? s[t - off] : 0;
    __syncthreads(); s[t] += u; __syncthreads();
  }
  if (t < NCHUNK) hist[b * NCHUNK + t] = s[t] - v;
  if (t == 255) bucketTot[b] = s[255];
}

// ---- B2: scatter edges into bucket-grouped order (packed (dlocal<<16)|src) ----
__global__ __launch_bounds__(512) void k_bucket(const int* __restrict__ src,
    const int* __restrict__ dst, const int* __restrict__ hist,
    const int* __restrict__ bucketTot, unsigned int* __restrict__ ebuf) {
  __shared__ int tl[512], sl[512], startL[NBUK];
  int t = threadIdx.x, c = blockIdx.x;
  int v = (t < NBUK) ? bucketTot[t] : 0;
  tl[t] = v; sl[t] = v; __syncthreads();
  for (int off = 1; off < 512; off <<= 1) {
    int u = (t >= off) ? sl[t - off] : 0;
    __syncthreads(); sl[t] += u; __syncthreads();
  }
  for (int i = t; i < NBUK; i += 512)
    startL[i] = (sl[i] - tl[i]) + hist[i * NCHUNK + c];
  __syncthreads();
  int e0 = c * CHUNK, m = min(CHUNK, E - e0);
  for (int i = t; i < m; i += 512) {
    int e = e0 + i;
    int d = dst[e], s = src[e];
    int pos = atomicAdd(&startL[d >> BSH], 1);         // LDS atomic
    ebuf[pos] = (unsigned int)s | ((unsigned int)(d & BMASK) << 16);
  }
}

// ---- B3: per-bucket CSR finalize + dinv + bf16 xs prescale ----
__global__ __launch_bounds__(512) void k_csr(const unsigned int* __restrict__ ebuf,
    const int* __restrict__ bucketTot, const float* __restrict__ x,
    int* __restrict__ cnt, int* __restrict__ rowend, float* __restrict__ dinv,
    int* __restrict__ ssrc, unsigned short* __restrict__ xs16) {
  __shared__ int tl[512], sl[512], cl[BNODES], sc[BNODES], cur[BNODES];
  __shared__ float dl[BNODES];
  int t = threadIdx.x, b = blockIdx.x;
  int v0 = (t < NBUK) ? bucketTot[t] : 0;
  tl[t] = v0; sl[t] = v0; __syncthreads();
  for (int off = 1; off < 512; off <<= 1) {
    int u = (t >= off) ? sl[t - off] : 0;
    __syncthreads(); sl[t] += u; __syncthreads();
  }
  int base = sl[b] - tl[b];
  int m    = tl[b];
  int node0 = b << BSH;
  if (t < BNODES) cl[t] = 0;
  __syncthreads();
  for (int i = t; i < m; i += 512)
    atomicAdd(&cl[(ebuf[base + i] >> 16) & BMASK], 1);
  __syncthreads();
  int v = 0;
  if (t < BNODES) { v = cl[t]; sc[t] = v; }
  __syncthreads();
  for (int off = 1; off < BNODES; off <<= 1) {
    int u = (t >= off && t < BNODES) ? sc[t - off] : 0;
    __syncthreads();
    if (t < BNODES) sc[t] += u;
    __syncthreads();
  }
  if (t < BNODES) {
    int excl = sc[t] - v;
    cur[t] = excl;
    float dv = rsqrtf((float)(v + 1));                // +1 self-loop
    dl[t] = dv;
    int g = node0 + t;
    if (g < N) {
      cnt[g]    = v;
      rowend[g] = base + excl + v;
      dinv[g]   = dv;
    }
  }
  __syncthreads();
  for (int i = t; i < m; i += 512) {
    unsigned int p = ebuf[base + i];
    int d = (p >> 16) & BMASK;
    int r = atomicAdd(&cur[d], 1);                     // LDS atomic
    ssrc[base + r] = (int)(p & 0xFFFFu);
  }
  // fused prescale: xs16[n] = bf16(x[n] * dinv[n]); 8 feats per iteration
  for (int i = t; i < BNODES * (F0 / 8); i += 512) {
    int nl = i >> 3, oc = i & 7;                       // node-local, feat octet
    int n = node0 + nl;
    if (n < N) {
      float4 a = reinterpret_cast<const float4*>(x)[n * 16 + oc * 2];
      float4 b2_ = reinterpret_cast<const float4*>(x)[n * 16 + oc * 2 + 1];
      float d = dl[nl];
      uint4 pk;
      pk.x = f2bf(a.x * d)   | (f2bf(a.y * d) << 16);
      pk.y = f2bf(a.z * d)   | (f2bf(a.w * d) << 16);
      pk.z = f2bf(b2_.x * d) | (f2bf(b2_.y * d) << 16);
      pk.w = f2bf(b2_.z * d) | (f2bf(b2_.w * d) << 16);
      reinterpret_cast<uint4*>(xs16)[(size_t)n * 8 + oc] = pk;
    }
  }
}

// ---- layer-1 aggregation (bf16 gathers): AX[n] = dinv[n]*(xs[n] + sum xs[s]) ----
// 8 lanes per 128B row -> 8 edges per VMEM instruction; 16 edges per step.
__global__ __launch_bounds__(256) void k_agg1(const int* __restrict__ rowend,
    const int* __restrict__ cnt, const int* __restrict__ ssrc,
    const unsigned short* __restrict__ xs16, const float* __restrict__ dinv,
    float* __restrict__ AX) {
  int gw = (blockIdx.x * 256 + threadIdx.x) >> 6;   // node (one wave each)
  int lane = threadIdx.x & 63;
  if (gw >= N) return;
  int end   = __builtin_amdgcn_readfirstlane(rowend[gw]);
  int deg   = __builtin_amdgcn_readfirstlane(cnt[gw]);
  int start = end - deg;
  const int g = lane >> 3, fl = lane & 7;           // edge slot, feat octet
  const uint4* xsv = reinterpret_cast<const uint4*>(xs16);
  float acc[8];
  #pragma unroll
  for (int k = 0; k < 8; ++k) acc[k] = 0.f;
  for (int e0 = start; e0 < end; e0 += 16) {
    if (e0 + 16 <= end) {
      int s0 = ssrc[e0 + g];
      int s1 = ssrc[e0 + 8 + g];
      uint4 u0 = xsv[(size_t)s0 * 8 + fl];
      uint4 u1 = xsv[(size_t)s1 * 8 + fl];
      acc[0] += bflo(u0.x); acc[1] += bfhi(u0.x);
      acc[2] += bflo(u0.y); acc[3] += bfhi(u0.y);
      acc[4] += bflo(u0.z); acc[5] += bfhi(u0.z);
      acc[6] += bflo(u0.w); acc[7] += bfhi(u0.w);
      acc[0] += bflo(u1.x); acc[1] += bfhi(u1.x);
      acc[2] += bflo(u1.y); acc[3] += bfhi(u1.y);
      acc[4] += bflo(u1.z); acc[5] += bfhi(u1.z);
      acc[6] += bflo(u1.w); acc[7] += bfhi(u1.w);
    } else {
      int j0 = e0 + g, j1 = e0 + 8 + g;
      int s0 = ssrc[(j0 < end) ? j0 : start];
      int s1 = ssrc[(j1 < end) ? j1 : start];
      float m0 = (j0 < end) ? 1.f : 0.f;
      float m1 = (j1 < end) ? 1.f : 0.f;
      uint4 u0 = xsv[(size_t)s0 * 8 + fl];
      uint4 u1 = xsv[(size_t)s1 * 8 + fl];
      acc[0] = fmaf(bflo(u0.x), m0, acc[0]); acc[1] = fmaf(bfhi(u0.x), m0, acc[1]);
      acc[2] = fmaf(bflo(u0.y), m0, acc[2]); acc[3] = fmaf(bfhi(u0.y), m0, acc[3]);
      acc[4] = fmaf(bflo(u0.z), m0, acc[4]); acc[5] = fmaf(bfhi(u0.z), m0, acc[5]);
      acc[6] = fmaf(bflo(u0.w), m0, acc[6]); acc[7] = fmaf(bfhi(u0.w), m0, acc[7]);
      acc[0] = fmaf(bflo(u1.x), m1, acc[0]); acc[1] = fmaf(bfhi(u1.x), m1, acc[1]);
      acc[2] = fmaf(bflo(u1.y), m1, acc[2]); acc[3] = fmaf(bfhi(u1.y), m1, acc[3]);
      acc[4] = fmaf(bflo(u1.z), m1, acc[4]); acc[5] = fmaf(bfhi(u1.z), m1, acc[5]);
      acc[6] = fmaf(bflo(u1.w), m1, acc[6]); acc[7] = fmaf(bfhi(u1.w), m1, acc[7]);
    }
  }
  // combine the 8 groups (butterfly over lane bits 3..5)
  #pragma unroll
  for (int r = 8; r < 64; r <<= 1) {
    #pragma unroll
    for (int k = 0; k < 8; ++k) acc[k] += __shfl_xor(acc[k], r);
  }
  if (lane < 8) {
    uint4 su = xsv[(size_t)gw * 8 + fl];
    float dv = dinv[gw];
    float o[8];
    o[0] = (acc[0] + bflo(su.x)) * dv; o[1] = (acc[1] + bfhi(su.x)) * dv;
    o[2] = (acc[2] + bflo(su.y)) * dv; o[3] = (acc[3] + bfhi(su.y)) * dv;
    o[4] = (acc[4] + bflo(su.z)) * dv; o[5] = (acc[5] + bfhi(su.z)) * dv;
    o[6] = (acc[6] + bflo(su.w)) * dv; o[7] = (acc[7] + bfhi(su.w)) * dv;
    *reinterpret_cast<float4*>(&AX[(size_t)gw * F0 + fl * 8])     = *reinterpret_cast<float4*>(o);
    *reinterpret_cast<float4*>(&AX[(size_t)gw * F0 + fl * 8 + 4]) = *reinterpret_cast<float4*>(o + 4);
  }
}

// ---- GEMM1: H1r = relu(AX @ W1 + b1), 64x128 tile, 4r x 8c per thread ----
__global__ __launch_bounds__(256) void k_gemm1(const float* __restrict__ AX,
    const float* __restrict__ W1, const float* __restrict__ b1,
    float* __restrict__ H1r) {
  __shared__ float Ws[F0 * F1];      // 32 KB, [64][32 float4-slots] swizzled
  __shared__ float Xs[64][F0 + 4];   // 17.4 KB, stride 68 -> clean broadcast
  const int tid = threadIdx.x;
  const int row0 = blockIdx.x * 64;
  float4* Wsf4 = reinterpret_cast<float4*>(Ws);
  for (int i = tid; i < F0 * F1 / 4; i += 256) {
    int k = i >> 5, s = i & 31;
    int p = s ^ (s >> 2);
    Wsf4[k * 32 + p] = reinterpret_cast<const float4*>(W1)[i];
  }
  for (int i = tid; i < 64 * 16; i += 256) {
    int r = i >> 4, c4 = i & 15;
    int n = row0 + r;
    float4 v = make_float4(0.f, 0.f, 0.f, 0.f);
    if (n < N) v = reinterpret_cast<const float4*>(AX)[n * 16 + c4];
    *reinterpret_cast<float4*>(&Xs[r][c4 * 4]) = v;
  }
  __syncthreads();
  const int cg = tid & 15, rg = tid >> 4;
  const int c0 = cg * 8;
  const int s0 = 2 * cg, s1 = 2 * cg + 1;
  const int p0 = s0 ^ (s0 >> 2), p1 = s1 ^ (s1 >> 2);
  float acc[4][8];
  #pragma unroll
  for (int i = 0; i < 4; ++i)
    #pragma unroll
    for (int j = 0; j < 8; ++j) acc[i][j] = 0.f;
  for (int k0 = 0; k0 < F0; k0 += 4) {
    float x0[4], x1[4], x2[4], x3[4];
    *reinterpret_cast<float4*>(x0) = *reinterpret_cast<const float4*>(&Xs[rg * 4 + 0][k0]);
    *reinterpret_cast<float4*>(x1) = *reinterpret_cast<const float4*>(&Xs[rg * 4 + 1][k0]);
    *reinterpret_cast<float4*>(x2) = *reinterpret_cast<const float4*>(&Xs[rg * 4 + 2][k0]);
    *reinterpret_cast<float4*>(x3) = *reinterpret_cast<const float4*>(&Xs[rg * 4 + 3][k0]);
    #pragma unroll
    for (int kk = 0; kk < 4; ++kk) {
      float w[8];
      *reinterpret_cast<float4*>(w)     = Wsf4[(k0 + kk) * 32 + p0];
      *reinterpret_cast<float4*>(w + 4) = Wsf4[(k0 + kk) * 32 + p1];
      #pragma unroll
      for (int j = 0; j < 8; ++j) {
        acc[0][j] = fmaf(x0[kk], w[j], acc[0][j]);
        acc[1][j] = fmaf(x1[kk], w[j], acc[1][j]);
        acc[2][j] = fmaf(x2[kk], w[j], acc[2][j]);
        acc[3][j] = fmaf(x3[kk], w[j], acc[3][j]);
      }
    }
  }
  float bb[8];
  *reinterpret_cast<float4*>(bb)     = *reinterpret_cast<const float4*>(&b1[c0]);
  *reinterpret_cast<float4*>(bb + 4) = *reinterpret_cast<const float4*>(&b1[c0 + 4]);
  #pragma unroll
  for (int i = 0; i < 4; ++i) {
    int n = row0 + rg * 4 + i;
    if (n < N) {
      float o[8];
      #pragma unroll
      for (int j = 0; j < 8; ++j) o[j] = fmaxf(acc[i][j] + bb[j], 0.f);
      *reinterpret_cast<float4*>(&H1r[(size_t)n * F1 + c0])     = *reinterpret_cast<float4*>(o);
      *reinterpret_cast<float4*>(&H1r[(size_t)n * F1 + c0 + 4]) = *reinterpret_cast<float4*>(o + 4);
    }
  }
}

// ---- GEMM2: H2s16 = bf16((H1r @ W2) * dinv), 128-row tile, 2r x 8c/thread ----
__global__ __launch_bounds__(256) void k_gemm2(const float* __restrict__ H1r,
    const float* __restrict__ dinv, const float* __restrict__ W2,
    unsigned short* __restrict__ H2s16) {
  __shared__ float Ws[F1 * F2];      // 16 KB
  const int tid = threadIdx.x;
  const int row0 = blockIdx.x * 128;
  float4* Wsf4 = reinterpret_cast<float4*>(Ws);
  for (int i = tid; i < F1 * F2 / 4; i += 256)
    Wsf4[i] = reinterpret_cast<const float4*>(W2)[i];
  __syncthreads();
  const int cg = tid & 3, rg = tid >> 2;           // cols cg*8.. ; rows rg*2..
  const int c0 = cg * 8;
  const int n0 = row0 + rg * 2, n1 = n0 + 1;
  const int na = (n0 < N) ? n0 : 0, nb = (n1 < N) ? n1 : 0;
  const float4* X0 = reinterpret_cast<const float4*>(H1r + (size_t)na * F1);
  const float4* X1 = reinterpret_cast<const float4*>(H1r + (size_t)nb * F1);
  float acc[2][8];
  #pragma unroll
  for (int i = 0; i < 2; ++i)
    #pragma unroll
    for (int j = 0; j < 8; ++j) acc[i][j] = 0.f;
  for (int k0 = 0; k0 < F1; k0 += 4) {
    float x0[4], x1[4];
    *reinterpret_cast<float4*>(x0) = X0[k0 >> 2];
    *reinterpret_cast<float4*>(x1) = X1[k0 >> 2];
    #pragma unroll
    for (int kk = 0; kk < 4; ++kk) {
      float w[8];
      *reinterpret_cast<float4*>(w)     = Wsf4[(k0 + kk) * 8 + cg * 2];
      *reinterpret_cast<float4*>(w + 4) = Wsf4[(k0 + kk) * 8 + cg * 2 + 1];
      #pragma unroll
      for (int j = 0; j < 8; ++j) {
        acc[0][j] = fmaf(x0[kk], w[j], acc[0][j]);
        acc[1][j] = fmaf(x1[kk], w[j], acc[1][j]);
      }
    }
  }
  #pragma unroll
  for (int i = 0; i < 2; ++i) {
    int n = n0 + i;
    if (n < N) {
      float d = dinv[n];
      uint4 pk;
      pk.x = f2bf(acc[i][0] * d) | (f2bf(acc[i][1] * d) << 16);
      pk.y = f2bf(acc[i][2] * d) | (f2bf(acc[i][3] * d) << 16);
      pk.z = f2bf(acc[i][4] * d) | (f2bf(acc[i][5] * d) << 16);
      pk.w = f2bf(acc[i][6] * d) | (f2bf(acc[i][7] * d) << 16);
      reinterpret_cast<uint4*>(H2s16)[(size_t)n * 4 + (c0 >> 3)] = pk;
    }
  }
}

// ---- fused layer-2 aggregation + bias + head (bf16 gathers) ----
// 4 lanes per 64B row -> 16 edges per VMEM instruction.
__global__ __launch_bounds__(256) void k_agg2h(const int* __restrict__ rowend,
    const int* __restrict__ cnt, const int* __restrict__ ssrc,
    const unsigned short* __restrict__ H2s16, const float* __restrict__ dinv,
    const float* __restrict__ b2, const float* __restrict__ Wc,
    const float* __restrict__ bc, float* __restrict__ h2,
    float* __restrict__ out) {
  __shared__ float Wcs[F2][F2];   // 4 KB
  __shared__ float h2row[4][F2];  // per-wave h2 row
  const int tid = threadIdx.x;
  for (int i = tid; i < F2 * F2; i += 256) Wcs[i >> 5][i & 31] = Wc[i];
  __syncthreads();
  int gw = (blockIdx.x * 256 + tid) >> 6;           // node (one wave each)
  int lane = tid & 63;
  int w = tid >> 6;                                 // wave slot in block
  if (gw >= N) return;
  int end   = __builtin_amdgcn_readfirstlane(rowend[gw]);
  int deg   = __builtin_amdgcn_readfirstlane(cnt[gw]);
  int start = end - deg;
  const int g = lane >> 2, fl = lane & 3;           // edge slot (16), feat octet
  const uint4* hv = reinterpret_cast<const uint4*>(H2s16);
  float acc[8];
  #pragma unroll
  for (int k = 0; k < 8; ++k) acc[k] = 0.f;
  for (int e0 = start; e0 < end; e0 += 16) {
    if (e0 + 16 <= end) {
      int s = ssrc[e0 + g];
      uint4 u = hv[(size_t)s * 4 + fl];
      acc[0] += bflo(u.x); acc[1] += bfhi(u.x);
      acc[2] += bflo(u.y); acc[3] += bfhi(u.y);
      acc[4] += bflo(u.z); acc[5] += bfhi(u.z);
      acc[6] += bflo(u.w); acc[7] += bfhi(u.w);
    } else {
      int j = e0 + g;
      int s = ssrc[(j < end) ? j : start];
      float mm = (j < end) ? 1.f : 0.f;
      uint4 u = hv[(size_t)s * 4 + fl];
      acc[0] = fmaf(bflo(u.x), mm, acc[0]); acc[1] = fmaf(bfhi(u.x), mm, acc[1]);
      acc[2] = fmaf(bflo(u.y), mm, acc[2]); acc[3] = fmaf(bfhi(u.y), mm, acc[3]);
      acc[4] = fmaf(bflo(u.z), mm, acc[4]); acc[5] = fmaf(bfhi(u.z), mm, acc[5]);
      acc[6] = fmaf(bflo(u.w), mm, acc[6]); acc[7] = fmaf(bfhi(u.w), mm, acc[7]);
    }
  }
  // combine the 16 groups (butterfly over lane bits 2..5)
  #pragma unroll
  for (int r = 4; r < 64; r <<= 1) {
    #pragma unroll
    for (int k = 0; k < 8; ++k) acc[k] += __shfl_xor(acc[k], r);
  }
  float dv = dinv[gw];
  if (lane < 4) {
    uint4 su = hv[(size_t)gw * 4 + fl];
    float o[8];
    o[0] = dv * (acc[0] + bflo(su.x)) + b2[fl * 8 + 0];
    o[1] = dv * (acc[1] + bfhi(su.x)) + b2[fl * 8 + 1];
    o[2] = dv * (acc[2] + bflo(su.y)) + b2[fl * 8 + 2];
    o[3] = dv * (acc[3] + bfhi(su.y)) + b2[fl * 8 + 3];
    o[4] = dv * (acc[4] + bflo(su.z)) + b2[fl * 8 + 4];
    o[5] = dv * (acc[5] + bfhi(su.z)) + b2[fl * 8 + 5];
    o[6] = dv * (acc[6] + bflo(su.w)) + b2[fl * 8 + 6];
    o[7] = dv * (acc[7] + bfhi(su.w)) + b2[fl * 8 + 7];
    *reinterpret_cast<float4*>(&h2[(size_t)gw * F2 + fl * 8])     = *reinterpret_cast<float4*>(o);
    *reinterpret_cast<float4*>(&h2[(size_t)gw * F2 + fl * 8 + 4]) = *reinterpret_cast<float4*>(o + 4);
    #pragma unroll
    for (int k = 0; k < 8; ++k) h2row[w][fl * 8 + k] = o[k];
  }
  // head (within-wave LDS visibility; no block barrier needed)
  int f = lane & 31, half = lane >> 5;
  float acco = 0.f;
  #pragma unroll
  for (int kk = 0; kk < 16; ++kk) {
    int k = kk + 16 * half;
    acco = fmaf(h2row[w][k], Wcs[k][f], acco);
  }
  acco += __shfl_xor(acco, 32);
  if (half == 0) out[(size_t)gw * F2 + f] = acco + bc[f];
}

extern "C" void kernel_launch(void* const* d_in, const int* in_sizes, int n_in,
                              void* d_out, int out_size, void* d_ws, size_t ws_size,
                              hipStream_t stream) {
  const float* x  = (const float*)d_in[0];
  const int*   ei = (const int*)d_in[1];
  const int*   src = ei;                 // edge_index[0]
  const int*   dst = ei + E;             // edge_index[1]
  const float* W1 = (const float*)d_in[2];
  const float* b1 = (const float*)d_in[3];
  const float* W2 = (const float*)d_in[4];
  const float* b2 = (const float*)d_in[5];
  const float* Wc = (const float*)d_in[6];
  const float* bc = (const float*)d_in[7];

  float* out = (float*)d_out;                    // [N, 32] logits
  float* h2  = out + (size_t)N * F2;             // [N, 32] hidden output

  // workspace layout (~60 MB of 256 MB) — all disjoint, no aliasing
  int*   cnt        = (int*)d_ws;                // N
  int*   rowend     = cnt + N;                   // N
  int*   bucketTot  = rowend + N;                // NBUK (pad to 512)
  float* dinv       = (float*)(bucketTot + 512); // N
  int*   ssrc       = (int*)(dinv + N);          // E
  unsigned int* ebuf = (unsigned int*)(ssrc + E);// E
  int*   hist       = (int*)(ebuf + E);          // NBUK*NCHUNK (bucket-major)
  unsigned short* xs16  = (unsigned short*)(hist + NBUK * NCHUNK + 64); // N*64 bf16
  float* AX         = (float*)(xs16 + (size_t)N * F0);  // N*64 f32
  float* H1r        = AX + (size_t)N * F0;              // N*128 f32
  unsigned short* H2s16 = (unsigned short*)(H1r + (size_t)N * F1); // N*32 bf16

  k_hist  <<<NCHUNK, 512, 0, stream>>>(dst, hist);
  k_scanbk<<<NBUK,   256, 0, stream>>>(hist, bucketTot);
  k_bucket<<<NCHUNK, 512, 0, stream>>>(src, dst, hist, bucketTot, ebuf);
  k_csr   <<<NBUK,   512, 0, stream>>>(ebuf, bucketTot, x, cnt, rowend, dinv, ssrc, xs16);

  k_agg1 <<<(N + 3) / 4, 256, 0, stream>>>(rowend, cnt, ssrc, xs16, dinv, AX);
  k_gemm1<<<(N + 63) / 64, 256, 0, stream>>>(AX, W1, b1, H1r);
  k_gemm2<<<(N + 127) / 128, 256, 0, stream>>>(H1r, dinv, W2, H2s16);
  k_agg2h<<<(N + 3) / 4, 256, 0, stream>>>(rowend, cnt, ssrc, H2s16, dinv, b2, Wc, bc, h2, out);
}

// Round 13
// 118.386 us; speedup vs baseline: 1.3003x; 1.0556x over previous
//
#include <hip/hip_runtime.h>

// GCN forward: two GCNConv layers + linear head.
// Round 13: (a) CSR build via fixed-capacity buckets (BCAP=3072): no hist
// matrix, no scan kernels — k_bucket self-reserves with line-padded global
// atomics; bucket bases are constants. (b) gemm1+gemm2 fused (3rd attempt:
// proven 256-thread phase-A geometry + register-tiled phase B over LDS
// overlay). bf16 gather arrays (xs16, H2s16) as in R12.
// 6 dispatches:
//   memset(gcur) -> k_bucket -> k_csr(+dinv+bf16 prescale) ->
//   k_agg1 -> k_gemm12 -> k_agg2h
// out = dinv[d] * sum_{s in N(d)+self} (dinv[s]*h[s]) per layer.

static constexpr int N  = 50000;
static constexpr int E  = 800000;
static constexpr int F0 = 64;    // input feats
static constexpr int F1 = 128;   // hidden
static constexpr int F2 = 32;    // classes

static constexpr int BSH    = 7;     // bucket = dst>>7 (128 nodes)
static constexpr int BNODES = 128;
static constexpr int BMASK  = 127;
static constexpr int NBUK   = 392;   // ceil(N/128)
static constexpr int BCAP   = 3072;  // per-bucket capacity (mean 2048 + 22 sigma)
static constexpr int CHUNK  = 4096;  // edges per chunk
static constexpr int NCHUNK = 196;   // ceil(E/CHUNK)

__device__ __forceinline__ unsigned int f2bf(float f) {
  unsigned int u = __float_as_uint(f);
  return (u + 0x7fffu + ((u >> 16) & 1u)) >> 16;     // RNE
}
__device__ __forceinline__ float bflo(unsigned int u) {
  return __uint_as_float(u << 16);
}
__device__ __forceinline__ float bfhi(unsigned int u) {
  return __uint_as_float(u & 0xffff0000u);
}

// ---- B1: bucket-scatter with per-chunk LDS count + global reservation ----
// gcur[b*16] is a line-padded cursor per bucket (memset to 0 before launch).
__global__ __launch_bounds__(512) void k_bucket(const int* __restrict__ src,
    const int* __restrict__ dst, int* __restrict__ gcur,
    unsigned int* __restrict__ ebuf) {
  __shared__ int hl[NBUK];
  int t = threadIdx.x, c = blockIdx.x;
  for (int i = t; i < NBUK; i += 512) hl[i] = 0;
  __syncthreads();
  int e0 = c * CHUNK, m = min(CHUNK, E - e0);
  for (int i = t; i < m; i += 512)
    atomicAdd(&hl[dst[e0 + i] >> BSH], 1);
  __syncthreads();
  for (int i = t; i < NBUK; i += 512) {
    int cc = hl[i];
    int rbase = (cc > 0) ? atomicAdd(&gcur[i * 16], cc) : 0;
    hl[i] = i * BCAP + rbase;                        // LDS cursor for pass 2
  }
  __syncthreads();
  for (int i = t; i < m; i += 512) {
    int e = e0 + i;
    int d = dst[e], s = src[e];
    int pos = atomicAdd(&hl[d >> BSH], 1);           // LDS atomic
    ebuf[pos] = (unsigned int)s | ((unsigned int)(d & BMASK) << 16);
  }
}

// ---- B2: per-bucket CSR finalize + dinv + bf16 xs prescale ----
__global__ __launch_bounds__(512) void k_csr(const unsigned int* __restrict__ ebuf,
    const int* __restrict__ gcur, const float* __restrict__ x,
    int* __restrict__ cnt, int* __restrict__ rowend, float* __restrict__ dinv,
    int* __restrict__ ssrc, unsigned short* __restrict__ xs16) {
  __shared__ int cl[BNODES], sc[BNODES], cur[BNODES];
  __shared__ float dl[BNODES];
  int t = threadIdx.x, b = blockIdx.x;
  int base = b * BCAP;
  int m    = gcur[b * 16];                           // bucket total
  int node0 = b << BSH;
  if (t < BNODES) cl[t] = 0;
  __syncthreads();
  for (int i = t; i < m; i += 512)
    atomicAdd(&cl[(ebuf[base + i] >> 16) & BMASK], 1);
  __syncthreads();
  int v = 0;
  if (t < BNODES) { v = cl[t]; sc[t] = v; }
  __syncthreads();
  for (int off = 1; off < BNODES; off <<= 1) {
    int u = (t >= off && t < BNODES) ? sc[t - off] : 0;
    __syncthreads();
    if (t < BNODES) sc[t] += u;
    __syncthreads();
  }
  if (t < BNODES) {
    int excl = sc[t] - v;
    cur[t] = excl;
    float dv = rsqrtf((float)(v + 1));               // +1 self-loop
    dl[t] = dv;
    int g = node0 + t;
    if (g < N) {
      cnt[g]    = v;
      rowend[g] = base + excl + v;
      dinv[g]   = dv;
    }
  }
  __syncthreads();
  for (int i = t; i < m; i += 512) {
    unsigned int p = ebuf[base + i];
    int d = (p >> 16) & BMASK;
    int r = atomicAdd(&cur[d], 1);                   // LDS atomic
    ssrc[base + r] = (int)(p & 0xFFFFu);
  }
  // fused prescale: xs16[n] = bf16(x[n] * dinv[n]); 8 feats per iteration
  for (int i = t; i < BNODES * (F0 / 8); i += 512) {
    int nl = i >> 3, oc = i & 7;
    int n = node0 + nl;
    if (n < N) {
      float4 a  = reinterpret_cast<const float4*>(x)[n * 16 + oc * 2];
      float4 bb = reinterpret_cast<const float4*>(x)[n * 16 + oc * 2 + 1];
      float d = dl[nl];
      uint4 pk;
      pk.x = f2bf(a.x * d)  | (f2bf(a.y * d) << 16);
      pk.y = f2bf(a.z * d)  | (f2bf(a.w * d) << 16);
      pk.z = f2bf(bb.x * d) | (f2bf(bb.y * d) << 16);
      pk.w = f2bf(bb.z * d) | (f2bf(bb.w * d) << 16);
      reinterpret_cast<uint4*>(xs16)[(size_t)n * 8 + oc] = pk;
    }
  }
}

// ---- layer-1 aggregation (bf16 gathers): AX[n] = dinv[n]*(xs[n] + sum xs[s]) ----
__global__ __launch_bounds__(256) void k_agg1(const int* __restrict__ rowend,
    const int* __restrict__ cnt, const int* __restrict__ ssrc,
    const unsigned short* __restrict__ xs16, const float* __restrict__ dinv,
    float* __restrict__ AX) {
  int gw = (blockIdx.x * 256 + threadIdx.x) >> 6;   // node (one wave each)
  int lane = threadIdx.x & 63;
  if (gw >= N) return;
  int end   = __builtin_amdgcn_readfirstlane(rowend[gw]);
  int deg   = __builtin_amdgcn_readfirstlane(cnt[gw]);
  int start = end - deg;
  const int g = lane >> 3, fl = lane & 7;           // edge slot, feat octet
  const uint4* xsv = reinterpret_cast<const uint4*>(xs16);
  float acc[8];
  #pragma unroll
  for (int k = 0; k < 8; ++k) acc[k] = 0.f;
  for (int e0 = start; e0 < end; e0 += 16) {
    if (e0 + 16 <= end) {
      int s0 = ssrc[e0 + g];
      int s1 = ssrc[e0 + 8 + g];
      uint4 u0 = xsv[(size_t)s0 * 8 + fl];
      uint4 u1 = xsv[(size_t)s1 * 8 + fl];
      acc[0] += bflo(u0.x); acc[1] += bfhi(u0.x);
      acc[2] += bflo(u0.y); acc[3] += bfhi(u0.y);
      acc[4] += bflo(u0.z); acc[5] += bfhi(u0.z);
      acc[6] += bflo(u0.w); acc[7] += bfhi(u0.w);
      acc[0] += bflo(u1.x); acc[1] += bfhi(u1.x);
      acc[2] += bflo(u1.y); acc[3] += bfhi(u1.y);
      acc[4] += bflo(u1.z); acc[5] += bfhi(u1.z);
      acc[6] += bflo(u1.w); acc[7] += bfhi(u1.w);
    } else {
      int j0 = e0 + g, j1 = e0 + 8 + g;
      int s0 = ssrc[(j0 < end) ? j0 : start];
      int s1 = ssrc[(j1 < end) ? j1 : start];
      float m0 = (j0 < end) ? 1.f : 0.f;
      float m1 = (j1 < end) ? 1.f : 0.f;
      uint4 u0 = xsv[(size_t)s0 * 8 + fl];
      uint4 u1 = xsv[(size_t)s1 * 8 + fl];
      acc[0] = fmaf(bflo(u0.x), m0, acc[0]); acc[1] = fmaf(bfhi(u0.x), m0, acc[1]);
      acc[2] = fmaf(bflo(u0.y), m0, acc[2]); acc[3] = fmaf(bfhi(u0.y), m0, acc[3]);
      acc[4] = fmaf(bflo(u0.z), m0, acc[4]); acc[5] = fmaf(bfhi(u0.z), m0, acc[5]);
      acc[6] = fmaf(bflo(u0.w), m0, acc[6]); acc[7] = fmaf(bfhi(u0.w), m0, acc[7]);
      acc[0] = fmaf(bflo(u1.x), m1, acc[0]); acc[1] = fmaf(bfhi(u1.x), m1, acc[1]);
      acc[2] = fmaf(bflo(u1.y), m1, acc[2]); acc[3] = fmaf(bfhi(u1.y), m1, acc[3]);
      acc[4] = fmaf(bflo(u1.z), m1, acc[4]); acc[5] = fmaf(bfhi(u1.z), m1, acc[5]);
      acc[6] = fmaf(bflo(u1.w), m1, acc[6]); acc[7] = fmaf(bfhi(u1.w), m1, acc[7]);
    }
  }
  #pragma unroll
  for (int r = 8; r < 64; r <<= 1) {
    #pragma unroll
    for (int k = 0; k < 8; ++k) acc[k] += __shfl_xor(acc[k], r);
  }
  if (lane < 8) {
    uint4 su = xsv[(size_t)gw * 8 + fl];
    float dv = dinv[gw];
    float o[8];
    o[0] = (acc[0] + bflo(su.x)) * dv; o[1] = (acc[1] + bfhi(su.x)) * dv;
    o[2] = (acc[2] + bflo(su.y)) * dv; o[3] = (acc[3] + bfhi(su.y)) * dv;
    o[4] = (acc[4] + bflo(su.z)) * dv; o[5] = (acc[5] + bfhi(su.z)) * dv;
    o[6] = (acc[6] + bflo(su.w)) * dv; o[7] = (acc[7] + bfhi(su.w)) * dv;
    *reinterpret_cast<float4*>(&AX[(size_t)gw * F0 + fl * 8])     = *reinterpret_cast<float4*>(o);
    *reinterpret_cast<float4*>(&AX[(size_t)gw * F0 + fl * 8 + 4]) = *reinterpret_cast<float4*>(o + 4);
  }
}

// ---- fused GEMM1+relu+GEMM2: H2s16 = bf16(relu(AX@W1+b1)@W2 * dinv) ----
// 256 threads, 64-row tile. Phase A = proven R6/R12 gemm1 geometry (4r x 8c,
// swizzled W1, Xs stride 68). Overlay sync. Phase B: 2r x 4c register tile,
// H1s [64][132] (stride/4 odd -> conflict-free b128), W2 reads broadcast.
__global__ __launch_bounds__(256) void k_gemm12(const float* __restrict__ AX,
    const float* __restrict__ W1, const float* __restrict__ b1,
    const float* __restrict__ W2, const float* __restrict__ dinv,
    unsigned short* __restrict__ H2s16) {
  __shared__ float arena[12544];           // 50176 B
  float* Ws1 = arena;                      // A: [64 k][32 f4-slots] = 8192 f
  float* Xs  = arena + 8192;               // A: [64][68] = 4352 f
  float* H1s = arena;                      // B: [64][132] = 8448 f
  float* Ws2 = arena + 8448;               // B: [128][8 f4] = 4096 f
  const int tid = threadIdx.x;
  const int row0 = blockIdx.x * 64;
  float4* Ws1f4 = reinterpret_cast<float4*>(Ws1);
  for (int i = tid; i < F0 * F1 / 4; i += 256) {
    int k = i >> 5, s = i & 31;
    int p = s ^ (s >> 2);
    Ws1f4[k * 32 + p] = reinterpret_cast<const float4*>(W1)[i];
  }
  for (int i = tid; i < 64 * 16; i += 256) {
    int r = i >> 4, c4 = i & 15;
    int n = row0 + r;
    float4 v = make_float4(0.f, 0.f, 0.f, 0.f);
    if (n < N) v = reinterpret_cast<const float4*>(AX)[n * 16 + c4];
    *reinterpret_cast<float4*>(&Xs[r * 68 + c4 * 4]) = v;
  }
  __syncthreads();
  // phase A: 4 rows x 8 cols per thread
  const int cg = tid & 15, rg = tid >> 4;
  const int c0 = cg * 8;
  const int s0 = 2 * cg, s1 = 2 * cg + 1;
  const int p0 = s0 ^ (s0 >> 2), p1 = s1 ^ (s1 >> 2);
  float acc[4][8];
  #pragma unroll
  for (int i = 0; i < 4; ++i)
    #pragma unroll
    for (int j = 0; j < 8; ++j) acc[i][j] = 0.f;
  for (int k0 = 0; k0 < F0; k0 += 4) {
    float x0[4], x1[4], x2[4], x3[4];
    *reinterpret_cast<float4*>(x0) = *reinterpret_cast<const float4*>(&Xs[(rg * 4 + 0) * 68 + k0]);
    *reinterpret_cast<float4*>(x1) = *reinterpret_cast<const float4*>(&Xs[(rg * 4 + 1) * 68 + k0]);
    *reinterpret_cast<float4*>(x2) = *reinterpret_cast<const float4*>(&Xs[(rg * 4 + 2) * 68 + k0]);
    *reinterpret_cast<float4*>(x3) = *reinterpret_cast<const float4*>(&Xs[(rg * 4 + 3) * 68 + k0]);
    #pragma unroll
    for (int kk = 0; kk < 4; ++kk) {
      float w[8];
      *reinterpret_cast<float4*>(w)     = Ws1f4[(k0 + kk) * 32 + p0];
      *reinterpret_cast<float4*>(w + 4) = Ws1f4[(k0 + kk) * 32 + p1];
      #pragma unroll
      for (int j = 0; j < 8; ++j) {
        acc[0][j] = fmaf(x0[kk], w[j], acc[0][j]);
        acc[1][j] = fmaf(x1[kk], w[j], acc[1][j]);
        acc[2][j] = fmaf(x2[kk], w[j], acc[2][j]);
        acc[3][j] = fmaf(x3[kk], w[j], acc[3][j]);
      }
    }
  }
  {
    float bb[8];
    *reinterpret_cast<float4*>(bb)     = *reinterpret_cast<const float4*>(&b1[c0]);
    *reinterpret_cast<float4*>(bb + 4) = *reinterpret_cast<const float4*>(&b1[c0 + 4]);
    #pragma unroll
    for (int i = 0; i < 4; ++i)
      #pragma unroll
      for (int j = 0; j < 8; ++j)
        acc[i][j] = fmaxf(acc[i][j] + bb[j], 0.f);   // bias+relu in registers
  }
  __syncthreads();                                   // all phase-A LDS reads done
  // overlay: write relu'd H1 tile; co-load W2
  #pragma unroll
  for (int i = 0; i < 4; ++i) {
    int r = rg * 4 + i;
    *reinterpret_cast<float4*>(&H1s[r * 132 + c0])     = *reinterpret_cast<float4*>(&acc[i][0]);
    *reinterpret_cast<float4*>(&H1s[r * 132 + c0 + 4]) = *reinterpret_cast<float4*>(&acc[i][4]);
  }
  float4* Ws2f4 = reinterpret_cast<float4*>(Ws2);
  for (int i = tid; i < F1 * F2 / 4; i += 256)
    Ws2f4[i] = reinterpret_cast<const float4*>(W2)[i];
  __syncthreads();
  // phase B: rows {rg2, rg2+32}, cols cg2*4..+3
  const int rg2 = tid & 31, cg2 = tid >> 5;
  float acc2[2][4];
  #pragma unroll
  for (int i = 0; i < 2; ++i)
    #pragma unroll
    for (int j = 0; j < 4; ++j) acc2[i][j] = 0.f;
  for (int k0 = 0; k0 < F1; k0 += 4) {
    float h0[4], h1[4];
    *reinterpret_cast<float4*>(h0) = *reinterpret_cast<const float4*>(&H1s[rg2 * 132 + k0]);
    *reinterpret_cast<float4*>(h1) = *reinterpret_cast<const float4*>(&H1s[(rg2 + 32) * 132 + k0]);
    #pragma unroll
    for (int kk = 0; kk < 4; ++kk) {
      float w[4];
      *reinterpret_cast<float4*>(w) = Ws2f4[(k0 + kk) * 8 + cg2];  // broadcast
      #pragma unroll
      for (int j = 0; j < 4; ++j) {
        acc2[0][j] = fmaf(h0[kk], w[j], acc2[0][j]);
        acc2[1][j] = fmaf(h1[kk], w[j], acc2[1][j]);
      }
    }
  }
  #pragma unroll
  for (int i = 0; i < 2; ++i) {
    int n = row0 + rg2 + 32 * i;
    if (n < N) {
      float d = dinv[n];
      uint2 pk;
      pk.x = f2bf(acc2[i][0] * d) | (f2bf(acc2[i][1] * d) << 16);
      pk.y = f2bf(acc2[i][2] * d) | (f2bf(acc2[i][3] * d) << 16);
      reinterpret_cast<uint2*>(H2s16)[(size_t)n * 8 + cg2] = pk;
    }
  }
}

// ---- fused layer-2 aggregation + bias + head (bf16 gathers) ----
__global__ __launch_bounds__(256) void k_agg2h(const int* __restrict__ rowend,
    const int* __restrict__ cnt, const int* __restrict__ ssrc,
    const unsigned short* __restrict__ H2s16, const float* __restrict__ dinv,
    const float* __restrict__ b2, const float* __restrict__ Wc,
    const float* __restrict__ bc, float* __restrict__ h2,
    float* __restrict__ out) {
  __shared__ float Wcs[F2][F2];   // 4 KB
  __shared__ float h2row[4][F2];  // per-wave h2 row
  const int tid = threadIdx.x;
  for (int i = tid; i < F2 * F2; i += 256) Wcs[i >> 5][i & 31] = Wc[i];
  __syncthreads();
  int gw = (blockIdx.x * 256 + tid) >> 6;           // node (one wave each)
  int lane = tid & 63;
  int w = tid >> 6;                                 // wave slot in block
  if (gw >= N) return;
  int end   = __builtin_amdgcn_readfirstlane(rowend[gw]);
  int deg   = __builtin_amdgcn_readfirstlane(cnt[gw]);
  int start = end - deg;
  const int g = lane >> 2, fl = lane & 3;           // edge slot (16), feat octet
  const uint4* hv = reinterpret_cast<const uint4*>(H2s16);
  float acc[8];
  #pragma unroll
  for (int k = 0; k < 8; ++k) acc[k] = 0.f;
  for (int e0 = start; e0 < end; e0 += 16) {
    if (e0 + 16 <= end) {
      int s = ssrc[e0 + g];
      uint4 u = hv[(size_t)s * 4 + fl];
      acc[0] += bflo(u.x); acc[1] += bfhi(u.x);
      acc[2] += bflo(u.y); acc[3] += bfhi(u.y);
      acc[4] += bflo(u.z); acc[5] += bfhi(u.z);
      acc[6] += bflo(u.w); acc[7] += bfhi(u.w);
    } else {
      int j = e0 + g;
      int s = ssrc[(j < end) ? j : start];
      float mm = (j < end) ? 1.f : 0.f;
      uint4 u = hv[(size_t)s * 4 + fl];
      acc[0] = fmaf(bflo(u.x), mm, acc[0]); acc[1] = fmaf(bfhi(u.x), mm, acc[1]);
      acc[2] = fmaf(bflo(u.y), mm, acc[2]); acc[3] = fmaf(bfhi(u.y), mm, acc[3]);
      acc[4] = fmaf(bflo(u.z), mm, acc[4]); acc[5] = fmaf(bfhi(u.z), mm, acc[5]);
      acc[6] = fmaf(bflo(u.w), mm, acc[6]); acc[7] = fmaf(bfhi(u.w), mm, acc[7]);
    }
  }
  #pragma unroll
  for (int r = 4; r < 64; r <<= 1) {
    #pragma unroll
    for (int k = 0; k < 8; ++k) acc[k] += __shfl_xor(acc[k], r);
  }
  float dv = dinv[gw];
  if (lane < 4) {
    uint4 su = hv[(size_t)gw * 4 + fl];
    float o[8];
    o[0] = dv * (acc[0] + bflo(su.x)) + b2[fl * 8 + 0];
    o[1] = dv * (acc[1] + bfhi(su.x)) + b2[fl * 8 + 1];
    o[2] = dv * (acc[2] + bflo(su.y)) + b2[fl * 8 + 2];
    o[3] = dv * (acc[3] + bfhi(su.y)) + b2[fl * 8 + 3];
    o[4] = dv * (acc[4] + bflo(su.z)) + b2[fl * 8 + 4];
    o[5] = dv * (acc[5] + bfhi(su.z)) + b2[fl * 8 + 5];
    o[6] = dv * (acc[6] + bflo(su.w)) + b2[fl * 8 + 6];
    o[7] = dv * (acc[7] + bfhi(su.w)) + b2[fl * 8 + 7];
    *reinterpret_cast<float4*>(&h2[(size_t)gw * F2 + fl * 8])     = *reinterpret_cast<float4*>(o);
    *reinterpret_cast<float4*>(&h2[(size_t)gw * F2 + fl * 8 + 4]) = *reinterpret_cast<float4*>(o + 4);
    #pragma unroll
    for (int k = 0; k < 8; ++k) h2row[w][fl * 8 + k] = o[k];
  }
  int f = lane & 31, half = lane >> 5;
  float acco = 0.f;
  #pragma unroll
  for (int kk = 0; kk < 16; ++kk) {
    int k = kk + 16 * half;
    acco = fmaf(h2row[w][k], Wcs[k][f], acco);
  }
  acco += __shfl_xor(acco, 32);
  if (half == 0) out[(size_t)gw * F2 + f] = acco + bc[f];
}

extern "C" void kernel_launch(void* const* d_in, const int* in_sizes, int n_in,
                              void* d_out, int out_size, void* d_ws, size_t ws_size,
                              hipStream_t stream) {
  const float* x  = (const float*)d_in[0];
  const int*   ei = (const int*)d_in[1];
  const int*   src = ei;                 // edge_index[0]
  const int*   dst = ei + E;             // edge_index[1]
  const float* W1 = (const float*)d_in[2];
  const float* b1 = (const float*)d_in[3];
  const float* W2 = (const float*)d_in[4];
  const float* b2 = (const float*)d_in[5];
  const float* Wc = (const float*)d_in[6];
  const float* bc = (const float*)d_in[7];

  float* out = (float*)d_out;                    // [N, 32] logits
  float* h2  = out + (size_t)N * F2;             // [N, 32] hidden output

  // workspace layout (~35 MB of 256 MB) — all disjoint, no aliasing
  int*   cnt     = (int*)d_ws;                   // N
  int*   rowend  = cnt + N;                      // N
  int*   gcur    = rowend + N;                   // NBUK*16 (line-padded cursors)
  float* dinv    = (float*)(gcur + NBUK * 16);   // N
  int*   ssrc    = (int*)(dinv + N);             // NBUK*BCAP (padded)
  unsigned int* ebuf = (unsigned int*)(ssrc + NBUK * BCAP); // NBUK*BCAP
  unsigned short* xs16 = (unsigned short*)(ebuf + NBUK * BCAP); // N*64 bf16
  float* AX      = (float*)(xs16 + (size_t)N * F0);  // N*64 f32
  unsigned short* H2s16 = (unsigned short*)(AX + (size_t)N * F0); // N*32 bf16

  hipMemsetAsync(gcur, 0, NBUK * 16 * sizeof(int), stream);
  k_bucket<<<NCHUNK, 512, 0, stream>>>(src, dst, gcur, ebuf);
  k_csr   <<<NBUK,   512, 0, stream>>>(ebuf, gcur, x, cnt, rowend, dinv, ssrc, xs16);

  k_agg1  <<<(N + 3) / 4, 256, 0, stream>>>(rowend, cnt, ssrc, xs16, dinv, AX);
  k_gemm12<<<(N + 63) / 64, 256, 0, stream>>>(AX, W1, b1, W2, dinv, H2s16);
  k_agg2h <<<(N + 3) / 4, 256, 0, stream>>>(rowend, cnt, ssrc, H2s16, dinv, b2, Wc, bc, h2, out);
}

// Round 14
// 116.359 us; speedup vs baseline: 1.3229x; 1.0174x over previous
//
#include <hip/hip_runtime.h>

// GCN forward: two GCNConv layers + linear head.
// Round 14: R13 structure +
//   (a) AX stored bf16 (agg1 -> gemm12): halves AX traffic; gemm12 converts
//       to f32 during LDS staging, phase-A math unchanged.
//   (b) k_bucket caches dst in registers across its two passes (one read).
// bf16 gather arrays xs16/H2s16 as in R12/13.
// 6 dispatches:
//   memset(gcur) -> k_bucket -> k_csr(+dinv+bf16 prescale) ->
//   k_agg1 -> k_gemm12 -> k_agg2h
// out = dinv[d] * sum_{s in N(d)+self} (dinv[s]*h[s]) per layer.

static constexpr int N  = 50000;
static constexpr int E  = 800000;
static constexpr int F0 = 64;    // input feats
static constexpr int F1 = 128;   // hidden
static constexpr int F2 = 32;    // classes

static constexpr int BSH    = 7;     // bucket = dst>>7 (128 nodes)
static constexpr int BNODES = 128;
static constexpr int BMASK  = 127;
static constexpr int NBUK   = 392;   // ceil(N/128)
static constexpr int BCAP   = 3072;  // per-bucket capacity (mean 2041 + ~22 sigma)
static constexpr int CHUNK  = 4096;  // edges per chunk
static constexpr int NCHUNK = 196;   // ceil(E/CHUNK)

__device__ __forceinline__ unsigned int f2bf(float f) {
  unsigned int u = __float_as_uint(f);
  return (u + 0x7fffu + ((u >> 16) & 1u)) >> 16;     // RNE
}
__device__ __forceinline__ float bflo(unsigned int u) {
  return __uint_as_float(u << 16);
}
__device__ __forceinline__ float bfhi(unsigned int u) {
  return __uint_as_float(u & 0xffff0000u);
}

// ---- B1: bucket-scatter with per-chunk LDS count + global reservation ----
// gcur[b*16] is a line-padded cursor per bucket (memset to 0 before launch).
__global__ __launch_bounds__(512) void k_bucket(const int* __restrict__ src,
    const int* __restrict__ dst, int* __restrict__ gcur,
    unsigned int* __restrict__ ebuf) {
  __shared__ int hl[NBUK];
  int t = threadIdx.x, c = blockIdx.x;
  for (int i = t; i < NBUK; i += 512) hl[i] = 0;
  __syncthreads();
  int e0 = c * CHUNK, m = min(CHUNK, E - e0);
  int dreg[8];
  #pragma unroll
  for (int k = 0; k < 8; ++k) {
    int i = t + k * 512;
    if (i < m) {
      int d = dst[e0 + i];
      dreg[k] = d;
      atomicAdd(&hl[d >> BSH], 1);
    }
  }
  __syncthreads();
  for (int i = t; i < NBUK; i += 512) {
    int cc = hl[i];
    int rbase = (cc > 0) ? atomicAdd(&gcur[i * 16], cc) : 0;
    hl[i] = i * BCAP + rbase;                        // LDS cursor for pass 2
  }
  __syncthreads();
  #pragma unroll
  for (int k = 0; k < 8; ++k) {
    int i = t + k * 512;
    if (i < m) {
      int d = dreg[k], s = src[e0 + i];
      int pos = atomicAdd(&hl[d >> BSH], 1);         // LDS atomic
      ebuf[pos] = (unsigned int)s | ((unsigned int)(d & BMASK) << 16);
    }
  }
}

// ---- B2: per-bucket CSR finalize + dinv + bf16 xs prescale ----
__global__ __launch_bounds__(512) void k_csr(const unsigned int* __restrict__ ebuf,
    const int* __restrict__ gcur, const float* __restrict__ x,
    int* __restrict__ cnt, int* __restrict__ rowend, float* __restrict__ dinv,
    int* __restrict__ ssrc, unsigned short* __restrict__ xs16) {
  __shared__ int cl[BNODES], sc[BNODES], cur[BNODES];
  __shared__ float dl[BNODES];
  int t = threadIdx.x, b = blockIdx.x;
  int base = b * BCAP;
  int m    = gcur[b * 16];                           // bucket total
  int node0 = b << BSH;
  if (t < BNODES) cl[t] = 0;
  __syncthreads();
  for (int i = t; i < m; i += 512)
    atomicAdd(&cl[(ebuf[base + i] >> 16) & BMASK], 1);
  __syncthreads();
  int v = 0;
  if (t < BNODES) { v = cl[t]; sc[t] = v; }
  __syncthreads();
  for (int off = 1; off < BNODES; off <<= 1) {
    int u = (t >= off && t < BNODES) ? sc[t - off] : 0;
    __syncthreads();
    if (t < BNODES) sc[t] += u;
    __syncthreads();
  }
  if (t < BNODES) {
    int excl = sc[t] - v;
    cur[t] = excl;
    float dv = rsqrtf((float)(v + 1));               // +1 self-loop
    dl[t] = dv;
    int g = node0 + t;
    if (g < N) {
      cnt[g]    = v;
      rowend[g] = base + excl + v;
      dinv[g]   = dv;
    }
  }
  __syncthreads();
  for (int i = t; i < m; i += 512) {
    unsigned int p = ebuf[base + i];
    int d = (p >> 16) & BMASK;
    int r = atomicAdd(&cur[d], 1);                   // LDS atomic
    ssrc[base + r] = (int)(p & 0xFFFFu);
  }
  // fused prescale: xs16[n] = bf16(x[n] * dinv[n]); 8 feats per iteration
  for (int i = t; i < BNODES * (F0 / 8); i += 512) {
    int nl = i >> 3, oc = i & 7;
    int n = node0 + nl;
    if (n < N) {
      float4 a  = reinterpret_cast<const float4*>(x)[n * 16 + oc * 2];
      float4 bb = reinterpret_cast<const float4*>(x)[n * 16 + oc * 2 + 1];
      float d = dl[nl];
      uint4 pk;
      pk.x = f2bf(a.x * d)  | (f2bf(a.y * d) << 16);
      pk.y = f2bf(a.z * d)  | (f2bf(a.w * d) << 16);
      pk.z = f2bf(bb.x * d) | (f2bf(bb.y * d) << 16);
      pk.w = f2bf(bb.z * d) | (f2bf(bb.w * d) << 16);
      reinterpret_cast<uint4*>(xs16)[(size_t)n * 8 + oc] = pk;
    }
  }
}

// ---- layer-1 aggregation (bf16 gathers): AX16[n] = bf16(dinv[n]*(xs[n]+sum xs[s])) ----
__global__ __launch_bounds__(256) void k_agg1(const int* __restrict__ rowend,
    const int* __restrict__ cnt, const int* __restrict__ ssrc,
    const unsigned short* __restrict__ xs16, const float* __restrict__ dinv,
    unsigned short* __restrict__ AX16) {
  int gw = (blockIdx.x * 256 + threadIdx.x) >> 6;   // node (one wave each)
  int lane = threadIdx.x & 63;
  if (gw >= N) return;
  int end   = __builtin_amdgcn_readfirstlane(rowend[gw]);
  int deg   = __builtin_amdgcn_readfirstlane(cnt[gw]);
  int start = end - deg;
  const int g = lane >> 3, fl = lane & 7;           // edge slot, feat octet
  const uint4* xsv = reinterpret_cast<const uint4*>(xs16);
  float acc[8];
  #pragma unroll
  for (int k = 0; k < 8; ++k) acc[k] = 0.f;
  for (int e0 = start; e0 < end; e0 += 16) {
    if (e0 + 16 <= end) {
      int s0 = ssrc[e0 + g];
      int s1 = ssrc[e0 + 8 + g];
      uint4 u0 = xsv[(size_t)s0 * 8 + fl];
      uint4 u1 = xsv[(size_t)s1 * 8 + fl];
      acc[0] += bflo(u0.x); acc[1] += bfhi(u0.x);
      acc[2] += bflo(u0.y); acc[3] += bfhi(u0.y);
      acc[4] += bflo(u0.z); acc[5] += bfhi(u0.z);
      acc[6] += bflo(u0.w); acc[7] += bfhi(u0.w);
      acc[0] += bflo(u1.x); acc[1] += bfhi(u1.x);
      acc[2] += bflo(u1.y); acc[3] += bfhi(u1.y);
      acc[4] += bflo(u1.z); acc[5] += bfhi(u1.z);
      acc[6] += bflo(u1.w); acc[7] += bfhi(u1.w);
    } else {
      int j0 = e0 + g, j1 = e0 + 8 + g;
      int s0 = ssrc[(j0 < end) ? j0 : start];
      int s1 = ssrc[(j1 < end) ? j1 : start];
      float m0 = (j0 < end) ? 1.f : 0.f;
      float m1 = (j1 < end) ? 1.f : 0.f;
      uint4 u0 = xsv[(size_t)s0 * 8 + fl];
      uint4 u1 = xsv[(size_t)s1 * 8 + fl];
      acc[0] = fmaf(bflo(u0.x), m0, acc[0]); acc[1] = fmaf(bfhi(u0.x), m0, acc[1]);
      acc[2] = fmaf(bflo(u0.y), m0, acc[2]); acc[3] = fmaf(bfhi(u0.y), m0, acc[3]);
      acc[4] = fmaf(bflo(u0.z), m0, acc[4]); acc[5] = fmaf(bfhi(u0.z), m0, acc[5]);
      acc[6] = fmaf(bflo(u0.w), m0, acc[6]); acc[7] = fmaf(bfhi(u0.w), m0, acc[7]);
      acc[0] = fmaf(bflo(u1.x), m1, acc[0]); acc[1] = fmaf(bfhi(u1.x), m1, acc[1]);
      acc[2] = fmaf(bflo(u1.y), m1, acc[2]); acc[3] = fmaf(bfhi(u1.y), m1, acc[3]);
      acc[4] = fmaf(bflo(u1.z), m1, acc[4]); acc[5] = fmaf(bfhi(u1.z), m1, acc[5]);
      acc[6] = fmaf(bflo(u1.w), m1, acc[6]); acc[7] = fmaf(bfhi(u1.w), m1, acc[7]);
    }
  }
  #pragma unroll
  for (int r = 8; r < 64; r <<= 1) {
    #pragma unroll
    for (int k = 0; k < 8; ++k) acc[k] += __shfl_xor(acc[k], r);
  }
  if (lane < 8) {
    uint4 su = xsv[(size_t)gw * 8 + fl];
    float dv = dinv[gw];
    float o[8];
    o[0] = (acc[0] + bflo(su.x)) * dv; o[1] = (acc[1] + bfhi(su.x)) * dv;
    o[2] = (acc[2] + bflo(su.y)) * dv; o[3] = (acc[3] + bfhi(su.y)) * dv;
    o[4] = (acc[4] + bflo(su.z)) * dv; o[5] = (acc[5] + bfhi(su.z)) * dv;
    o[6] = (acc[6] + bflo(su.w)) * dv; o[7] = (acc[7] + bfhi(su.w)) * dv;
    uint4 pk;
    pk.x = f2bf(o[0]) | (f2bf(o[1]) << 16);
    pk.y = f2bf(o[2]) | (f2bf(o[3]) << 16);
    pk.z = f2bf(o[4]) | (f2bf(o[5]) << 16);
    pk.w = f2bf(o[6]) | (f2bf(o[7]) << 16);
    reinterpret_cast<uint4*>(AX16)[(size_t)gw * 8 + fl] = pk;
  }
}

// ---- fused GEMM1+relu+GEMM2: H2s16 = bf16(relu(AX@W1+b1)@W2 * dinv) ----
// 256 threads, 64-row tile. Phase A = proven 4r x 8c geometry (swizzled W1,
// Xs stride 68, f32 math; staged from bf16 AX16). Overlay sync. Phase B:
// 2r x 4c register tile over H1s [64][132] + broadcast W2.
__global__ __launch_bounds__(256) void k_gemm12(const unsigned short* __restrict__ AX16,
    const float* __restrict__ W1, const float* __restrict__ b1,
    const float* __restrict__ W2, const float* __restrict__ dinv,
    unsigned short* __restrict__ H2s16) {
  __shared__ float arena[12544];           // 50176 B
  float* Ws1 = arena;                      // A: [64 k][32 f4-slots] = 8192 f
  float* Xs  = arena + 8192;               // A: [64][68] = 4352 f
  float* H1s = arena;                      // B: [64][132] = 8448 f
  float* Ws2 = arena + 8448;               // B: [128][8 f4] = 4096 f
  const int tid = threadIdx.x;
  const int row0 = blockIdx.x * 64;
  float4* Ws1f4 = reinterpret_cast<float4*>(Ws1);
  for (int i = tid; i < F0 * F1 / 4; i += 256) {
    int k = i >> 5, s = i & 31;
    int p = s ^ (s >> 2);
    Ws1f4[k * 32 + p] = reinterpret_cast<const float4*>(W1)[i];
  }
  // stage X tile from bf16 (8 bf16 per uint4 slot), convert to f32
  const uint4* axv = reinterpret_cast<const uint4*>(AX16);
  for (int i = tid; i < 64 * 8; i += 256) {
    int r = i >> 3, q = i & 7;
    int n = row0 + r;
    float o[8] = {0.f, 0.f, 0.f, 0.f, 0.f, 0.f, 0.f, 0.f};
    if (n < N) {
      uint4 u = axv[(size_t)n * 8 + q];
      o[0] = bflo(u.x); o[1] = bfhi(u.x);
      o[2] = bflo(u.y); o[3] = bfhi(u.y);
      o[4] = bflo(u.z); o[5] = bfhi(u.z);
      o[6] = bflo(u.w); o[7] = bfhi(u.w);
    }
    *reinterpret_cast<float4*>(&Xs[r * 68 + q * 8])     = *reinterpret_cast<float4*>(o);
    *reinterpret_cast<float4*>(&Xs[r * 68 + q * 8 + 4]) = *reinterpret_cast<float4*>(o + 4);
  }
  __syncthreads();
  // phase A: 4 rows x 8 cols per thread
  const int cg = tid & 15, rg = tid >> 4;
  const int c0 = cg * 8;
  const int s0 = 2 * cg, s1 = 2 * cg + 1;
  const int p0 = s0 ^ (s0 >> 2), p1 = s1 ^ (s1 >> 2);
  float acc[4][8];
  #pragma unroll
  for (int i = 0; i < 4; ++i)
    #pragma unroll
    for (int j = 0; j < 8; ++j) acc[i][j] = 0.f;
  for (int k0 = 0; k0 < F0; k0 += 4) {
    float x0[4], x1[4], x2[4], x3[4];
    *reinterpret_cast<float4*>(x0) = *reinterpret_cast<const float4*>(&Xs[(rg * 4 + 0) * 68 + k0]);
    *reinterpret_cast<float4*>(x1) = *reinterpret_cast<const float4*>(&Xs[(rg * 4 + 1) * 68 + k0]);
    *reinterpret_cast<float4*>(x2) = *reinterpret_cast<const float4*>(&Xs[(rg * 4 + 2) * 68 + k0]);
    *reinterpret_cast<float4*>(x3) = *reinterpret_cast<const float4*>(&Xs[(rg * 4 + 3) * 68 + k0]);
    #pragma unroll
    for (int kk = 0; kk < 4; ++kk) {
      float w[8];
      *reinterpret_cast<float4*>(w)     = Ws1f4[(k0 + kk) * 32 + p0];
      *reinterpret_cast<float4*>(w + 4) = Ws1f4[(k0 + kk) * 32 + p1];
      #pragma unroll
      for (int j = 0; j < 8; ++j) {
        acc[0][j] = fmaf(x0[kk], w[j], acc[0][j]);
        acc[1][j] = fmaf(x1[kk], w[j], acc[1][j]);
        acc[2][j] = fmaf(x2[kk], w[j], acc[2][j]);
        acc[3][j] = fmaf(x3[kk], w[j], acc[3][j]);
      }
    }
  }
  {
    float bb[8];
    *reinterpret_cast<float4*>(bb)     = *reinterpret_cast<const float4*>(&b1[c0]);
    *reinterpret_cast<float4*>(bb + 4) = *reinterpret_cast<const float4*>(&b1[c0 + 4]);
    #pragma unroll
    for (int i = 0; i < 4; ++i)
      #pragma unroll
      for (int j = 0; j < 8; ++j)
        acc[i][j] = fmaxf(acc[i][j] + bb[j], 0.f);   // bias+relu in registers
  }
  __syncthreads();                                   // all phase-A LDS reads done
  // overlay: write relu'd H1 tile; co-load W2
  #pragma unroll
  for (int i = 0; i < 4; ++i) {
    int r = rg * 4 + i;
    *reinterpret_cast<float4*>(&H1s[r * 132 + c0])     = *reinterpret_cast<float4*>(&acc[i][0]);
    *reinterpret_cast<float4*>(&H1s[r * 132 + c0 + 4]) = *reinterpret_cast<float4*>(&acc[i][4]);
  }
  float4* Ws2f4 = reinterpret_cast<float4*>(Ws2);
  for (int i = tid; i < F1 * F2 / 4; i += 256)
    Ws2f4[i] = reinterpret_cast<const float4*>(W2)[i];
  __syncthreads();
  // phase B: rows {rg2, rg2+32}, cols cg2*4..+3
  const int rg2 = tid & 31, cg2 = tid >> 5;
  float acc2[2][4];
  #pragma unroll
  for (int i = 0; i < 2; ++i)
    #pragma unroll
    for (int j = 0; j < 4; ++j) acc2[i][j] = 0.f;
  for (int k0 = 0; k0 < F1; k0 += 4) {
    float h0[4], h1[4];
    *reinterpret_cast<float4*>(h0) = *reinterpret_cast<const float4*>(&H1s[rg2 * 132 + k0]);
    *reinterpret_cast<float4*>(h1) = *reinterpret_cast<const float4*>(&H1s[(rg2 + 32) * 132 + k0]);
    #pragma unroll
    for (int kk = 0; kk < 4; ++kk) {
      float w[4];
      *reinterpret_cast<float4*>(w) = Ws2f4[(k0 + kk) * 8 + cg2];  // broadcast
      #pragma unroll
      for (int j = 0; j < 4; ++j) {
        acc2[0][j] = fmaf(h0[kk], w[j], acc2[0][j]);
        acc2[1][j] = fmaf(h1[kk], w[j], acc2[1][j]);
      }
    }
  }
  #pragma unroll
  for (int i = 0; i < 2; ++i) {
    int n = row0 + rg2 + 32 * i;
    if (n < N) {
      float d = dinv[n];
      uint2 pk;
      pk.x = f2bf(acc2[i][0] * d) | (f2bf(acc2[i][1] * d) << 16);
      pk.y = f2bf(acc2[i][2] * d) | (f2bf(acc2[i][3] * d) << 16);
      reinterpret_cast<uint2*>(H2s16)[(size_t)n * 8 + cg2] = pk;
    }
  }
}

// ---- fused layer-2 aggregation + bias + head (bf16 gathers) ----
__global__ __launch_bounds__(256) void k_agg2h(const int* __restrict__ rowend,
    const int* __restrict__ cnt, const int* __restrict__ ssrc,
    const unsigned short* __restrict__ H2s16, const float* __restrict__ dinv,
    const float* __restrict__ b2, const float* __restrict__ Wc,
    const float* __restrict__ bc, float* __restrict__ h2,
    float* __restrict__ out) {
  __shared__ float Wcs[F2][F2];   // 4 KB
  __shared__ float h2row[4][F2];  // per-wave h2 row
  const int tid = threadIdx.x;
  for (int i = tid; i < F2 * F2; i += 256) Wcs[i >> 5][i & 31] = Wc[i];
  __syncthreads();
  int gw = (blockIdx.x * 256 + tid) >> 6;           // node (one wave each)
  int lane = tid & 63;
  int w = tid >> 6;                                 // wave slot in block
  if (gw >= N) return;
  int end   = __builtin_amdgcn_readfirstlane(rowend[gw]);
  int deg   = __builtin_amdgcn_readfirstlane(cnt[gw]);
  int start = end - deg;
  const int g = lane >> 2, fl = lane & 3;           // edge slot (16), feat octet
  const uint4* hv = reinterpret_cast<const uint4*>(H2s16);
  float acc[8];
  #pragma unroll
  for (int k = 0; k < 8; ++k) acc[k] = 0.f;
  for (int e0 = start; e0 < end; e0 += 16) {
    if (e0 + 16 <= end) {
      int s = ssrc[e0 + g];
      uint4 u = hv[(size_t)s * 4 + fl];
      acc[0] += bflo(u.x); acc[1] += bfhi(u.x);
      acc[2] += bflo(u.y); acc[3] += bfhi(u.y);
      acc[4] += bflo(u.z); acc[5] += bfhi(u.z);
      acc[6] += bflo(u.w); acc[7] += bfhi(u.w);
    } else {
      int j = e0 + g;
      int s = ssrc[(j < end) ? j : start];
      float mm = (j < end) ? 1.f : 0.f;
      uint4 u = hv[(size_t)s * 4 + fl];
      acc[0] = fmaf(bflo(u.x), mm, acc[0]); acc[1] = fmaf(bfhi(u.x), mm, acc[1]);
      acc[2] = fmaf(bflo(u.y), mm, acc[2]); acc[3] = fmaf(bfhi(u.y), mm, acc[3]);
      acc[4] = fmaf(bflo(u.z), mm, acc[4]); acc[5] = fmaf(bfhi(u.z), mm, acc[5]);
      acc[6] = fmaf(bflo(u.w), mm, acc[6]); acc[7] = fmaf(bfhi(u.w), mm, acc[7]);
    }
  }
  #pragma unroll
  for (int r = 4; r < 64; r <<= 1) {
    #pragma unroll
    for (int k = 0; k < 8; ++k) acc[k] += __shfl_xor(acc[k], r);
  }
  float dv = dinv[gw];
  if (lane < 4) {
    uint4 su = hv[(size_t)gw * 4 + fl];
    float o[8];
    o[0] = dv * (acc[0] + bflo(su.x)) + b2[fl * 8 + 0];
    o[1] = dv * (acc[1] + bfhi(su.x)) + b2[fl * 8 + 1];
    o[2] = dv * (acc[2] + bflo(su.y)) + b2[fl * 8 + 2];
    o[3] = dv * (acc[3] + bfhi(su.y)) + b2[fl * 8 + 3];
    o[4] = dv * (acc[4] + bflo(su.z)) + b2[fl * 8 + 4];
    o[5] = dv * (acc[5] + bfhi(su.z)) + b2[fl * 8 + 5];
    o[6] = dv * (acc[6] + bflo(su.w)) + b2[fl * 8 + 6];
    o[7] = dv * (acc[7] + bfhi(su.w)) + b2[fl * 8 + 7];
    *reinterpret_cast<float4*>(&h2[(size_t)gw * F2 + fl * 8])     = *reinterpret_cast<float4*>(o);
    *reinterpret_cast<float4*>(&h2[(size_t)gw * F2 + fl * 8 + 4]) = *reinterpret_cast<float4*>(o + 4);
    #pragma unroll
    for (int k = 0; k < 8; ++k) h2row[w][fl * 8 + k] = o[k];
  }
  int f = lane & 31, half = lane >> 5;
  float acco = 0.f;
  #pragma unroll
  for (int kk = 0; kk < 16; ++kk) {
    int k = kk + 16 * half;
    acco = fmaf(h2row[w][k], Wcs[k][f], acco);
  }
  acco += __shfl_xor(acco, 32);
  if (half == 0) out[(size_t)gw * F2 + f] = acco + bc[f];
}

extern "C" void kernel_launch(void* const* d_in, const int* in_sizes, int n_in,
                              void* d_out, int out_size, void* d_ws, size_t ws_size,
                              hipStream_t stream) {
  const float* x  = (const float*)d_in[0];
  const int*   ei = (const int*)d_in[1];
  const int*   src = ei;                 // edge_index[0]
  const int*   dst = ei + E;             // edge_index[1]
  const float* W1 = (const float*)d_in[2];
  const float* b1 = (const float*)d_in[3];
  const float* W2 = (const float*)d_in[4];
  const float* b2 = (const float*)d_in[5];
  const float* Wc = (const float*)d_in[6];
  const float* bc = (const float*)d_in[7];

  float* out = (float*)d_out;                    // [N, 32] logits
  float* h2  = out + (size_t)N * F2;             // [N, 32] hidden output

  // workspace layout (~30 MB of 256 MB) — all disjoint, no aliasing
  int*   cnt     = (int*)d_ws;                   // N
  int*   rowend  = cnt + N;                      // N
  int*   gcur    = rowend + N;                   // NBUK*16 (line-padded cursors)
  float* dinv    = (float*)(gcur + NBUK * 16);   // N
  int*   ssrc    = (int*)(dinv + N);             // NBUK*BCAP (padded)
  unsigned int* ebuf = (unsigned int*)(ssrc + NBUK * BCAP); // NBUK*BCAP
  unsigned short* xs16 = (unsigned short*)(ebuf + NBUK * BCAP); // N*64 bf16
  unsigned short* AX16 = xs16 + (size_t)N * F0;  // N*64 bf16
  unsigned short* H2s16 = AX16 + (size_t)N * F0; // N*32 bf16

  hipMemsetAsync(gcur, 0, NBUK * 16 * sizeof(int), stream);
  k_bucket<<<NCHUNK, 512, 0, stream>>>(src, dst, gcur, ebuf);
  k_csr   <<<NBUK,   512, 0, stream>>>(ebuf, gcur, x, cnt, rowend, dinv, ssrc, xs16);

  k_agg1  <<<(N + 3) / 4, 256, 0, stream>>>(rowend, cnt, ssrc, xs16, dinv, AX16);
  k_gemm12<<<(N + 63) / 64, 256, 0, stream>>>(AX16, W1, b1, W2, dinv, H2s16);
  k_agg2h <<<(N + 3) / 4, 256, 0, stream>>>(rowend, cnt, ssrc, H2s16, dinv, b2, Wc, bc, h2, out);
}

// Round 15
// 115.322 us; speedup vs baseline: 1.3348x; 1.0090x over previous
//
#include <hip/hip_runtime.h>

// GCN forward: two GCNConv layers + linear head.
// Round 15: R14 structure + build-side contention fixes:
//   (a) 4-way sub-cursors per bucket (chunk c -> segment c&3, SEGCAP=768):
//       global fetch-add contention per line drops 196 -> 49.
//   (b) k_csr caches its ebuf entries in registers during the count pass and
//       permutes from registers (single ebuf read).
// bf16 arrays xs16/AX16/H2s16 as in R14.
// 6 dispatches:
//   memset(gcur) -> k_bucket -> k_csr(+dinv+bf16 prescale) ->
//   k_agg1 -> k_gemm12 -> k_agg2h
// out = dinv[d] * sum_{s in N(d)+self} (dinv[s]*h[s]) per layer.

static constexpr int N  = 50000;
static constexpr int E  = 800000;
static constexpr int F0 = 64;    // input feats
static constexpr int F1 = 128;   // hidden
static constexpr int F2 = 32;    // classes

static constexpr int BSH    = 7;     // bucket = dst>>7 (128 nodes)
static constexpr int BNODES = 128;
static constexpr int BMASK  = 127;
static constexpr int NBUK   = 392;   // ceil(N/128)
static constexpr int NSEG   = 4;     // sub-cursors per bucket (chunk c -> c&3)
static constexpr int SEGCAP = 768;   // per-segment capacity (mean 514 + 11 sigma)
static constexpr int BCAP   = NSEG * SEGCAP;  // 3072
static constexpr int CHUNK  = 4096;  // edges per chunk
static constexpr int NCHUNK = 196;   // ceil(E/CHUNK)

__device__ __forceinline__ unsigned int f2bf(float f) {
  unsigned int u = __float_as_uint(f);
  return (u + 0x7fffu + ((u >> 16) & 1u)) >> 16;     // RNE
}
__device__ __forceinline__ float bflo(unsigned int u) {
  return __uint_as_float(u << 16);
}
__device__ __forceinline__ float bfhi(unsigned int u) {
  return __uint_as_float(u & 0xffff0000u);
}

// ---- B1: bucket-scatter; per-chunk LDS count + segmented global reservation ----
// gcur[(b*4+sub)*16] are line-padded cursors (memset to 0 before launch).
__global__ __launch_bounds__(512) void k_bucket(const int* __restrict__ src,
    const int* __restrict__ dst, int* __restrict__ gcur,
    unsigned int* __restrict__ ebuf) {
  __shared__ int hl[NBUK];
  int t = threadIdx.x, c = blockIdx.x;
  const int sub = c & (NSEG - 1);
  for (int i = t; i < NBUK; i += 512) hl[i] = 0;
  __syncthreads();
  int e0 = c * CHUNK, m = min(CHUNK, E - e0);
  int dreg[8];
  #pragma unroll
  for (int k = 0; k < 8; ++k) {
    int i = t + k * 512;
    if (i < m) {
      int d = dst[e0 + i];
      dreg[k] = d;
      atomicAdd(&hl[d >> BSH], 1);
    }
  }
  __syncthreads();
  for (int i = t; i < NBUK; i += 512) {
    int cc = hl[i];
    int rbase = (cc > 0) ? atomicAdd(&gcur[(i * NSEG + sub) * 16], cc) : 0;
    hl[i] = i * BCAP + sub * SEGCAP + rbase;         // LDS cursor for pass 2
  }
  __syncthreads();
  #pragma unroll
  for (int k = 0; k < 8; ++k) {
    int i = t + k * 512;
    if (i < m) {
      int d = dreg[k], s = src[e0 + i];
      int pos = atomicAdd(&hl[d >> BSH], 1);         // LDS atomic
      ebuf[pos] = (unsigned int)s | ((unsigned int)(d & BMASK) << 16);
    }
  }
}

// ---- B2: per-bucket CSR finalize + dinv + bf16 xs prescale ----
// Single ebuf read: entries cached in registers across count/permute passes.
__global__ __launch_bounds__(512) void k_csr(const unsigned int* __restrict__ ebuf,
    const int* __restrict__ gcur, const float* __restrict__ x,
    int* __restrict__ cnt, int* __restrict__ rowend, float* __restrict__ dinv,
    int* __restrict__ ssrc, unsigned short* __restrict__ xs16) {
  __shared__ int cl[BNODES], sc[BNODES], cur[BNODES];
  __shared__ float dl[BNODES];
  int t = threadIdx.x, b = blockIdx.x;
  int base = b * BCAP;
  int node0 = b << BSH;
  int ms[NSEG];
  #pragma unroll
  for (int s = 0; s < NSEG; ++s) ms[s] = gcur[(b * NSEG + s) * 16];
  if (t < BNODES) cl[t] = 0;
  __syncthreads();
  unsigned int ereg[NSEG * 2];                       // SEGCAP=768 <= 2*512
  #pragma unroll
  for (int s = 0; s < NSEG; ++s) {
    int msz = ms[s], sb = base + s * SEGCAP;
    #pragma unroll
    for (int k = 0; k < 2; ++k) {
      int i = t + k * 512;
      unsigned int p = 0xFFFFFFFFu;                  // unreachable sentinel
      if (i < msz) {
        p = ebuf[sb + i];
        atomicAdd(&cl[(p >> 16) & BMASK], 1);
      }
      ereg[s * 2 + k] = p;
    }
  }
  __syncthreads();
  int v = 0;
  if (t < BNODES) { v = cl[t]; sc[t] = v; }
  __syncthreads();
  for (int off = 1; off < BNODES; off <<= 1) {
    int u = (t >= off && t < BNODES) ? sc[t - off] : 0;
    __syncthreads();
    if (t < BNODES) sc[t] += u;
    __syncthreads();
  }
  if (t < BNODES) {
    int excl = sc[t] - v;
    cur[t] = excl;
    float dv = rsqrtf((float)(v + 1));               // +1 self-loop
    dl[t] = dv;
    int g = node0 + t;
    if (g < N) {
      cnt[g]    = v;
      rowend[g] = base + excl + v;
      dinv[g]   = dv;
    }
  }
  __syncthreads();
  #pragma unroll
  for (int s = 0; s < NSEG; ++s) {
    #pragma unroll
    for (int k = 0; k < 2; ++k) {
      unsigned int p = ereg[s * 2 + k];
      if (p != 0xFFFFFFFFu) {
        int d = (p >> 16) & BMASK;
        int r = atomicAdd(&cur[d], 1);               // LDS atomic
        ssrc[base + r] = (int)(p & 0xFFFFu);
      }
    }
  }
  // fused prescale: xs16[n] = bf16(x[n] * dinv[n]); 8 feats per iteration
  for (int i = t; i < BNODES * (F0 / 8); i += 512) {
    int nl = i >> 3, oc = i & 7;
    int n = node0 + nl;
    if (n < N) {
      float4 a  = reinterpret_cast<const float4*>(x)[n * 16 + oc * 2];
      float4 bb = reinterpret_cast<const float4*>(x)[n * 16 + oc * 2 + 1];
      float d = dl[nl];
      uint4 pk;
      pk.x = f2bf(a.x * d)  | (f2bf(a.y * d) << 16);
      pk.y = f2bf(a.z * d)  | (f2bf(a.w * d) << 16);
      pk.z = f2bf(bb.x * d) | (f2bf(bb.y * d) << 16);
      pk.w = f2bf(bb.z * d) | (f2bf(bb.w * d) << 16);
      reinterpret_cast<uint4*>(xs16)[(size_t)n * 8 + oc] = pk;
    }
  }
}

// ---- layer-1 aggregation (bf16 gathers): AX16[n] = bf16(dinv[n]*(xs[n]+sum xs[s])) ----
__global__ __launch_bounds__(256) void k_agg1(const int* __restrict__ rowend,
    const int* __restrict__ cnt, const int* __restrict__ ssrc,
    const unsigned short* __restrict__ xs16, const float* __restrict__ dinv,
    unsigned short* __restrict__ AX16) {
  int gw = (blockIdx.x * 256 + threadIdx.x) >> 6;   // node (one wave each)
  int lane = threadIdx.x & 63;
  if (gw >= N) return;
  int end   = __builtin_amdgcn_readfirstlane(rowend[gw]);
  int deg   = __builtin_amdgcn_readfirstlane(cnt[gw]);
  int start = end - deg;
  const int g = lane >> 3, fl = lane & 7;           // edge slot, feat octet
  const uint4* xsv = reinterpret_cast<const uint4*>(xs16);
  float acc[8];
  #pragma unroll
  for (int k = 0; k < 8; ++k) acc[k] = 0.f;
  for (int e0 = start; e0 < end; e0 += 16) {
    if (e0 + 16 <= end) {
      int s0 = ssrc[e0 + g];
      int s1 = ssrc[e0 + 8 + g];
      uint4 u0 = xsv[(size_t)s0 * 8 + fl];
      uint4 u1 = xsv[(size_t)s1 * 8 + fl];
      acc[0] += bflo(u0.x); acc[1] += bfhi(u0.x);
      acc[2] += bflo(u0.y); acc[3] += bfhi(u0.y);
      acc[4] += bflo(u0.z); acc[5] += bfhi(u0.z);
      acc[6] += bflo(u0.w); acc[7] += bfhi(u0.w);
      acc[0] += bflo(u1.x); acc[1] += bfhi(u1.x);
      acc[2] += bflo(u1.y); acc[3] += bfhi(u1.y);
      acc[4] += bflo(u1.z); acc[5] += bfhi(u1.z);
      acc[6] += bflo(u1.w); acc[7] += bfhi(u1.w);
    } else {
      int j0 = e0 + g, j1 = e0 + 8 + g;
      int s0 = ssrc[(j0 < end) ? j0 : start];
      int s1 = ssrc[(j1 < end) ? j1 : start];
      float m0 = (j0 < end) ? 1.f : 0.f;
      float m1 = (j1 < end) ? 1.f : 0.f;
      uint4 u0 = xsv[(size_t)s0 * 8 + fl];
      uint4 u1 = xsv[(size_t)s1 * 8 + fl];
      acc[0] = fmaf(bflo(u0.x), m0, acc[0]); acc[1] = fmaf(bfhi(u0.x), m0, acc[1]);
      acc[2] = fmaf(bflo(u0.y), m0, acc[2]); acc[3] = fmaf(bfhi(u0.y), m0, acc[3]);
      acc[4] = fmaf(bflo(u0.z), m0, acc[4]); acc[5] = fmaf(bfhi(u0.z), m0, acc[5]);
      acc[6] = fmaf(bflo(u0.w), m0, acc[6]); acc[7] = fmaf(bfhi(u0.w), m0, acc[7]);
      acc[0] = fmaf(bflo(u1.x), m1, acc[0]); acc[1] = fmaf(bfhi(u1.x), m1, acc[1]);
      acc[2] = fmaf(bflo(u1.y), m1, acc[2]); acc[3] = fmaf(bfhi(u1.y), m1, acc[3]);
      acc[4] = fmaf(bflo(u1.z), m1, acc[4]); acc[5] = fmaf(bfhi(u1.z), m1, acc[5]);
      acc[6] = fmaf(bflo(u1.w), m1, acc[6]); acc[7] = fmaf(bfhi(u1.w), m1, acc[7]);
    }
  }
  #pragma unroll
  for (int r = 8; r < 64; r <<= 1) {
    #pragma unroll
    for (int k = 0; k < 8; ++k) acc[k] += __shfl_xor(acc[k], r);
  }
  if (lane < 8) {
    uint4 su = xsv[(size_t)gw * 8 + fl];
    float dv = dinv[gw];
    float o[8];
    o[0] = (acc[0] + bflo(su.x)) * dv; o[1] = (acc[1] + bfhi(su.x)) * dv;
    o[2] = (acc[2] + bflo(su.y)) * dv; o[3] = (acc[3] + bfhi(su.y)) * dv;
    o[4] = (acc[4] + bflo(su.z)) * dv; o[5] = (acc[5] + bfhi(su.z)) * dv;
    o[6] = (acc[6] + bflo(su.w)) * dv; o[7] = (acc[7] + bfhi(su.w)) * dv;
    uint4 pk;
    pk.x = f2bf(o[0]) | (f2bf(o[1]) << 16);
    pk.y = f2bf(o[2]) | (f2bf(o[3]) << 16);
    pk.z = f2bf(o[4]) | (f2bf(o[5]) << 16);
    pk.w = f2bf(o[6]) | (f2bf(o[7]) << 16);
    reinterpret_cast<uint4*>(AX16)[(size_t)gw * 8 + fl] = pk;
  }
}

// ---- fused GEMM1+relu+GEMM2: H2s16 = bf16(relu(AX@W1+b1)@W2 * dinv) ----
// 256 threads, 64-row tile. Phase A = proven 4r x 8c geometry (swizzled W1,
// Xs stride 68, f32 math; staged from bf16 AX16). Overlay sync. Phase B:
// 2r x 4c register tile over H1s [64][132] + broadcast W2.
__global__ __launch_bounds__(256) void k_gemm12(const unsigned short* __restrict__ AX16,
    const float* __restrict__ W1, const float* __restrict__ b1,
    const float* __restrict__ W2, const float* __restrict__ dinv,
    unsigned short* __restrict__ H2s16) {
  __shared__ float arena[12544];           // 50176 B
  float* Ws1 = arena;                      // A: [64 k][32 f4-slots] = 8192 f
  float* Xs  = arena + 8192;               // A: [64][68] = 4352 f
  float* H1s = arena;                      // B: [64][132] = 8448 f
  float* Ws2 = arena + 8448;               // B: [128][8 f4] = 4096 f
  const int tid = threadIdx.x;
  const int row0 = blockIdx.x * 64;
  float4* Ws1f4 = reinterpret_cast<float4*>(Ws1);
  for (int i = tid; i < F0 * F1 / 4; i += 256) {
    int k = i >> 5, s = i & 31;
    int p = s ^ (s >> 2);
    Ws1f4[k * 32 + p] = reinterpret_cast<const float4*>(W1)[i];
  }
  // stage X tile from bf16 (8 bf16 per uint4 slot), convert to f32
  const uint4* axv = reinterpret_cast<const uint4*>(AX16);
  for (int i = tid; i < 64 * 8; i += 256) {
    int r = i >> 3, q = i & 7;
    int n = row0 + r;
    float o[8] = {0.f, 0.f, 0.f, 0.f, 0.f, 0.f, 0.f, 0.f};
    if (n < N) {
      uint4 u = axv[(size_t)n * 8 + q];
      o[0] = bflo(u.x); o[1] = bfhi(u.x);
      o[2] = bflo(u.y); o[3] = bfhi(u.y);
      o[4] = bflo(u.z); o[5] = bfhi(u.z);
      o[6] = bflo(u.w); o[7] = bfhi(u.w);
    }
    *reinterpret_cast<float4*>(&Xs[r * 68 + q * 8])     = *reinterpret_cast<float4*>(o);
    *reinterpret_cast<float4*>(&Xs[r * 68 + q * 8 + 4]) = *reinterpret_cast<float4*>(o + 4);
  }
  __syncthreads();
  // phase A: 4 rows x 8 cols per thread
  const int cg = tid & 15, rg = tid >> 4;
  const int c0 = cg * 8;
  const int s0 = 2 * cg, s1 = 2 * cg + 1;
  const int p0 = s0 ^ (s0 >> 2), p1 = s1 ^ (s1 >> 2);
  float acc[4][8];
  #pragma unroll
  for (int i = 0; i < 4; ++i)
    #pragma unroll
    for (int j = 0; j < 8; ++j) acc[i][j] = 0.f;
  for (int k0 = 0; k0 < F0; k0 += 4) {
    float x0[4], x1[4], x2[4], x3[4];
    *reinterpret_cast<float4*>(x0) = *reinterpret_cast<const float4*>(&Xs[(rg * 4 + 0) * 68 + k0]);
    *reinterpret_cast<float4*>(x1) = *reinterpret_cast<const float4*>(&Xs[(rg * 4 + 1) * 68 + k0]);
    *reinterpret_cast<float4*>(x2) = *reinterpret_cast<const float4*>(&Xs[(rg * 4 + 2) * 68 + k0]);
    *reinterpret_cast<float4*>(x3) = *reinterpret_cast<const float4*>(&Xs[(rg * 4 + 3) * 68 + k0]);
    #pragma unroll
    for (int kk = 0; kk < 4; ++kk) {
      float w[8];
      *reinterpret_cast<float4*>(w)     = Ws1f4[(k0 + kk) * 32 + p0];
      *reinterpret_cast<float4*>(w + 4) = Ws1f4[(k0 + kk) * 32 + p1];
      #pragma unroll
      for (int j = 0; j < 8; ++j) {
        acc[0][j] = fmaf(x0[kk], w[j], acc[0][j]);
        acc[1][j] = fmaf(x1[kk], w[j], acc[1][j]);
        acc[2][j] = fmaf(x2[kk], w[j], acc[2][j]);
        acc[3][j] = fmaf(x3[kk], w[j], acc[3][j]);
      }
    }
  }
  {
    float bb[8];
    *reinterpret_cast<float4*>(bb)     = *reinterpret_cast<const float4*>(&b1[c0]);
    *reinterpret_cast<float4*>(bb + 4) = *reinterpret_cast<const float4*>(&b1[c0 + 4]);
    #pragma unroll
    for (int i = 0; i < 4; ++i)
      #pragma unroll
      for (int j = 0; j < 8; ++j)
        acc[i][j] = fmaxf(acc[i][j] + bb[j], 0.f);   // bias+relu in registers
  }
  __syncthreads();                                   // all phase-A LDS reads done
  // overlay: write relu'd H1 tile; co-load W2
  #pragma unroll
  for (int i = 0; i < 4; ++i) {
    int r = rg * 4 + i;
    *reinterpret_cast<float4*>(&H1s[r * 132 + c0])     = *reinterpret_cast<float4*>(&acc[i][0]);
    *reinterpret_cast<float4*>(&H1s[r * 132 + c0 + 4]) = *reinterpret_cast<float4*>(&acc[i][4]);
  }
  float4* Ws2f4 = reinterpret_cast<float4*>(Ws2);
  for (int i = tid; i < F1 * F2 / 4; i += 256)
    Ws2f4[i] = reinterpret_cast<const float4*>(W2)[i];
  __syncthreads();
  // phase B: rows {rg2, rg2+32}, cols cg2*4..+3
  const int rg2 = tid & 31, cg2 = tid >> 5;
  float acc2[2][4];
  #pragma unroll
  for (int i = 0; i < 2; ++i)
    #pragma unroll
    for (int j = 0; j < 4; ++j) acc2[i][j] = 0.f;
  for (int k0 = 0; k0 < F1; k0 += 4) {
    float h0[4], h1[4];
    *reinterpret_cast<float4*>(h0) = *reinterpret_cast<const float4*>(&H1s[rg2 * 132 + k0]);
    *reinterpret_cast<float4*>(h1) = *reinterpret_cast<const float4*>(&H1s[(rg2 + 32) * 132 + k0]);
    #pragma unroll
    for (int kk = 0; kk < 4; ++kk) {
      float w[4];
      *reinterpret_cast<float4*>(w) = Ws2f4[(k0 + kk) * 8 + cg2];  // broadcast
      #pragma unroll
      for (int j = 0; j < 4; ++j) {
        acc2[0][j] = fmaf(h0[kk], w[j], acc2[0][j]);
        acc2[1][j] = fmaf(h1[kk], w[j], acc2[1][j]);
      }
    }
  }
  #pragma unroll
  for (int i = 0; i < 2; ++i) {
    int n = row0 + rg2 + 32 * i;
    if (n < N) {
      float d = dinv[n];
      uint2 pk;
      pk.x = f2bf(acc2[i][0] * d) | (f2bf(acc2[i][1] * d) << 16);
      pk.y = f2bf(acc2[i][2] * d) | (f2bf(acc2[i][3] * d) << 16);
      reinterpret_cast<uint2*>(H2s16)[(size_t)n * 8 + cg2] = pk;
    }
  }
}

// ---- fused layer-2 aggregation + bias + head (bf16 gathers) ----
__global__ __launch_bounds__(256) void k_agg2h(const int* __restrict__ rowend,
    const int* __restrict__ cnt, const int* __restrict__ ssrc,
    const unsigned short* __restrict__ H2s16, const float* __restrict__ dinv,
    const float* __restrict__ b2, const float* __restrict__ Wc,
    const float* __restrict__ bc, float* __restrict__ h2,
    float* __restrict__ out) {
  __shared__ float Wcs[F2][F2];   // 4 KB
  __shared__ float h2row[4][F2];  // per-wave h2 row
  const int tid = threadIdx.x;
  for (int i = tid; i < F2 * F2; i += 256) Wcs[i >> 5][i & 31] = Wc[i];
  __syncthreads();
  int gw = (blockIdx.x * 256 + tid) >> 6;           // node (one wave each)
  int lane = tid & 63;
  int w = tid >> 6;                                 // wave slot in block
  if (gw >= N) return;
  int end   = __builtin_amdgcn_readfirstlane(rowend[gw]);
  int deg   = __builtin_amdgcn_readfirstlane(cnt[gw]);
  int start = end - deg;
  const int g = lane >> 2, fl = lane & 3;           // edge slot (16), feat octet
  const uint4* hv = reinterpret_cast<const uint4*>(H2s16);
  float acc[8];
  #pragma unroll
  for (int k = 0; k < 8; ++k) acc[k] = 0.f;
  for (int e0 = start; e0 < end; e0 += 16) {
    if (e0 + 16 <= end) {
      int s = ssrc[e0 + g];
      uint4 u = hv[(size_t)s * 4 + fl];
      acc[0] += bflo(u.x); acc[1] += bfhi(u.x);
      acc[2] += bflo(u.y); acc[3] += bfhi(u.y);
      acc[4] += bflo(u.z); acc[5] += bfhi(u.z);
      acc[6] += bflo(u.w); acc[7] += bfhi(u.w);
    } else {
      int j = e0 + g;
      int s = ssrc[(j < end) ? j : start];
      float mm = (j < end) ? 1.f : 0.f;
      uint4 u = hv[(size_t)s * 4 + fl];
      acc[0] = fmaf(bflo(u.x), mm, acc[0]); acc[1] = fmaf(bfhi(u.x), mm, acc[1]);
      acc[2] = fmaf(bflo(u.y), mm, acc[2]); acc[3] = fmaf(bfhi(u.y), mm, acc[3]);
      acc[4] = fmaf(bflo(u.z), mm, acc[4]); acc[5] = fmaf(bfhi(u.z), mm, acc[5]);
      acc[6] = fmaf(bflo(u.w), mm, acc[6]); acc[7] = fmaf(bfhi(u.w), mm, acc[7]);
    }
  }
  #pragma unroll
  for (int r = 4; r < 64; r <<= 1) {
    #pragma unroll
    for (int k = 0; k < 8; ++k) acc[k] += __shfl_xor(acc[k], r);
  }
  float dv = dinv[gw];
  if (lane < 4) {
    uint4 su = hv[(size_t)gw * 4 + fl];
    float o[8];
    o[0] = dv * (acc[0] + bflo(su.x)) + b2[fl * 8 + 0];
    o[1] = dv * (acc[1] + bfhi(su.x)) + b2[fl * 8 + 1];
    o[2] = dv * (acc[2] + bflo(su.y)) + b2[fl * 8 + 2];
    o[3] = dv * (acc[3] + bfhi(su.y)) + b2[fl * 8 + 3];
    o[4] = dv * (acc[4] + bflo(su.z)) + b2[fl * 8 + 4];
    o[5] = dv * (acc[5] + bfhi(su.z)) + b2[fl * 8 + 5];
    o[6] = dv * (acc[6] + bflo(su.w)) + b2[fl * 8 + 6];
    o[7] = dv * (acc[7] + bfhi(su.w)) + b2[fl * 8 + 7];
    *reinterpret_cast<float4*>(&h2[(size_t)gw * F2 + fl * 8])     = *reinterpret_cast<float4*>(o);
    *reinterpret_cast<float4*>(&h2[(size_t)gw * F2 + fl * 8 + 4]) = *reinterpret_cast<float4*>(o + 4);
    #pragma unroll
    for (int k = 0; k < 8; ++k) h2row[w][fl * 8 + k] = o[k];
  }
  int f = lane & 31, half = lane >> 5;
  float acco = 0.f;
  #pragma unroll
  for (int kk = 0; kk < 16; ++kk) {
    int k = kk + 16 * half;
    acco = fmaf(h2row[w][k], Wcs[k][f], acco);
  }
  acco += __shfl_xor(acco, 32);
  if (half == 0) out[(size_t)gw * F2 + f] = acco + bc[f];
}

extern "C" void kernel_launch(void* const* d_in, const int* in_sizes, int n_in,
                              void* d_out, int out_size, void* d_ws, size_t ws_size,
                              hipStream_t stream) {
  const float* x  = (const float*)d_in[0];
  const int*   ei = (const int*)d_in[1];
  const int*   src = ei;                 // edge_index[0]
  const int*   dst = ei + E;             // edge_index[1]
  const float* W1 = (const float*)d_in[2];
  const float* b1 = (const float*)d_in[3];
  const float* W2 = (const float*)d_in[4];
  const float* b2 = (const float*)d_in[5];
  const float* Wc = (const float*)d_in[6];
  const float* bc = (const float*)d_in[7];

  float* out = (float*)d_out;                    // [N, 32] logits
  float* h2  = out + (size_t)N * F2;             // [N, 32] hidden output

  // workspace layout (~30 MB of 256 MB) — all disjoint, no aliasing
  int*   cnt     = (int*)d_ws;                   // N
  int*   rowend  = cnt + N;                      // N
  int*   gcur    = rowend + N;                   // NBUK*NSEG*16 (line-padded)
  float* dinv    = (float*)(gcur + NBUK * NSEG * 16); // N
  int*   ssrc    = (int*)(dinv + N);             // NBUK*BCAP (padded)
  unsigned int* ebuf = (unsigned int*)(ssrc + NBUK * BCAP); // NBUK*BCAP
  unsigned short* xs16 = (unsigned short*)(ebuf + NBUK * BCAP); // N*64 bf16
  unsigned short* AX16 = xs16 + (size_t)N * F0;  // N*64 bf16
  unsigned short* H2s16 = AX16 + (size_t)N * F0; // N*32 bf16

  hipMemsetAsync(gcur, 0, NBUK * NSEG * 16 * sizeof(int), stream);
  k_bucket<<<NCHUNK, 512, 0, stream>>>(src, dst, gcur, ebuf);
  k_csr   <<<NBUK,   512, 0, stream>>>(ebuf, gcur, x, cnt, rowend, dinv, ssrc, xs16);

  k_agg1  <<<(N + 3) / 4, 256, 0, stream>>>(rowend, cnt, ssrc, xs16, dinv, AX16);
  k_gemm12<<<(N + 63) / 64, 256, 0, stream>>>(AX16, W1, b1, W2, dinv, H2s16);
  k_agg2h <<<(N + 3) / 4, 256, 0, stream>>>(rowend, cnt, ssrc, H2s16, dinv, b2, Wc, bc, h2, out);
}

// Round 16
// 108.729 us; speedup vs baseline: 1.4158x; 1.0606x over previous
//
#include <hip/hip_runtime.h>

// GCN forward: two GCNConv layers + linear head.
// Round 16: R15 + gemm12 phase A on matrix cores (mfma_f32_16x16x32_bf16).
//   W1 pre-packed in B-fragment order in LDS (bf16); A frags read direct from
//   global AX16 (bf16); D (f32) -> bias+relu in regs -> H1s; phase B unchanged.
// bf16 arrays xs16/AX16/H2s16 as in R14/15.
// 6 dispatches:
//   memset(gcur) -> k_bucket -> k_csr(+dinv+bf16 prescale) ->
//   k_agg1 -> k_gemm12(MFMA phase A) -> k_agg2h
// out = dinv[d] * sum_{s in N(d)+self} (dinv[s]*h[s]) per layer.

static constexpr int N  = 50000;
static constexpr int E  = 800000;
static constexpr int F0 = 64;    // input feats
static constexpr int F1 = 128;   // hidden
static constexpr int F2 = 32;    // classes

static constexpr int BSH    = 7;     // bucket = dst>>7 (128 nodes)
static constexpr int BNODES = 128;
static constexpr int BMASK  = 127;
static constexpr int NBUK   = 392;   // ceil(N/128)
static constexpr int NSEG   = 4;     // sub-cursors per bucket (chunk c -> c&3)
static constexpr int SEGCAP = 768;   // per-segment capacity (mean 514 + 11 sigma)
static constexpr int BCAP   = NSEG * SEGCAP;  // 3072
static constexpr int CHUNK  = 4096;  // edges per chunk
static constexpr int NCHUNK = 196;   // ceil(E/CHUNK)

typedef __attribute__((ext_vector_type(8))) short short8v;   // 8 bf16 (4 VGPRs)
typedef __attribute__((ext_vector_type(4))) float float4v;   // 4 f32 acc

__device__ __forceinline__ unsigned int f2bf(float f) {
  unsigned int u = __float_as_uint(f);
  return (u + 0x7fffu + ((u >> 16) & 1u)) >> 16;     // RNE
}
__device__ __forceinline__ float bflo(unsigned int u) {
  return __uint_as_float(u << 16);
}
__device__ __forceinline__ float bfhi(unsigned int u) {
  return __uint_as_float(u & 0xffff0000u);
}

// ---- B1: bucket-scatter; per-chunk LDS count + segmented global reservation ----
__global__ __launch_bounds__(512) void k_bucket(const int* __restrict__ src,
    const int* __restrict__ dst, int* __restrict__ gcur,
    unsigned int* __restrict__ ebuf) {
  __shared__ int hl[NBUK];
  int t = threadIdx.x, c = blockIdx.x;
  const int sub = c & (NSEG - 1);
  for (int i = t; i < NBUK; i += 512) hl[i] = 0;
  __syncthreads();
  int e0 = c * CHUNK, m = min(CHUNK, E - e0);
  int dreg[8];
  #pragma unroll
  for (int k = 0; k < 8; ++k) {
    int i = t + k * 512;
    if (i < m) {
      int d = dst[e0 + i];
      dreg[k] = d;
      atomicAdd(&hl[d >> BSH], 1);
    }
  }
  __syncthreads();
  for (int i = t; i < NBUK; i += 512) {
    int cc = hl[i];
    int rbase = (cc > 0) ? atomicAdd(&gcur[(i * NSEG + sub) * 16], cc) : 0;
    hl[i] = i * BCAP + sub * SEGCAP + rbase;         // LDS cursor for pass 2
  }
  __syncthreads();
  #pragma unroll
  for (int k = 0; k < 8; ++k) {
    int i = t + k * 512;
    if (i < m) {
      int d = dreg[k], s = src[e0 + i];
      int pos = atomicAdd(&hl[d >> BSH], 1);         // LDS atomic
      ebuf[pos] = (unsigned int)s | ((unsigned int)(d & BMASK) << 16);
    }
  }
}

// ---- B2: per-bucket CSR finalize + dinv + bf16 xs prescale ----
__global__ __launch_bounds__(512) void k_csr(const unsigned int* __restrict__ ebuf,
    const int* __restrict__ gcur, const float* __restrict__ x,
    int* __restrict__ cnt, int* __restrict__ rowend, float* __restrict__ dinv,
    int* __restrict__ ssrc, unsigned short* __restrict__ xs16) {
  __shared__ int cl[BNODES], sc[BNODES], cur[BNODES];
  __shared__ float dl[BNODES];
  int t = threadIdx.x, b = blockIdx.x;
  int base = b * BCAP;
  int node0 = b << BSH;
  int ms[NSEG];
  #pragma unroll
  for (int s = 0; s < NSEG; ++s) ms[s] = gcur[(b * NSEG + s) * 16];
  if (t < BNODES) cl[t] = 0;
  __syncthreads();
  unsigned int ereg[NSEG * 2];                       // SEGCAP=768 <= 2*512
  #pragma unroll
  for (int s = 0; s < NSEG; ++s) {
    int msz = ms[s], sb = base + s * SEGCAP;
    #pragma unroll
    for (int k = 0; k < 2; ++k) {
      int i = t + k * 512;
      unsigned int p = 0xFFFFFFFFu;                  // unreachable sentinel
      if (i < msz) {
        p = ebuf[sb + i];
        atomicAdd(&cl[(p >> 16) & BMASK], 1);
      }
      ereg[s * 2 + k] = p;
    }
  }
  __syncthreads();
  int v = 0;
  if (t < BNODES) { v = cl[t]; sc[t] = v; }
  __syncthreads();
  for (int off = 1; off < BNODES; off <<= 1) {
    int u = (t >= off && t < BNODES) ? sc[t - off] : 0;
    __syncthreads();
    if (t < BNODES) sc[t] += u;
    __syncthreads();
  }
  if (t < BNODES) {
    int excl = sc[t] - v;
    cur[t] = excl;
    float dv = rsqrtf((float)(v + 1));               // +1 self-loop
    dl[t] = dv;
    int g = node0 + t;
    if (g < N) {
      cnt[g]    = v;
      rowend[g] = base + excl + v;
      dinv[g]   = dv;
    }
  }
  __syncthreads();
  #pragma unroll
  for (int s = 0; s < NSEG; ++s) {
    #pragma unroll
    for (int k = 0; k < 2; ++k) {
      unsigned int p = ereg[s * 2 + k];
      if (p != 0xFFFFFFFFu) {
        int d = (p >> 16) & BMASK;
        int r = atomicAdd(&cur[d], 1);               // LDS atomic
        ssrc[base + r] = (int)(p & 0xFFFFu);
      }
    }
  }
  // fused prescale: xs16[n] = bf16(x[n] * dinv[n]); 8 feats per iteration
  for (int i = t; i < BNODES * (F0 / 8); i += 512) {
    int nl = i >> 3, oc = i & 7;
    int n = node0 + nl;
    if (n < N) {
      float4 a  = reinterpret_cast<const float4*>(x)[n * 16 + oc * 2];
      float4 bb = reinterpret_cast<const float4*>(x)[n * 16 + oc * 2 + 1];
      float d = dl[nl];
      uint4 pk;
      pk.x = f2bf(a.x * d)  | (f2bf(a.y * d) << 16);
      pk.y = f2bf(a.z * d)  | (f2bf(a.w * d) << 16);
      pk.z = f2bf(bb.x * d) | (f2bf(bb.y * d) << 16);
      pk.w = f2bf(bb.z * d) | (f2bf(bb.w * d) << 16);
      reinterpret_cast<uint4*>(xs16)[(size_t)n * 8 + oc] = pk;
    }
  }
}

// ---- layer-1 aggregation (bf16 gathers): AX16[n] = bf16(dinv[n]*(xs[n]+sum xs[s])) ----
__global__ __launch_bounds__(256) void k_agg1(const int* __restrict__ rowend,
    const int* __restrict__ cnt, const int* __restrict__ ssrc,
    const unsigned short* __restrict__ xs16, const float* __restrict__ dinv,
    unsigned short* __restrict__ AX16) {
  int gw = (blockIdx.x * 256 + threadIdx.x) >> 6;   // node (one wave each)
  int lane = threadIdx.x & 63;
  if (gw >= N) return;
  int end   = __builtin_amdgcn_readfirstlane(rowend[gw]);
  int deg   = __builtin_amdgcn_readfirstlane(cnt[gw]);
  int start = end - deg;
  const int g = lane >> 3, fl = lane & 7;           // edge slot, feat octet
  const uint4* xsv = reinterpret_cast<const uint4*>(xs16);
  float acc[8];
  #pragma unroll
  for (int k = 0; k < 8; ++k) acc[k] = 0.f;
  for (int e0 = start; e0 < end; e0 += 16) {
    if (e0 + 16 <= end) {
      int s0 = ssrc[e0 + g];
      int s1 = ssrc[e0 + 8 + g];
      uint4 u0 = xsv[(size_t)s0 * 8 + fl];
      uint4 u1 = xsv[(size_t)s1 * 8 + fl];
      acc[0] += bflo(u0.x); acc[1] += bfhi(u0.x);
      acc[2] += bflo(u0.y); acc[3] += bfhi(u0.y);
      acc[4] += bflo(u0.z); acc[5] += bfhi(u0.z);
      acc[6] += bflo(u0.w); acc[7] += bfhi(u0.w);
      acc[0] += bflo(u1.x); acc[1] += bfhi(u1.x);
      acc[2] += bflo(u1.y); acc[3] += bfhi(u1.y);
      acc[4] += bflo(u1.z); acc[5] += bfhi(u1.z);
      acc[6] += bflo(u1.w); acc[7] += bfhi(u1.w);
    } else {
      int j0 = e0 + g, j1 = e0 + 8 + g;
      int s0 = ssrc[(j0 < end) ? j0 : start];
      int s1 = ssrc[(j1 < end) ? j1 : start];
      float m0 = (j0 < end) ? 1.f : 0.f;
      float m1 = (j1 < end) ? 1.f : 0.f;
      uint4 u0 = xsv[(size_t)s0 * 8 + fl];
      uint4 u1 = xsv[(size_t)s1 * 8 + fl];
      acc[0] = fmaf(bflo(u0.x), m0, acc[0]); acc[1] = fmaf(bfhi(u0.x), m0, acc[1]);
      acc[2] = fmaf(bflo(u0.y), m0, acc[2]); acc[3] = fmaf(bfhi(u0.y), m0, acc[3]);
      acc[4] = fmaf(bflo(u0.z), m0, acc[4]); acc[5] = fmaf(bfhi(u0.z), m0, acc[5]);
      acc[6] = fmaf(bflo(u0.w), m0, acc[6]); acc[7] = fmaf(bfhi(u0.w), m0, acc[7]);
      acc[0] = fmaf(bflo(u1.x), m1, acc[0]); acc[1] = fmaf(bfhi(u1.x), m1, acc[1]);
      acc[2] = fmaf(bflo(u1.y), m1, acc[2]); acc[3] = fmaf(bfhi(u1.y), m1, acc[3]);
      acc[4] = fmaf(bflo(u1.z), m1, acc[4]); acc[5] = fmaf(bfhi(u1.z), m1, acc[5]);
      acc[6] = fmaf(bflo(u1.w), m1, acc[6]); acc[7] = fmaf(bfhi(u1.w), m1, acc[7]);
    }
  }
  #pragma unroll
  for (int r = 8; r < 64; r <<= 1) {
    #pragma unroll
    for (int k = 0; k < 8; ++k) acc[k] += __shfl_xor(acc[k], r);
  }
  if (lane < 8) {
    uint4 su = xsv[(size_t)gw * 8 + fl];
    float dv = dinv[gw];
    float o[8];
    o[0] = (acc[0] + bflo(su.x)) * dv; o[1] = (acc[1] + bfhi(su.x)) * dv;
    o[2] = (acc[2] + bflo(su.y)) * dv; o[3] = (acc[3] + bfhi(su.y)) * dv;
    o[4] = (acc[4] + bflo(su.z)) * dv; o[5] = (acc[5] + bfhi(su.z)) * dv;
    o[6] = (acc[6] + bflo(su.w)) * dv; o[7] = (acc[7] + bfhi(su.w)) * dv;
    uint4 pk;
    pk.x = f2bf(o[0]) | (f2bf(o[1]) << 16);
    pk.y = f2bf(o[2]) | (f2bf(o[3]) << 16);
    pk.z = f2bf(o[4]) | (f2bf(o[5]) << 16);
    pk.w = f2bf(o[6]) | (f2bf(o[7]) << 16);
    reinterpret_cast<uint4*>(AX16)[(size_t)gw * 8 + fl] = pk;
  }
}

// ---- fused GEMM1(MFMA)+relu+GEMM2: H2s16 = bf16(relu(AX@W1+b1)@W2 * dinv) ----
// 256 threads = 4 waves, 64-row tile. Phase A: wave w owns rows w*16..+15;
// 8 col-tiles x 2 k-steps of mfma_f32_16x16x32_bf16. B frags (W1 bf16) are
// pre-packed in fragment order in LDS; A frags read direct from global AX16.
// D layout: col=lane&15, row=(lane>>4)*4+reg (verified). Phase B unchanged.
__global__ __launch_bounds__(256) void k_gemm12(const unsigned short* __restrict__ AX16,
    const float* __restrict__ W1, const float* __restrict__ b1,
    const float* __restrict__ W2, const float* __restrict__ dinv,
    unsigned short* __restrict__ H2s16) {
  __shared__ float arena[12544];           // 50176 B
  // phase A: Wf = arena[0..4095] uints (16 KB, W1 bf16 in B-fragment order)
  // phase B: H1s = arena[0..8447] f32 [64][132]; Ws2 = arena[8448..12543]
  float* H1s = arena;
  float* Ws2 = arena + 8448;
  unsigned int* Wfu = reinterpret_cast<unsigned int*>(arena);
  const short8v* Wf8 = reinterpret_cast<const short8v*>(arena);
  const int tid = threadIdx.x;
  const int row0 = blockIdx.x * 64;
  // stage W1 -> bf16 fragment order: frag f=ct*2+ks, elem (l,j):
  //   k = ks*32 + (l>>4)*8 + j, col = ct*16 + (l&15)
  for (int i = tid; i < 4096; i += 256) {
    int jh = i & 3, l = (i >> 2) & 63, f = i >> 8;
    int k0  = (f & 1) * 32 + ((l >> 4) << 3) + jh * 2;
    int col = (f >> 1) * 16 + (l & 15);
    float w0 = W1[k0 * F1 + col];
    float w1 = W1[(k0 + 1) * F1 + col];
    Wfu[i] = f2bf(w0) | (f2bf(w1) << 16);
  }
  __syncthreads();
  // phase A: MFMA
  const int w = tid >> 6, l = tid & 63;
  const int nrow = row0 + w * 16 + (l & 15);        // may read past N (masked later)
  const short8v* axv8 = reinterpret_cast<const short8v*>(AX16);
  short8v A0 = axv8[(size_t)nrow * 8 + (l >> 4)];
  short8v A1 = axv8[(size_t)nrow * 8 + 4 + (l >> 4)];
  float4v acc[8];
  #pragma unroll
  for (int ct = 0; ct < 8; ++ct)
    #pragma unroll
    for (int r = 0; r < 4; ++r) acc[ct][r] = 0.f;
  #pragma unroll
  for (int ct = 0; ct < 8; ++ct) {
    short8v B0 = Wf8[(ct * 2 + 0) * 64 + l];
    short8v B1 = Wf8[(ct * 2 + 1) * 64 + l];
    acc[ct] = __builtin_amdgcn_mfma_f32_16x16x32_bf16(A0, B0, acc[ct], 0, 0, 0);
    acc[ct] = __builtin_amdgcn_mfma_f32_16x16x32_bf16(A1, B1, acc[ct], 0, 0, 0);
  }
  __syncthreads();                                   // all Wf reads done
  // bias+relu in registers -> H1s [64][132]; co-stage Ws2
  #pragma unroll
  for (int ct = 0; ct < 8; ++ct) {
    int col = ct * 16 + (l & 15);
    float bb = b1[col];
    #pragma unroll
    for (int r = 0; r < 4; ++r) {
      int row = w * 16 + ((l >> 4) << 2) + r;
      H1s[row * 132 + col] = fmaxf(acc[ct][r] + bb, 0.f);
    }
  }
  float4* Ws2f4 = reinterpret_cast<float4*>(Ws2);
  for (int i = tid; i < F1 * F2 / 4; i += 256)
    Ws2f4[i] = reinterpret_cast<const float4*>(W2)[i];
  __syncthreads();
  // phase B: rows {rg2, rg2+32}, cols cg2*4..+3 (f32 register tile)
  const int rg2 = tid & 31, cg2 = tid >> 5;
  float acc2[2][4];
  #pragma unroll
  for (int i = 0; i < 2; ++i)
    #pragma unroll
    for (int j = 0; j < 4; ++j) acc2[i][j] = 0.f;
  for (int k0 = 0; k0 < F1; k0 += 4) {
    float h0[4], h1[4];
    *reinterpret_cast<float4*>(h0) = *reinterpret_cast<const float4*>(&H1s[rg2 * 132 + k0]);
    *reinterpret_cast<float4*>(h1) = *reinterpret_cast<const float4*>(&H1s[(rg2 + 32) * 132 + k0]);
    #pragma unroll
    for (int kk = 0; kk < 4; ++kk) {
      float ww[4];
      *reinterpret_cast<float4*>(ww) = Ws2f4[(k0 + kk) * 8 + cg2];  // broadcast
      #pragma unroll
      for (int j = 0; j < 4; ++j) {
        acc2[0][j] = fmaf(h0[kk], ww[j], acc2[0][j]);
        acc2[1][j] = fmaf(h1[kk], ww[j], acc2[1][j]);
      }
    }
  }
  #pragma unroll
  for (int i = 0; i < 2; ++i) {
    int n = row0 + rg2 + 32 * i;
    if (n < N) {
      float d = dinv[n];
      uint2 pk;
      pk.x = f2bf(acc2[i][0] * d) | (f2bf(acc2[i][1] * d) << 16);
      pk.y = f2bf(acc2[i][2] * d) | (f2bf(acc2[i][3] * d) << 16);
      reinterpret_cast<uint2*>(H2s16)[(size_t)n * 8 + cg2] = pk;
    }
  }
}

// ---- fused layer-2 aggregation + bias + head (bf16 gathers) ----
__global__ __launch_bounds__(256) void k_agg2h(const int* __restrict__ rowend,
    const int* __restrict__ cnt, const int* __restrict__ ssrc,
    const unsigned short* __restrict__ H2s16, const float* __restrict__ dinv,
    const float* __restrict__ b2, const float* __restrict__ Wc,
    const float* __restrict__ bc, float* __restrict__ h2,
    float* __restrict__ out) {
  __shared__ float Wcs[F2][F2];   // 4 KB
  __shared__ float h2row[4][F2];  // per-wave h2 row
  const int tid = threadIdx.x;
  for (int i = tid; i < F2 * F2; i += 256) Wcs[i >> 5][i & 31] = Wc[i];
  __syncthreads();
  int gw = (blockIdx.x * 256 + tid) >> 6;           // node (one wave each)
  int lane = tid & 63;
  int w = tid >> 6;                                 // wave slot in block
  if (gw >= N) return;
  int end   = __builtin_amdgcn_readfirstlane(rowend[gw]);
  int deg   = __builtin_amdgcn_readfirstlane(cnt[gw]);
  int start = end - deg;
  const int g = lane >> 2, fl = lane & 3;           // edge slot (16), feat octet
  const uint4* hv = reinterpret_cast<const uint4*>(H2s16);
  float acc[8];
  #pragma unroll
  for (int k = 0; k < 8; ++k) acc[k] = 0.f;
  for (int e0 = start; e0 < end; e0 += 16) {
    if (e0 + 16 <= end) {
      int s = ssrc[e0 + g];
      uint4 u = hv[(size_t)s * 4 + fl];
      acc[0] += bflo(u.x); acc[1] += bfhi(u.x);
      acc[2] += bflo(u.y); acc[3] += bfhi(u.y);
      acc[4] += bflo(u.z); acc[5] += bfhi(u.z);
      acc[6] += bflo(u.w); acc[7] += bfhi(u.w);
    } else {
      int j = e0 + g;
      int s = ssrc[(j < end) ? j : start];
      float mm = (j < end) ? 1.f : 0.f;
      uint4 u = hv[(size_t)s * 4 + fl];
      acc[0] = fmaf(bflo(u.x), mm, acc[0]); acc[1] = fmaf(bfhi(u.x), mm, acc[1]);
      acc[2] = fmaf(bflo(u.y), mm, acc[2]); acc[3] = fmaf(bfhi(u.y), mm, acc[3]);
      acc[4] = fmaf(bflo(u.z), mm, acc[4]); acc[5] = fmaf(bfhi(u.z), mm, acc[5]);
      acc[6] = fmaf(bflo(u.w), mm, acc[6]); acc[7] = fmaf(bfhi(u.w), mm, acc[7]);
    }
  }
  #pragma unroll
  for (int r = 4; r < 64; r <<= 1) {
    #pragma unroll
    for (int k = 0; k < 8; ++k) acc[k] += __shfl_xor(acc[k], r);
  }
  float dv = dinv[gw];
  if (lane < 4) {
    uint4 su = hv[(size_t)gw * 4 + fl];
    float o[8];
    o[0] = dv * (acc[0] + bflo(su.x)) + b2[fl * 8 + 0];
    o[1] = dv * (acc[1] + bfhi(su.x)) + b2[fl * 8 + 1];
    o[2] = dv * (acc[2] + bflo(su.y)) + b2[fl * 8 + 2];
    o[3] = dv * (acc[3] + bfhi(su.y)) + b2[fl * 8 + 3];
    o[4] = dv * (acc[4] + bflo(su.z)) + b2[fl * 8 + 4];
    o[5] = dv * (acc[5] + bfhi(su.z)) + b2[fl * 8 + 5];
    o[6] = dv * (acc[6] + bflo(su.w)) + b2[fl * 8 + 6];
    o[7] = dv * (acc[7] + bfhi(su.w)) + b2[fl * 8 + 7];
    *reinterpret_cast<float4*>(&h2[(size_t)gw * F2 + fl * 8])     = *reinterpret_cast<float4*>(o);
    *reinterpret_cast<float4*>(&h2[(size_t)gw * F2 + fl * 8 + 4]) = *reinterpret_cast<float4*>(o + 4);
    #pragma unroll
    for (int k = 0; k < 8; ++k) h2row[w][fl * 8 + k] = o[k];
  }
  int f = lane & 31, half = lane >> 5;
  float acco = 0.f;
  #pragma unroll
  for (int kk = 0; kk < 16; ++kk) {
    int k = kk + 16 * half;
    acco = fmaf(h2row[w][k], Wcs[k][f], acco);
  }
  acco += __shfl_xor(acco, 32);
  if (half == 0) out[(size_t)gw * F2 + f] = acco + bc[f];
}

extern "C" void kernel_launch(void* const* d_in, const int* in_sizes, int n_in,
                              void* d_out, int out_size, void* d_ws, size_t ws_size,
                              hipStream_t stream) {
  const float* x  = (const float*)d_in[0];
  const int*   ei = (const int*)d_in[1];
  const int*   src = ei;                 // edge_index[0]
  const int*   dst = ei + E;             // edge_index[1]
  const float* W1 = (const float*)d_in[2];
  const float* b1 = (const float*)d_in[3];
  const float* W2 = (const float*)d_in[4];
  const float* b2 = (const float*)d_in[5];
  const float* Wc = (const float*)d_in[6];
  const float* bc = (const float*)d_in[7];

  float* out = (float*)d_out;                    // [N, 32] logits
  float* h2  = out + (size_t)N * F2;             // [N, 32] hidden output

  // workspace layout (~30 MB of 256 MB) — all disjoint, no aliasing
  int*   cnt     = (int*)d_ws;                   // N
  int*   rowend  = cnt + N;                      // N
  int*   gcur    = rowend + N;                   // NBUK*NSEG*16 (line-padded)
  float* dinv    = (float*)(gcur + NBUK * NSEG * 16); // N
  int*   ssrc    = (int*)(dinv + N);             // NBUK*BCAP (padded)
  unsigned int* ebuf = (unsigned int*)(ssrc + NBUK * BCAP); // NBUK*BCAP
  unsigned short* xs16 = (unsigned short*)(ebuf + NBUK * BCAP); // N*64 bf16
  unsigned short* AX16 = xs16 + (size_t)N * F0;  // N*64 bf16
  unsigned short* H2s16 = AX16 + (size_t)N * F0; // N*32 bf16

  hipMemsetAsync(gcur, 0, NBUK * NSEG * 16 * sizeof(int), stream);
  k_bucket<<<NCHUNK, 512, 0, stream>>>(src, dst, gcur, ebuf);
  k_csr   <<<NBUK,   512, 0, stream>>>(ebuf, gcur, x, cnt, rowend, dinv, ssrc, xs16);

  k_agg1  <<<(N + 3) / 4, 256, 0, stream>>>(rowend, cnt, ssrc, xs16, dinv, AX16);
  k_gemm12<<<(N + 63) / 64, 256, 0, stream>>>(AX16, W1, b1, W2, dinv, H2s16);
  k_agg2h <<<(N + 3) / 4, 256, 0, stream>>>(rowend, cnt, ssrc, H2s16, dinv, b2, Wc, bc, h2, out);
}

// Round 17
// 101.709 us; speedup vs baseline: 1.5135x; 1.0690x over previous
//
#include <hip/hip_runtime.h>

// GCN forward: two GCNConv layers + linear head.
// Round 17: R16 + gemm12 phase B on matrix cores too (mfma_f32_16x16x32_bf16).
//   Phase A epilogue writes H1 as bf16 to LDS [64][136] (272B stride, aligned
//   b128 A-frags); W2 pre-packed bf16 B-frags; phase B = 8 MFMA/wave.
//   LDS arena 50 -> 26 KB (6 blocks/CU).
// bf16 arrays xs16/AX16/H2s16 as in R14-16.
// 6 dispatches:
//   memset(gcur) -> k_bucket -> k_csr(+dinv+bf16 prescale) ->
//   k_agg1 -> k_gemm12(MFMA A+B) -> k_agg2h
// out = dinv[d] * sum_{s in N(d)+self} (dinv[s]*h[s]) per layer.

static constexpr int N  = 50000;
static constexpr int E  = 800000;
static constexpr int F0 = 64;    // input feats
static constexpr int F1 = 128;   // hidden
static constexpr int F2 = 32;    // classes

static constexpr int BSH    = 7;     // bucket = dst>>7 (128 nodes)
static constexpr int BNODES = 128;
static constexpr int BMASK  = 127;
static constexpr int NBUK   = 392;   // ceil(N/128)
static constexpr int NSEG   = 4;     // sub-cursors per bucket (chunk c -> c&3)
static constexpr int SEGCAP = 768;   // per-segment capacity (mean 514 + 11 sigma)
static constexpr int BCAP   = NSEG * SEGCAP;  // 3072
static constexpr int CHUNK  = 4096;  // edges per chunk
static constexpr int NCHUNK = 196;   // ceil(E/CHUNK)

typedef __attribute__((ext_vector_type(8))) short short8v;   // 8 bf16 (4 VGPRs)
typedef __attribute__((ext_vector_type(4))) float float4v;   // 4 f32 acc

__device__ __forceinline__ unsigned int f2bf(float f) {
  unsigned int u = __float_as_uint(f);
  return (u + 0x7fffu + ((u >> 16) & 1u)) >> 16;     // RNE
}
__device__ __forceinline__ float bflo(unsigned int u) {
  return __uint_as_float(u << 16);
}
__device__ __forceinline__ float bfhi(unsigned int u) {
  return __uint_as_float(u & 0xffff0000u);
}

// ---- B1: bucket-scatter; per-chunk LDS count + segmented global reservation ----
__global__ __launch_bounds__(512) void k_bucket(const int* __restrict__ src,
    const int* __restrict__ dst, int* __restrict__ gcur,
    unsigned int* __restrict__ ebuf) {
  __shared__ int hl[NBUK];
  int t = threadIdx.x, c = blockIdx.x;
  const int sub = c & (NSEG - 1);
  for (int i = t; i < NBUK; i += 512) hl[i] = 0;
  __syncthreads();
  int e0 = c * CHUNK, m = min(CHUNK, E - e0);
  int dreg[8];
  #pragma unroll
  for (int k = 0; k < 8; ++k) {
    int i = t + k * 512;
    if (i < m) {
      int d = dst[e0 + i];
      dreg[k] = d;
      atomicAdd(&hl[d >> BSH], 1);
    }
  }
  __syncthreads();
  for (int i = t; i < NBUK; i += 512) {
    int cc = hl[i];
    int rbase = (cc > 0) ? atomicAdd(&gcur[(i * NSEG + sub) * 16], cc) : 0;
    hl[i] = i * BCAP + sub * SEGCAP + rbase;         // LDS cursor for pass 2
  }
  __syncthreads();
  #pragma unroll
  for (int k = 0; k < 8; ++k) {
    int i = t + k * 512;
    if (i < m) {
      int d = dreg[k], s = src[e0 + i];
      int pos = atomicAdd(&hl[d >> BSH], 1);         // LDS atomic
      ebuf[pos] = (unsigned int)s | ((unsigned int)(d & BMASK) << 16);
    }
  }
}

// ---- B2: per-bucket CSR finalize + dinv + bf16 xs prescale ----
__global__ __launch_bounds__(512) void k_csr(const unsigned int* __restrict__ ebuf,
    const int* __restrict__ gcur, const float* __restrict__ x,
    int* __restrict__ cnt, int* __restrict__ rowend, float* __restrict__ dinv,
    int* __restrict__ ssrc, unsigned short* __restrict__ xs16) {
  __shared__ int cl[BNODES], sc[BNODES], cur[BNODES];
  __shared__ float dl[BNODES];
  int t = threadIdx.x, b = blockIdx.x;
  int base = b * BCAP;
  int node0 = b << BSH;
  int ms[NSEG];
  #pragma unroll
  for (int s = 0; s < NSEG; ++s) ms[s] = gcur[(b * NSEG + s) * 16];
  if (t < BNODES) cl[t] = 0;
  __syncthreads();
  unsigned int ereg[NSEG * 2];                       // SEGCAP=768 <= 2*512
  #pragma unroll
  for (int s = 0; s < NSEG; ++s) {
    int msz = ms[s], sb = base + s * SEGCAP;
    #pragma unroll
    for (int k = 0; k < 2; ++k) {
      int i = t + k * 512;
      unsigned int p = 0xFFFFFFFFu;                  // unreachable sentinel
      if (i < msz) {
        p = ebuf[sb + i];
        atomicAdd(&cl[(p >> 16) & BMASK], 1);
      }
      ereg[s * 2 + k] = p;
    }
  }
  __syncthreads();
  int v = 0;
  if (t < BNODES) { v = cl[t]; sc[t] = v; }
  __syncthreads();
  for (int off = 1; off < BNODES; off <<= 1) {
    int u = (t >= off && t < BNODES) ? sc[t - off] : 0;
    __syncthreads();
    if (t < BNODES) sc[t] += u;
    __syncthreads();
  }
  if (t < BNODES) {
    int excl = sc[t] - v;
    cur[t] = excl;
    float dv = rsqrtf((float)(v + 1));               // +1 self-loop
    dl[t] = dv;
    int g = node0 + t;
    if (g < N) {
      cnt[g]    = v;
      rowend[g] = base + excl + v;
      dinv[g]   = dv;
    }
  }
  __syncthreads();
  #pragma unroll
  for (int s = 0; s < NSEG; ++s) {
    #pragma unroll
    for (int k = 0; k < 2; ++k) {
      unsigned int p = ereg[s * 2 + k];
      if (p != 0xFFFFFFFFu) {
        int d = (p >> 16) & BMASK;
        int r = atomicAdd(&cur[d], 1);               // LDS atomic
        ssrc[base + r] = (int)(p & 0xFFFFu);
      }
    }
  }
  // fused prescale: xs16[n] = bf16(x[n] * dinv[n]); 8 feats per iteration
  for (int i = t; i < BNODES * (F0 / 8); i += 512) {
    int nl = i >> 3, oc = i & 7;
    int n = node0 + nl;
    if (n < N) {
      float4 a  = reinterpret_cast<const float4*>(x)[n * 16 + oc * 2];
      float4 bb = reinterpret_cast<const float4*>(x)[n * 16 + oc * 2 + 1];
      float d = dl[nl];
      uint4 pk;
      pk.x = f2bf(a.x * d)  | (f2bf(a.y * d) << 16);
      pk.y = f2bf(a.z * d)  | (f2bf(a.w * d) << 16);
      pk.z = f2bf(bb.x * d) | (f2bf(bb.y * d) << 16);
      pk.w = f2bf(bb.z * d) | (f2bf(bb.w * d) << 16);
      reinterpret_cast<uint4*>(xs16)[(size_t)n * 8 + oc] = pk;
    }
  }
}

// ---- layer-1 aggregation (bf16 gathers): AX16[n] = bf16(dinv[n]*(xs[n]+sum xs[s])) ----
__global__ __launch_bounds__(256) void k_agg1(const int* __restrict__ rowend,
    const int* __restrict__ cnt, const int* __restrict__ ssrc,
    const unsigned short* __restrict__ xs16, const float* __restrict__ dinv,
    unsigned short* __restrict__ AX16) {
  int gw = (blockIdx.x * 256 + threadIdx.x) >> 6;   // node (one wave each)
  int lane = threadIdx.x & 63;
  if (gw >= N) return;
  int end   = __builtin_amdgcn_readfirstlane(rowend[gw]);
  int deg   = __builtin_amdgcn_readfirstlane(cnt[gw]);
  int start = end - deg;
  const int g = lane >> 3, fl = lane & 7;           // edge slot, feat octet
  const uint4* xsv = reinterpret_cast<const uint4*>(xs16);
  float acc[8];
  #pragma unroll
  for (int k = 0; k < 8; ++k) acc[k] = 0.f;
  for (int e0 = start; e0 < end; e0 += 16) {
    if (e0 + 16 <= end) {
      int s0 = ssrc[e0 + g];
      int s1 = ssrc[e0 + 8 + g];
      uint4 u0 = xsv[(size_t)s0 * 8 + fl];
      uint4 u1 = xsv[(size_t)s1 * 8 + fl];
      acc[0] += bflo(u0.x); acc[1] += bfhi(u0.x);
      acc[2] += bflo(u0.y); acc[3] += bfhi(u0.y);
      acc[4] += bflo(u0.z); acc[5] += bfhi(u0.z);
      acc[6] += bflo(u0.w); acc[7] += bfhi(u0.w);
      acc[0] += bflo(u1.x); acc[1] += bfhi(u1.x);
      acc[2] += bflo(u1.y); acc[3] += bfhi(u1.y);
      acc[4] += bflo(u1.z); acc[5] += bfhi(u1.z);
      acc[6] += bflo(u1.w); acc[7] += bfhi(u1.w);
    } else {
      int j0 = e0 + g, j1 = e0 + 8 + g;
      int s0 = ssrc[(j0 < end) ? j0 : start];
      int s1 = ssrc[(j1 < end) ? j1 : start];
      float m0 = (j0 < end) ? 1.f : 0.f;
      float m1 = (j1 < end) ? 1.f : 0.f;
      uint4 u0 = xsv[(size_t)s0 * 8 + fl];
      uint4 u1 = xsv[(size_t)s1 * 8 + fl];
      acc[0] = fmaf(bflo(u0.x), m0, acc[0]); acc[1] = fmaf(bfhi(u0.x), m0, acc[1]);
      acc[2] = fmaf(bflo(u0.y), m0, acc[2]); acc[3] = fmaf(bfhi(u0.y), m0, acc[3]);
      acc[4] = fmaf(bflo(u0.z), m0, acc[4]); acc[5] = fmaf(bfhi(u0.z), m0, acc[5]);
      acc[6] = fmaf(bflo(u0.w), m0, acc[6]); acc[7] = fmaf(bfhi(u0.w), m0, acc[7]);
      acc[0] = fmaf(bflo(u1.x), m1, acc[0]); acc[1] = fmaf(bfhi(u1.x), m1, acc[1]);
      acc[2] = fmaf(bflo(u1.y), m1, acc[2]); acc[3] = fmaf(bfhi(u1.y), m1, acc[3]);
      acc[4] = fmaf(bflo(u1.z), m1, acc[4]); acc[5] = fmaf(bfhi(u1.z), m1, acc[5]);
      acc[6] = fmaf(bflo(u1.w), m1, acc[6]); acc[7] = fmaf(bfhi(u1.w), m1, acc[7]);
    }
  }
  #pragma unroll
  for (int r = 8; r < 64; r <<= 1) {
    #pragma unroll
    for (int k = 0; k < 8; ++k) acc[k] += __shfl_xor(acc[k], r);
  }
  if (lane < 8) {
    uint4 su = xsv[(size_t)gw * 8 + fl];
    float dv = dinv[gw];
    float o[8];
    o[0] = (acc[0] + bflo(su.x)) * dv; o[1] = (acc[1] + bfhi(su.x)) * dv;
    o[2] = (acc[2] + bflo(su.y)) * dv; o[3] = (acc[3] + bfhi(su.y)) * dv;
    o[4] = (acc[4] + bflo(su.z)) * dv; o[5] = (acc[5] + bfhi(su.z)) * dv;
    o[6] = (acc[6] + bflo(su.w)) * dv; o[7] = (acc[7] + bfhi(su.w)) * dv;
    uint4 pk;
    pk.x = f2bf(o[0]) | (f2bf(o[1]) << 16);
    pk.y = f2bf(o[2]) | (f2bf(o[3]) << 16);
    pk.z = f2bf(o[4]) | (f2bf(o[5]) << 16);
    pk.w = f2bf(o[6]) | (f2bf(o[7]) << 16);
    reinterpret_cast<uint4*>(AX16)[(size_t)gw * 8 + fl] = pk;
  }
}

// ---- fused GEMM1(MFMA)+relu+GEMM2(MFMA): H2s16 = bf16(relu(AX@W1+b1)@W2*dinv) ----
// 256 threads = 4 waves, 64-row tile.
// Phase A: wave w rows w*16..+15; 8 col-tiles x 2 k-steps of MFMA; W1 bf16
//   frags in LDS, A frags direct from global AX16.
// Handoff: bias+relu in regs -> H1b bf16 LDS [64][136] (272B stride).
// Phase B: 2 col-tiles x 4 k-steps of MFMA; W2 bf16 frags in LDS.
__global__ __launch_bounds__(256) void k_gemm12(const unsigned short* __restrict__ AX16,
    const float* __restrict__ W1, const float* __restrict__ b1,
    const float* __restrict__ W2, const float* __restrict__ dinv,
    unsigned short* __restrict__ H2s16) {
  __shared__ float arena[6656];            // 26624 B -> 6 blocks/CU
  // phase A: Wfu = arena[0..4095] uints (W1 frags bf16)
  // phase B: H1b = arena[0..4351] as shorts [64][136]; Wf2u = arena[4608..6655]
  unsigned int* Wfu = reinterpret_cast<unsigned int*>(arena);
  const short8v* Wf8 = reinterpret_cast<const short8v*>(arena);
  unsigned short* H1b = reinterpret_cast<unsigned short*>(arena);
  unsigned int* Wf2u = reinterpret_cast<unsigned int*>(arena + 4608);
  const short8v* Wf2_8 = reinterpret_cast<const short8v*>(arena + 4608);
  const short8v* H1b8 = reinterpret_cast<const short8v*>(arena);
  const int tid = threadIdx.x;
  const int row0 = blockIdx.x * 64;
  // stage W1 -> bf16 fragment order: frag f=ct*2+ks: k=ks*32+(l>>4)*8+j, col=ct*16+(l&15)
  for (int i = tid; i < 4096; i += 256) {
    int jh = i & 3, l = (i >> 2) & 63, f = i >> 8;
    int k0  = (f & 1) * 32 + ((l >> 4) << 3) + jh * 2;
    int col = (f >> 1) * 16 + (l & 15);
    float w0 = W1[k0 * F1 + col];
    float w1 = W1[(k0 + 1) * F1 + col];
    Wfu[i] = f2bf(w0) | (f2bf(w1) << 16);
  }
  __syncthreads();
  // phase A: MFMA
  const int w = tid >> 6, l = tid & 63;
  const int nrow = row0 + w * 16 + (l & 15);        // may read past N (masked later)
  const short8v* axv8 = reinterpret_cast<const short8v*>(AX16);
  short8v A0 = axv8[(size_t)nrow * 8 + (l >> 4)];
  short8v A1 = axv8[(size_t)nrow * 8 + 4 + (l >> 4)];
  float4v acc[8];
  #pragma unroll
  for (int ct = 0; ct < 8; ++ct)
    #pragma unroll
    for (int r = 0; r < 4; ++r) acc[ct][r] = 0.f;
  #pragma unroll
  for (int ct = 0; ct < 8; ++ct) {
    short8v B0 = Wf8[(ct * 2 + 0) * 64 + l];
    short8v B1 = Wf8[(ct * 2 + 1) * 64 + l];
    acc[ct] = __builtin_amdgcn_mfma_f32_16x16x32_bf16(A0, B0, acc[ct], 0, 0, 0);
    acc[ct] = __builtin_amdgcn_mfma_f32_16x16x32_bf16(A1, B1, acc[ct], 0, 0, 0);
  }
  __syncthreads();                                   // all Wf reads done
  // handoff: bias+relu -> H1b bf16 [64][136]; co-stage W2 frags
  #pragma unroll
  for (int ct = 0; ct < 8; ++ct) {
    int col = ct * 16 + (l & 15);
    float bb = b1[col];
    #pragma unroll
    for (int r = 0; r < 4; ++r) {
      int row = w * 16 + ((l >> 4) << 2) + r;
      H1b[row * 136 + col] = (unsigned short)f2bf(fmaxf(acc[ct][r] + bb, 0.f));
    }
  }
  for (int i = tid; i < 2048; i += 256) {
    int jh = i & 3, ll = (i >> 2) & 63, f = i >> 8;  // f = ctB*4 + ks
    int ks = f & 3, ctB = f >> 2;
    int k0  = ks * 32 + ((ll >> 4) << 3) + jh * 2;
    int col = ctB * 16 + (ll & 15);
    float w0 = W2[k0 * F2 + col];
    float w1 = W2[(k0 + 1) * F2 + col];
    Wf2u[i] = f2bf(w0) | (f2bf(w1) << 16);
  }
  __syncthreads();
  // phase B: MFMA over H1b
  float4v acc2[2];
  #pragma unroll
  for (int i = 0; i < 2; ++i)
    #pragma unroll
    for (int r = 0; r < 4; ++r) acc2[i][r] = 0.f;
  #pragma unroll
  for (int ks = 0; ks < 4; ++ks) {
    // A-frag: H1[row=w*16+(l&15)][k=ks*32+(l>>4)*8 ..+7]
    short8v Af = H1b8[(w * 16 + (l & 15)) * 17 + ks * 4 + (l >> 4)];
    acc2[0] = __builtin_amdgcn_mfma_f32_16x16x32_bf16(Af, Wf2_8[(0 * 4 + ks) * 64 + l], acc2[0], 0, 0, 0);
    acc2[1] = __builtin_amdgcn_mfma_f32_16x16x32_bf16(Af, Wf2_8[(1 * 4 + ks) * 64 + l], acc2[1], 0, 0, 0);
  }
  // epilogue: D layout col=l&15 (+16*ctB), row=w*16+(l>>4)*4+r
  #pragma unroll
  for (int r = 0; r < 4; ++r) {
    int n = row0 + w * 16 + ((l >> 4) << 2) + r;
    if (n < N) {
      float d = dinv[n];
      H2s16[(size_t)n * F2 + (l & 15)]      = (unsigned short)f2bf(acc2[0][r] * d);
      H2s16[(size_t)n * F2 + 16 + (l & 15)] = (unsigned short)f2bf(acc2[1][r] * d);
    }
  }
}

// ---- fused layer-2 aggregation + bias + head (bf16 gathers) ----
__global__ __launch_bounds__(256) void k_agg2h(const int* __restrict__ rowend,
    const int* __restrict__ cnt, const int* __restrict__ ssrc,
    const unsigned short* __restrict__ H2s16, const float* __restrict__ dinv,
    const float* __restrict__ b2, const float* __restrict__ Wc,
    const float* __restrict__ bc, float* __restrict__ h2,
    float* __restrict__ out) {
  __shared__ float Wcs[F2][F2];   // 4 KB
  __shared__ float h2row[4][F2];  // per-wave h2 row
  const int tid = threadIdx.x;
  for (int i = tid; i < F2 * F2; i += 256) Wcs[i >> 5][i & 31] = Wc[i];
  __syncthreads();
  int gw = (blockIdx.x * 256 + tid) >> 6;           // node (one wave each)
  int lane = tid & 63;
  int w = tid >> 6;                                 // wave slot in block
  if (gw >= N) return;
  int end   = __builtin_amdgcn_readfirstlane(rowend[gw]);
  int deg   = __builtin_amdgcn_readfirstlane(cnt[gw]);
  int start = end - deg;
  const int g = lane >> 2, fl = lane & 3;           // edge slot (16), feat octet
  const uint4* hv = reinterpret_cast<const uint4*>(H2s16);
  float acc[8];
  #pragma unroll
  for (int k = 0; k < 8; ++k) acc[k] = 0.f;
  for (int e0 = start; e0 < end; e0 += 16) {
    if (e0 + 16 <= end) {
      int s = ssrc[e0 + g];
      uint4 u = hv[(size_t)s * 4 + fl];
      acc[0] += bflo(u.x); acc[1] += bfhi(u.x);
      acc[2] += bflo(u.y); acc[3] += bfhi(u.y);
      acc[4] += bflo(u.z); acc[5] += bfhi(u.z);
      acc[6] += bflo(u.w); acc[7] += bfhi(u.w);
    } else {
      int j = e0 + g;
      int s = ssrc[(j < end) ? j : start];
      float mm = (j < end) ? 1.f : 0.f;
      uint4 u = hv[(size_t)s * 4 + fl];
      acc[0] = fmaf(bflo(u.x), mm, acc[0]); acc[1] = fmaf(bfhi(u.x), mm, acc[1]);
      acc[2] = fmaf(bflo(u.y), mm, acc[2]); acc[3] = fmaf(bfhi(u.y), mm, acc[3]);
      acc[4] = fmaf(bflo(u.z), mm, acc[4]); acc[5] = fmaf(bfhi(u.z), mm, acc[5]);
      acc[6] = fmaf(bflo(u.w), mm, acc[6]); acc[7] = fmaf(bfhi(u.w), mm, acc[7]);
    }
  }
  #pragma unroll
  for (int r = 4; r < 64; r <<= 1) {
    #pragma unroll
    for (int k = 0; k < 8; ++k) acc[k] += __shfl_xor(acc[k], r);
  }
  float dv = dinv[gw];
  if (lane < 4) {
    uint4 su = hv[(size_t)gw * 4 + fl];
    float o[8];
    o[0] = dv * (acc[0] + bflo(su.x)) + b2[fl * 8 + 0];
    o[1] = dv * (acc[1] + bfhi(su.x)) + b2[fl * 8 + 1];
    o[2] = dv * (acc[2] + bflo(su.y)) + b2[fl * 8 + 2];
    o[3] = dv * (acc[3] + bfhi(su.y)) + b2[fl * 8 + 3];
    o[4] = dv * (acc[4] + bflo(su.z)) + b2[fl * 8 + 4];
    o[5] = dv * (acc[5] + bfhi(su.z)) + b2[fl * 8 + 5];
    o[6] = dv * (acc[6] + bflo(su.w)) + b2[fl * 8 + 6];
    o[7] = dv * (acc[7] + bfhi(su.w)) + b2[fl * 8 + 7];
    *reinterpret_cast<float4*>(&h2[(size_t)gw * F2 + fl * 8])     = *reinterpret_cast<float4*>(o);
    *reinterpret_cast<float4*>(&h2[(size_t)gw * F2 + fl * 8 + 4]) = *reinterpret_cast<float4*>(o + 4);
    #pragma unroll
    for (int k = 0; k < 8; ++k) h2row[w][fl * 8 + k] = o[k];
  }
  int f = lane & 31, half = lane >> 5;
  float acco = 0.f;
  #pragma unroll
  for (int kk = 0; kk < 16; ++kk) {
    int k = kk + 16 * half;
    acco = fmaf(h2row[w][k], Wcs[k][f], acco);
  }
  acco += __shfl_xor(acco, 32);
  if (half == 0) out[(size_t)gw * F2 + f] = acco + bc[f];
}

extern "C" void kernel_launch(void* const* d_in, const int* in_sizes, int n_in,
                              void* d_out, int out_size, void* d_ws, size_t ws_size,
                              hipStream_t stream) {
  const float* x  = (const float*)d_in[0];
  const int*   ei = (const int*)d_in[1];
  const int*   src = ei;                 // edge_index[0]
  const int*   dst = ei + E;             // edge_index[1]
  const float* W1 = (const float*)d_in[2];
  const float* b1 = (const float*)d_in[3];
  const float* W2 = (const float*)d_in[4];
  const float* b2 = (const float*)d_in[5];
  const float* Wc = (const float*)d_in[6];
  const float* bc = (const float*)d_in[7];

  float* out = (float*)d_out;                    // [N, 32] logits
  float* h2  = out + (size_t)N * F2;             // [N, 32] hidden output

  // workspace layout (~30 MB of 256 MB) — all disjoint, no aliasing
  int*   cnt     = (int*)d_ws;                   // N
  int*   rowend  = cnt + N;                      // N
  int*   gcur    = rowend + N;                   // NBUK*NSEG*16 (line-padded)
  float* dinv    = (float*)(gcur + NBUK * NSEG * 16); // N
  int*   ssrc    = (int*)(dinv + N);             // NBUK*BCAP (padded)
  unsigned int* ebuf = (unsigned int*)(ssrc + NBUK * BCAP); // NBUK*BCAP
  unsigned short* xs16 = (unsigned short*)(ebuf + NBUK * BCAP); // N*64 bf16
  unsigned short* AX16 = xs16 + (size_t)N * F0;  // N*64 bf16
  unsigned short* H2s16 = AX16 + (size_t)N * F0; // N*32 bf16

  hipMemsetAsync(gcur, 0, NBUK * NSEG * 16 * sizeof(int), stream);
  k_bucket<<<NCHUNK, 512, 0, stream>>>(src, dst, gcur, ebuf);
  k_csr   <<<NBUK,   512, 0, stream>>>(ebuf, gcur, x, cnt, rowend, dinv, ssrc, xs16);

  k_agg1  <<<(N + 3) / 4, 256, 0, stream>>>(rowend, cnt, ssrc, xs16, dinv, AX16);
  k_gemm12<<<(N + 63) / 64, 256, 0, stream>>>(AX16, W1, b1, W2, dinv, H2s16);
  k_agg2h <<<(N + 3) / 4, 256, 0, stream>>>(rowend, cnt, ssrc, H2s16, dinv, b2, Wc, bc, h2, out);
}

// Round 18
// 97.818 us; speedup vs baseline: 1.5737x; 1.0398x over previous
//
#include <hip/hip_runtime.h>

// GCN forward: two GCNConv layers + linear head.
// Round 18: R17 + deeper gather MLP:
//   agg1: 32-edge steps (4 uint4 gathers in flight; same per-lane sum order)
//   agg2h: 32-edge steps (2 gathers in flight)
//   k_bucket: contiguous int4 edge reads on full chunks
// MFMA phases A+B in gemm12; bf16 arrays xs16/AX16/H2s16.
// 6 dispatches:
//   memset(gcur) -> k_bucket -> k_csr(+dinv+bf16 prescale) ->
//   k_agg1 -> k_gemm12 -> k_agg2h
// out = dinv[d] * sum_{s in N(d)+self} (dinv[s]*h[s]) per layer.

static constexpr int N  = 50000;
static constexpr int E  = 800000;
static constexpr int F0 = 64;    // input feats
static constexpr int F1 = 128;   // hidden
static constexpr int F2 = 32;    // classes

static constexpr int BSH    = 7;     // bucket = dst>>7 (128 nodes)
static constexpr int BNODES = 128;
static constexpr int BMASK  = 127;
static constexpr int NBUK   = 392;   // ceil(N/128)
static constexpr int NSEG   = 4;     // sub-cursors per bucket (chunk c -> c&3)
static constexpr int SEGCAP = 768;   // per-segment capacity (mean 514 + 11 sigma)
static constexpr int BCAP   = NSEG * SEGCAP;  // 3072
static constexpr int CHUNK  = 4096;  // edges per chunk
static constexpr int NCHUNK = 196;   // ceil(E/CHUNK)

typedef __attribute__((ext_vector_type(8))) short short8v;   // 8 bf16 (4 VGPRs)
typedef __attribute__((ext_vector_type(4))) float float4v;   // 4 f32 acc

__device__ __forceinline__ unsigned int f2bf(float f) {
  unsigned int u = __float_as_uint(f);
  return (u + 0x7fffu + ((u >> 16) & 1u)) >> 16;     // RNE
}
__device__ __forceinline__ float bflo(unsigned int u) {
  return __uint_as_float(u << 16);
}
__device__ __forceinline__ float bfhi(unsigned int u) {
  return __uint_as_float(u & 0xffff0000u);
}

// ---- B1: bucket-scatter; per-chunk LDS count + segmented global reservation ----
__global__ __launch_bounds__(512) void k_bucket(const int* __restrict__ src,
    const int* __restrict__ dst, int* __restrict__ gcur,
    unsigned int* __restrict__ ebuf) {
  __shared__ int hl[NBUK];
  int t = threadIdx.x, c = blockIdx.x;
  const int sub = c & (NSEG - 1);
  for (int i = t; i < NBUK; i += 512) hl[i] = 0;
  __syncthreads();
  int e0 = c * CHUNK, m = min(CHUNK, E - e0);
  int dreg[8];
  if (m == CHUNK) {
    const int4* dv4 = reinterpret_cast<const int4*>(dst + e0);
    int4 a = dv4[t * 2], b = dv4[t * 2 + 1];
    dreg[0] = a.x; dreg[1] = a.y; dreg[2] = a.z; dreg[3] = a.w;
    dreg[4] = b.x; dreg[5] = b.y; dreg[6] = b.z; dreg[7] = b.w;
    #pragma unroll
    for (int k = 0; k < 8; ++k) atomicAdd(&hl[dreg[k] >> BSH], 1);
  } else {
    #pragma unroll
    for (int k = 0; k < 8; ++k) {
      int i = t * 8 + k;
      dreg[k] = (i < m) ? dst[e0 + i] : -1;
      if (i < m) atomicAdd(&hl[dreg[k] >> BSH], 1);
    }
  }
  __syncthreads();
  for (int i = t; i < NBUK; i += 512) {
    int cc = hl[i];
    int rbase = (cc > 0) ? atomicAdd(&gcur[(i * NSEG + sub) * 16], cc) : 0;
    hl[i] = i * BCAP + sub * SEGCAP + rbase;         // LDS cursor for pass 2
  }
  __syncthreads();
  if (m == CHUNK) {
    const int4* sv4 = reinterpret_cast<const int4*>(src + e0);
    int4 a = sv4[t * 2], b = sv4[t * 2 + 1];
    int sreg[8] = {a.x, a.y, a.z, a.w, b.x, b.y, b.z, b.w};
    #pragma unroll
    for (int k = 0; k < 8; ++k) {
      int d = dreg[k];
      int pos = atomicAdd(&hl[d >> BSH], 1);         // LDS atomic
      ebuf[pos] = (unsigned int)sreg[k] | ((unsigned int)(d & BMASK) << 16);
    }
  } else {
    #pragma unroll
    for (int k = 0; k < 8; ++k) {
      int i = t * 8 + k;
      if (i < m) {
        int d = dreg[k], s = src[e0 + i];
        int pos = atomicAdd(&hl[d >> BSH], 1);       // LDS atomic
        ebuf[pos] = (unsigned int)s | ((unsigned int)(d & BMASK) << 16);
      }
    }
  }
}

// ---- B2: per-bucket CSR finalize + dinv + bf16 xs prescale ----
__global__ __launch_bounds__(512) void k_csr(const unsigned int* __restrict__ ebuf,
    const int* __restrict__ gcur, const float* __restrict__ x,
    int* __restrict__ cnt, int* __restrict__ rowend, float* __restrict__ dinv,
    int* __restrict__ ssrc, unsigned short* __restrict__ xs16) {
  __shared__ int cl[BNODES], sc[BNODES], cur[BNODES];
  __shared__ float dl[BNODES];
  int t = threadIdx.x, b = blockIdx.x;
  int base = b * BCAP;
  int node0 = b << BSH;
  int ms[NSEG];
  #pragma unroll
  for (int s = 0; s < NSEG; ++s) ms[s] = gcur[(b * NSEG + s) * 16];
  if (t < BNODES) cl[t] = 0;
  __syncthreads();
  unsigned int ereg[NSEG * 2];                       // SEGCAP=768 <= 2*512
  #pragma unroll
  for (int s = 0; s < NSEG; ++s) {
    int msz = ms[s], sb = base + s * SEGCAP;
    #pragma unroll
    for (int k = 0; k < 2; ++k) {
      int i = t + k * 512;
      unsigned int p = 0xFFFFFFFFu;                  // unreachable sentinel
      if (i < msz) {
        p = ebuf[sb + i];
        atomicAdd(&cl[(p >> 16) & BMASK], 1);
      }
      ereg[s * 2 + k] = p;
    }
  }
  __syncthreads();
  int v = 0;
  if (t < BNODES) { v = cl[t]; sc[t] = v; }
  __syncthreads();
  for (int off = 1; off < BNODES; off <<= 1) {
    int u = (t >= off && t < BNODES) ? sc[t - off] : 0;
    __syncthreads();
    if (t < BNODES) sc[t] += u;
    __syncthreads();
  }
  if (t < BNODES) {
    int excl = sc[t] - v;
    cur[t] = excl;
    float dv = rsqrtf((float)(v + 1));               // +1 self-loop
    dl[t] = dv;
    int g = node0 + t;
    if (g < N) {
      cnt[g]    = v;
      rowend[g] = base + excl + v;
      dinv[g]   = dv;
    }
  }
  __syncthreads();
  #pragma unroll
  for (int s = 0; s < NSEG; ++s) {
    #pragma unroll
    for (int k = 0; k < 2; ++k) {
      unsigned int p = ereg[s * 2 + k];
      if (p != 0xFFFFFFFFu) {
        int d = (p >> 16) & BMASK;
        int r = atomicAdd(&cur[d], 1);               // LDS atomic
        ssrc[base + r] = (int)(p & 0xFFFFu);
      }
    }
  }
  // fused prescale: xs16[n] = bf16(x[n] * dinv[n]); 8 feats per iteration
  for (int i = t; i < BNODES * (F0 / 8); i += 512) {
    int nl = i >> 3, oc = i & 7;
    int n = node0 + nl;
    if (n < N) {
      float4 a  = reinterpret_cast<const float4*>(x)[n * 16 + oc * 2];
      float4 bb = reinterpret_cast<const float4*>(x)[n * 16 + oc * 2 + 1];
      float d = dl[nl];
      uint4 pk;
      pk.x = f2bf(a.x * d)  | (f2bf(a.y * d) << 16);
      pk.y = f2bf(a.z * d)  | (f2bf(a.w * d) << 16);
      pk.z = f2bf(bb.x * d) | (f2bf(bb.y * d) << 16);
      pk.w = f2bf(bb.z * d) | (f2bf(bb.w * d) << 16);
      reinterpret_cast<uint4*>(xs16)[(size_t)n * 8 + oc] = pk;
    }
  }
}

// ---- layer-1 aggregation (bf16 gathers): AX16[n] = bf16(dinv[n]*(xs[n]+sum xs[s])) ----
// 32-edge steps: 4 uint4 gathers in flight per step.
__global__ __launch_bounds__(256) void k_agg1(const int* __restrict__ rowend,
    const int* __restrict__ cnt, const int* __restrict__ ssrc,
    const unsigned short* __restrict__ xs16, const float* __restrict__ dinv,
    unsigned short* __restrict__ AX16) {
  int gw = (blockIdx.x * 256 + threadIdx.x) >> 6;   // node (one wave each)
  int lane = threadIdx.x & 63;
  if (gw >= N) return;
  int end   = __builtin_amdgcn_readfirstlane(rowend[gw]);
  int deg   = __builtin_amdgcn_readfirstlane(cnt[gw]);
  int start = end - deg;
  const int g = lane >> 3, fl = lane & 7;           // edge slot, feat octet
  const uint4* xsv = reinterpret_cast<const uint4*>(xs16);
  float acc[8];
  #pragma unroll
  for (int k = 0; k < 8; ++k) acc[k] = 0.f;
  for (int e0 = start; e0 < end; e0 += 32) {
    if (e0 + 32 <= end) {
      int s0 = ssrc[e0 + g];
      int s1 = ssrc[e0 + 8 + g];
      int s2 = ssrc[e0 + 16 + g];
      int s3 = ssrc[e0 + 24 + g];
      uint4 u0 = xsv[(size_t)s0 * 8 + fl];
      uint4 u1 = xsv[(size_t)s1 * 8 + fl];
      uint4 u2 = xsv[(size_t)s2 * 8 + fl];
      uint4 u3 = xsv[(size_t)s3 * 8 + fl];
      acc[0] += bflo(u0.x); acc[1] += bfhi(u0.x);
      acc[2] += bflo(u0.y); acc[3] += bfhi(u0.y);
      acc[4] += bflo(u0.z); acc[5] += bfhi(u0.z);
      acc[6] += bflo(u0.w); acc[7] += bfhi(u0.w);
      acc[0] += bflo(u1.x); acc[1] += bfhi(u1.x);
      acc[2] += bflo(u1.y); acc[3] += bfhi(u1.y);
      acc[4] += bflo(u1.z); acc[5] += bfhi(u1.z);
      acc[6] += bflo(u1.w); acc[7] += bfhi(u1.w);
      acc[0] += bflo(u2.x); acc[1] += bfhi(u2.x);
      acc[2] += bflo(u2.y); acc[3] += bfhi(u2.y);
      acc[4] += bflo(u2.z); acc[5] += bfhi(u2.z);
      acc[6] += bflo(u2.w); acc[7] += bfhi(u2.w);
      acc[0] += bflo(u3.x); acc[1] += bfhi(u3.x);
      acc[2] += bflo(u3.y); acc[3] += bfhi(u3.y);
      acc[4] += bflo(u3.z); acc[5] += bfhi(u3.z);
      acc[6] += bflo(u3.w); acc[7] += bfhi(u3.w);
    } else {
      #pragma unroll
      for (int q = 0; q < 4; ++q) {
        int j = e0 + 8 * q + g;
        int s = ssrc[(j < end) ? j : start];
        float mm = (j < end) ? 1.f : 0.f;
        uint4 u = xsv[(size_t)s * 8 + fl];
        acc[0] = fmaf(bflo(u.x), mm, acc[0]); acc[1] = fmaf(bfhi(u.x), mm, acc[1]);
        acc[2] = fmaf(bflo(u.y), mm, acc[2]); acc[3] = fmaf(bfhi(u.y), mm, acc[3]);
        acc[4] = fmaf(bflo(u.z), mm, acc[4]); acc[5] = fmaf(bfhi(u.z), mm, acc[5]);
        acc[6] = fmaf(bflo(u.w), mm, acc[6]); acc[7] = fmaf(bfhi(u.w), mm, acc[7]);
      }
    }
  }
  #pragma unroll
  for (int r = 8; r < 64; r <<= 1) {
    #pragma unroll
    for (int k = 0; k < 8; ++k) acc[k] += __shfl_xor(acc[k], r);
  }
  if (lane < 8) {
    uint4 su = xsv[(size_t)gw * 8 + fl];
    float dv = dinv[gw];
    float o[8];
    o[0] = (acc[0] + bflo(su.x)) * dv; o[1] = (acc[1] + bfhi(su.x)) * dv;
    o[2] = (acc[2] + bflo(su.y)) * dv; o[3] = (acc[3] + bfhi(su.y)) * dv;
    o[4] = (acc[4] + bflo(su.z)) * dv; o[5] = (acc[5] + bfhi(su.z)) * dv;
    o[6] = (acc[6] + bflo(su.w)) * dv; o[7] = (acc[7] + bfhi(su.w)) * dv;
    uint4 pk;
    pk.x = f2bf(o[0]) | (f2bf(o[1]) << 16);
    pk.y = f2bf(o[2]) | (f2bf(o[3]) << 16);
    pk.z = f2bf(o[4]) | (f2bf(o[5]) << 16);
    pk.w = f2bf(o[6]) | (f2bf(o[7]) << 16);
    reinterpret_cast<uint4*>(AX16)[(size_t)gw * 8 + fl] = pk;
  }
}

// ---- fused GEMM1(MFMA)+relu+GEMM2(MFMA): H2s16 = bf16(relu(AX@W1+b1)@W2*dinv) ----
__global__ __launch_bounds__(256) void k_gemm12(const unsigned short* __restrict__ AX16,
    const float* __restrict__ W1, const float* __restrict__ b1,
    const float* __restrict__ W2, const float* __restrict__ dinv,
    unsigned short* __restrict__ H2s16) {
  __shared__ float arena[6656];            // 26624 B -> 6 blocks/CU
  unsigned int* Wfu = reinterpret_cast<unsigned int*>(arena);
  const short8v* Wf8 = reinterpret_cast<const short8v*>(arena);
  unsigned short* H1b = reinterpret_cast<unsigned short*>(arena);
  unsigned int* Wf2u = reinterpret_cast<unsigned int*>(arena + 4608);
  const short8v* Wf2_8 = reinterpret_cast<const short8v*>(arena + 4608);
  const short8v* H1b8 = reinterpret_cast<const short8v*>(arena);
  const int tid = threadIdx.x;
  const int row0 = blockIdx.x * 64;
  // stage W1 -> bf16 fragment order: frag f=ct*2+ks: k=ks*32+(l>>4)*8+j, col=ct*16+(l&15)
  for (int i = tid; i < 4096; i += 256) {
    int jh = i & 3, l = (i >> 2) & 63, f = i >> 8;
    int k0  = (f & 1) * 32 + ((l >> 4) << 3) + jh * 2;
    int col = (f >> 1) * 16 + (l & 15);
    float w0 = W1[k0 * F1 + col];
    float w1 = W1[(k0 + 1) * F1 + col];
    Wfu[i] = f2bf(w0) | (f2bf(w1) << 16);
  }
  __syncthreads();
  // phase A: MFMA
  const int w = tid >> 6, l = tid & 63;
  const int nrow = row0 + w * 16 + (l & 15);        // may read past N (masked later)
  const short8v* axv8 = reinterpret_cast<const short8v*>(AX16);
  short8v A0 = axv8[(size_t)nrow * 8 + (l >> 4)];
  short8v A1 = axv8[(size_t)nrow * 8 + 4 + (l >> 4)];
  float4v acc[8];
  #pragma unroll
  for (int ct = 0; ct < 8; ++ct)
    #pragma unroll
    for (int r = 0; r < 4; ++r) acc[ct][r] = 0.f;
  #pragma unroll
  for (int ct = 0; ct < 8; ++ct) {
    short8v B0 = Wf8[(ct * 2 + 0) * 64 + l];
    short8v B1 = Wf8[(ct * 2 + 1) * 64 + l];
    acc[ct] = __builtin_amdgcn_mfma_f32_16x16x32_bf16(A0, B0, acc[ct], 0, 0, 0);
    acc[ct] = __builtin_amdgcn_mfma_f32_16x16x32_bf16(A1, B1, acc[ct], 0, 0, 0);
  }
  __syncthreads();                                   // all Wf reads done
  // handoff: bias+relu -> H1b bf16 [64][136]; co-stage W2 frags
  #pragma unroll
  for (int ct = 0; ct < 8; ++ct) {
    int col = ct * 16 + (l & 15);
    float bb = b1[col];
    #pragma unroll
    for (int r = 0; r < 4; ++r) {
      int row = w * 16 + ((l >> 4) << 2) + r;
      H1b[row * 136 + col] = (unsigned short)f2bf(fmaxf(acc[ct][r] + bb, 0.f));
    }
  }
  for (int i = tid; i < 2048; i += 256) {
    int jh = i & 3, ll = (i >> 2) & 63, f = i >> 8;  // f = ctB*4 + ks
    int ks = f & 3, ctB = f >> 2;
    int k0  = ks * 32 + ((ll >> 4) << 3) + jh * 2;
    int col = ctB * 16 + (ll & 15);
    float w0 = W2[k0 * F2 + col];
    float w1 = W2[(k0 + 1) * F2 + col];
    Wf2u[i] = f2bf(w0) | (f2bf(w1) << 16);
  }
  __syncthreads();
  // phase B: MFMA over H1b
  float4v acc2[2];
  #pragma unroll
  for (int i = 0; i < 2; ++i)
    #pragma unroll
    for (int r = 0; r < 4; ++r) acc2[i][r] = 0.f;
  #pragma unroll
  for (int ks = 0; ks < 4; ++ks) {
    short8v Af = H1b8[(w * 16 + (l & 15)) * 17 + ks * 4 + (l >> 4)];
    acc2[0] = __builtin_amdgcn_mfma_f32_16x16x32_bf16(Af, Wf2_8[(0 * 4 + ks) * 64 + l], acc2[0], 0, 0, 0);
    acc2[1] = __builtin_amdgcn_mfma_f32_16x16x32_bf16(Af, Wf2_8[(1 * 4 + ks) * 64 + l], acc2[1], 0, 0, 0);
  }
  #pragma unroll
  for (int r = 0; r < 4; ++r) {
    int n = row0 + w * 16 + ((l >> 4) << 2) + r;
    if (n < N) {
      float d = dinv[n];
      H2s16[(size_t)n * F2 + (l & 15)]      = (unsigned short)f2bf(acc2[0][r] * d);
      H2s16[(size_t)n * F2 + 16 + (l & 15)] = (unsigned short)f2bf(acc2[1][r] * d);
    }
  }
}

// ---- fused layer-2 aggregation + bias + head (bf16 gathers, 32-edge steps) ----
__global__ __launch_bounds__(256) void k_agg2h(const int* __restrict__ rowend,
    const int* __restrict__ cnt, const int* __restrict__ ssrc,
    const unsigned short* __restrict__ H2s16, const float* __restrict__ dinv,
    const float* __restrict__ b2, const float* __restrict__ Wc,
    const float* __restrict__ bc, float* __restrict__ h2,
    float* __restrict__ out) {
  __shared__ float Wcs[F2][F2];   // 4 KB
  __shared__ float h2row[4][F2];  // per-wave h2 row
  const int tid = threadIdx.x;
  for (int i = tid; i < F2 * F2; i += 256) Wcs[i >> 5][i & 31] = Wc[i];
  __syncthreads();
  int gw = (blockIdx.x * 256 + tid) >> 6;           // node (one wave each)
  int lane = tid & 63;
  int w = tid >> 6;                                 // wave slot in block
  if (gw >= N) return;
  int end   = __builtin_amdgcn_readfirstlane(rowend[gw]);
  int deg   = __builtin_amdgcn_readfirstlane(cnt[gw]);
  int start = end - deg;
  const int g = lane >> 2, fl = lane & 3;           // edge slot (16), feat octet
  const uint4* hv = reinterpret_cast<const uint4*>(H2s16);
  float acc[8];
  #pragma unroll
  for (int k = 0; k < 8; ++k) acc[k] = 0.f;
  for (int e0 = start; e0 < end; e0 += 32) {
    if (e0 + 32 <= end) {
      int s0 = ssrc[e0 + g];
      int s1 = ssrc[e0 + 16 + g];
      uint4 u0 = hv[(size_t)s0 * 4 + fl];
      uint4 u1 = hv[(size_t)s1 * 4 + fl];
      acc[0] += bflo(u0.x); acc[1] += bfhi(u0.x);
      acc[2] += bflo(u0.y); acc[3] += bfhi(u0.y);
      acc[4] += bflo(u0.z); acc[5] += bfhi(u0.z);
      acc[6] += bflo(u0.w); acc[7] += bfhi(u0.w);
      acc[0] += bflo(u1.x); acc[1] += bfhi(u1.x);
      acc[2] += bflo(u1.y); acc[3] += bfhi(u1.y);
      acc[4] += bflo(u1.z); acc[5] += bfhi(u1.z);
      acc[6] += bflo(u1.w); acc[7] += bfhi(u1.w);
    } else {
      #pragma unroll
      for (int q = 0; q < 2; ++q) {
        int j = e0 + 16 * q + g;
        int s = ssrc[(j < end) ? j : start];
        float mm = (j < end) ? 1.f : 0.f;
        uint4 u = hv[(size_t)s * 4 + fl];
        acc[0] = fmaf(bflo(u.x), mm, acc[0]); acc[1] = fmaf(bfhi(u.x), mm, acc[1]);
        acc[2] = fmaf(bflo(u.y), mm, acc[2]); acc[3] = fmaf(bfhi(u.y), mm, acc[3]);
        acc[4] = fmaf(bflo(u.z), mm, acc[4]); acc[5] = fmaf(bfhi(u.z), mm, acc[5]);
        acc[6] = fmaf(bflo(u.w), mm, acc[6]); acc[7] = fmaf(bfhi(u.w), mm, acc[7]);
      }
    }
  }
  #pragma unroll
  for (int r = 4; r < 64; r <<= 1) {
    #pragma unroll
    for (int k = 0; k < 8; ++k) acc[k] += __shfl_xor(acc[k], r);
  }
  float dv = dinv[gw];
  if (lane < 4) {
    uint4 su = hv[(size_t)gw * 4 + fl];
    float o[8];
    o[0] = dv * (acc[0] + bflo(su.x)) + b2[fl * 8 + 0];
    o[1] = dv * (acc[1] + bfhi(su.x)) + b2[fl * 8 + 1];
    o[2] = dv * (acc[2] + bflo(su.y)) + b2[fl * 8 + 2];
    o[3] = dv * (acc[3] + bfhi(su.y)) + b2[fl * 8 + 3];
    o[4] = dv * (acc[4] + bflo(su.z)) + b2[fl * 8 + 4];
    o[5] = dv * (acc[5] + bfhi(su.z)) + b2[fl * 8 + 5];
    o[6] = dv * (acc[6] + bflo(su.w)) + b2[fl * 8 + 6];
    o[7] = dv * (acc[7] + bfhi(su.w)) + b2[fl * 8 + 7];
    *reinterpret_cast<float4*>(&h2[(size_t)gw * F2 + fl * 8])     = *reinterpret_cast<float4*>(o);
    *reinterpret_cast<float4*>(&h2[(size_t)gw * F2 + fl * 8 + 4]) = *reinterpret_cast<float4*>(o + 4);
    #pragma unroll
    for (int k = 0; k < 8; ++k) h2row[w][fl * 8 + k] = o[k];
  }
  int f = lane & 31, half = lane >> 5;
  float acco = 0.f;
  #pragma unroll
  for (int kk = 0; kk < 16; ++kk) {
    int k = kk + 16 * half;
    acco = fmaf(h2row[w][k], Wcs[k][f], acco);
  }
  acco += __shfl_xor(acco, 32);
  if (half == 0) out[(size_t)gw * F2 + f] = acco + bc[f];
}

extern "C" void kernel_launch(void* const* d_in, const int* in_sizes, int n_in,
                              void* d_out, int out_size, void* d_ws, size_t ws_size,
                              hipStream_t stream) {
  const float* x  = (const float*)d_in[0];
  const int*   ei = (const int*)d_in[1];
  const int*   src = ei;                 // edge_index[0]
  const int*   dst = ei + E;             // edge_index[1]
  const float* W1 = (const float*)d_in[2];
  const float* b1 = (const float*)d_in[3];
  const float* W2 = (const float*)d_in[4];
  const float* b2 = (const float*)d_in[5];
  const float* Wc = (const float*)d_in[6];
  const float* bc = (const float*)d_in[7];

  float* out = (float*)d_out;                    // [N, 32] logits
  float* h2  = out + (size_t)N * F2;             // [N, 32] hidden output

  // workspace layout (~30 MB of 256 MB) — all disjoint, no aliasing
  int*   cnt     = (int*)d_ws;                   // N
  int*   rowend  = cnt + N;                      // N
  int*   gcur    = rowend + N;                   // NBUK*NSEG*16 (line-padded)
  float* dinv    = (float*)(gcur + NBUK * NSEG * 16); // N
  int*   ssrc    = (int*)(dinv + N);             // NBUK*BCAP (padded)
  unsigned int* ebuf = (unsigned int*)(ssrc + NBUK * BCAP); // NBUK*BCAP
  unsigned short* xs16 = (unsigned short*)(ebuf + NBUK * BCAP); // N*64 bf16
  unsigned short* AX16 = xs16 + (size_t)N * F0;  // N*64 bf16
  unsigned short* H2s16 = AX16 + (size_t)N * F0; // N*32 bf16

  hipMemsetAsync(gcur, 0, NBUK * NSEG * 16 * sizeof(int), stream);
  k_bucket<<<NCHUNK, 512, 0, stream>>>(src, dst, gcur, ebuf);
  k_csr   <<<NBUK,   512, 0, stream>>>(ebuf, gcur, x, cnt, rowend, dinv, ssrc, xs16);

  k_agg1  <<<(N + 3) / 4, 256, 0, stream>>>(rowend, cnt, ssrc, xs16, dinv, AX16);
  k_gemm12<<<(N + 63) / 64, 256, 0, stream>>>(AX16, W1, b1, W2, dinv, H2s16);
  k_agg2h <<<(N + 3) / 4, 256, 0, stream>>>(rowend, cnt, ssrc, H2s16, dinv, b2, Wc, bc, h2, out);
}

// Round 19
// 93.002 us; speedup vs baseline: 1.6552x; 1.0518x over previous
//
#include <hip/hip_runtime.h>

// GCN forward: two GCNConv layers + linear head.
// Round 19: R18 + build restructure: fixed-capacity per-(bucket,chunk) ebuf
// regions (CCAP=44). k_bucket: non-atomic hist counts (no memset, no global
// atomics, pure LDS cursors). k_csr: 196-count LDS scan + compact bucket edges
// into LDS, then count/scan/permute from LDS. ssrc layout unchanged.
// 5 dispatches:
//   k_bucket -> k_csr(+dinv+bf16 prescale) -> k_agg1 -> k_gemm12 -> k_agg2h
// out = dinv[d] * sum_{s in N(d)+self} (dinv[s]*h[s]) per layer.

static constexpr int N  = 50000;
static constexpr int E  = 800000;
static constexpr int F0 = 64;    // input feats
static constexpr int F1 = 128;   // hidden
static constexpr int F2 = 32;    // classes

static constexpr int BSH    = 7;     // bucket = dst>>7 (128 nodes)
static constexpr int BNODES = 128;
static constexpr int BMASK  = 127;
static constexpr int NBUK   = 392;   // ceil(N/128)
static constexpr int CHUNK  = 4096;  // edges per chunk
static constexpr int NCHUNK = 196;   // ceil(E/CHUNK)
static constexpr int CCAP   = 44;    // per-(bucket,chunk) capacity (mean 10.45, ~1e-13 tail)
static constexpr int BCAP   = 3072;  // per-bucket ssrc capacity (mean 2041 + 22 sigma)

typedef __attribute__((ext_vector_type(8))) short short8v;   // 8 bf16 (4 VGPRs)
typedef __attribute__((ext_vector_type(4))) float float4v;   // 4 f32 acc

__device__ __forceinline__ unsigned int f2bf(float f) {
  unsigned int u = __float_as_uint(f);
  return (u + 0x7fffu + ((u >> 16) & 1u)) >> 16;     // RNE
}
__device__ __forceinline__ float bflo(unsigned int u) {
  return __uint_as_float(u << 16);
}
__device__ __forceinline__ float bfhi(unsigned int u) {
  return __uint_as_float(u & 0xffff0000u);
}

// ---- B1: bucket-scatter into fixed (bucket,chunk) regions; counts non-atomic ----
__global__ __launch_bounds__(512) void k_bucket(const int* __restrict__ src,
    const int* __restrict__ dst, int* __restrict__ hist,
    unsigned int* __restrict__ ebuf) {
  __shared__ int hl[NBUK];
  int t = threadIdx.x, c = blockIdx.x;
  for (int i = t; i < NBUK; i += 512) hl[i] = 0;
  __syncthreads();
  int e0 = c * CHUNK, m = min(CHUNK, E - e0);
  int dreg[8];
  if (m == CHUNK) {
    const int4* dv4 = reinterpret_cast<const int4*>(dst + e0);
    int4 a = dv4[t * 2], b = dv4[t * 2 + 1];
    dreg[0] = a.x; dreg[1] = a.y; dreg[2] = a.z; dreg[3] = a.w;
    dreg[4] = b.x; dreg[5] = b.y; dreg[6] = b.z; dreg[7] = b.w;
    #pragma unroll
    for (int k = 0; k < 8; ++k) atomicAdd(&hl[dreg[k] >> BSH], 1);
  } else {
    #pragma unroll
    for (int k = 0; k < 8; ++k) {
      int i = t * 8 + k;
      dreg[k] = (i < m) ? dst[e0 + i] : -1;
      if (i < m) atomicAdd(&hl[dreg[k] >> BSH], 1);
    }
  }
  __syncthreads();
  for (int i = t; i < NBUK; i += 512) {
    hist[i * NCHUNK + c] = hl[i];                    // non-atomic count write
    hl[i] = (i * NCHUNK + c) * CCAP;                 // fixed region base -> cursor
  }
  __syncthreads();
  if (m == CHUNK) {
    const int4* sv4 = reinterpret_cast<const int4*>(src + e0);
    int4 a = sv4[t * 2], b = sv4[t * 2 + 1];
    int sreg[8] = {a.x, a.y, a.z, a.w, b.x, b.y, b.z, b.w};
    #pragma unroll
    for (int k = 0; k < 8; ++k) {
      int d = dreg[k];
      int pos = atomicAdd(&hl[d >> BSH], 1);         // LDS atomic
      ebuf[pos] = (unsigned int)sreg[k] | ((unsigned int)(d & BMASK) << 16);
    }
  } else {
    #pragma unroll
    for (int k = 0; k < 8; ++k) {
      int i = t * 8 + k;
      if (i < m) {
        int d = dreg[k], s = src[e0 + i];
        int pos = atomicAdd(&hl[d >> BSH], 1);       // LDS atomic
        ebuf[pos] = (unsigned int)s | ((unsigned int)(d & BMASK) << 16);
      }
    }
  }
}

// ---- B2: per-bucket CSR finalize + dinv + bf16 xs prescale ----
// Scans this bucket's 196 chunk counts, compacts valid entries into LDS,
// then count/scan/permute entirely from LDS. ssrc layout: base = b*BCAP.
__global__ __launch_bounds__(512) void k_csr(const unsigned int* __restrict__ ebuf,
    const int* __restrict__ hist, const float* __restrict__ x,
    int* __restrict__ cnt, int* __restrict__ rowend, float* __restrict__ dinv,
    int* __restrict__ ssrc, unsigned short* __restrict__ xs16) {
  __shared__ int s512[512];
  __shared__ unsigned int eb[BCAP];                  // 12 KB compacted edges
  __shared__ int cl[BNODES], sc[BNODES], cur[BNODES];
  __shared__ float dl[BNODES];
  int t = threadIdx.x, b = blockIdx.x;
  int base = b * BCAP;
  int node0 = b << BSH;
  int cntc = (t < NCHUNK) ? hist[b * NCHUNK + t] : 0;
  s512[t] = cntc; __syncthreads();
  for (int off = 1; off < 512; off <<= 1) {
    int u = (t >= off) ? s512[t - off] : 0;
    __syncthreads(); s512[t] += u; __syncthreads();
  }
  int pref = s512[t] - cntc;
  int m = s512[511];                                 // bucket total
  if (t < BNODES) cl[t] = 0;
  // compact: thread t copies its chunk's region into eb[pref..]
  if (t < NCHUNK && cntc > 0) {
    const unsigned int* rp = ebuf + ((size_t)b * NCHUNK + t) * CCAP;
    for (int i = 0; i < cntc; ++i) eb[pref + i] = rp[i];
  }
  __syncthreads();
  for (int i = t; i < m; i += 512)
    atomicAdd(&cl[(eb[i] >> 16) & BMASK], 1);
  __syncthreads();
  int v = 0;
  if (t < BNODES) { v = cl[t]; sc[t] = v; }
  __syncthreads();
  for (int off = 1; off < BNODES; off <<= 1) {
    int u = (t >= off && t < BNODES) ? sc[t - off] : 0;
    __syncthreads();
    if (t < BNODES) sc[t] += u;
    __syncthreads();
  }
  if (t < BNODES) {
    int excl = sc[t] - v;
    cur[t] = excl;
    float dv = rsqrtf((float)(v + 1));               // +1 self-loop
    dl[t] = dv;
    int g = node0 + t;
    if (g < N) {
      cnt[g]    = v;
      rowend[g] = base + excl + v;
      dinv[g]   = dv;
    }
  }
  __syncthreads();
  for (int i = t; i < m; i += 512) {
    unsigned int p = eb[i];
    int d = (p >> 16) & BMASK;
    int r = atomicAdd(&cur[d], 1);                   // LDS atomic
    ssrc[base + r] = (int)(p & 0xFFFFu);
  }
  // fused prescale: xs16[n] = bf16(x[n] * dinv[n]); 8 feats per iteration
  for (int i = t; i < BNODES * (F0 / 8); i += 512) {
    int nl = i >> 3, oc = i & 7;
    int n = node0 + nl;
    if (n < N) {
      float4 a  = reinterpret_cast<const float4*>(x)[n * 16 + oc * 2];
      float4 bb = reinterpret_cast<const float4*>(x)[n * 16 + oc * 2 + 1];
      float d = dl[nl];
      uint4 pk;
      pk.x = f2bf(a.x * d)  | (f2bf(a.y * d) << 16);
      pk.y = f2bf(a.z * d)  | (f2bf(a.w * d) << 16);
      pk.z = f2bf(bb.x * d) | (f2bf(bb.y * d) << 16);
      pk.w = f2bf(bb.z * d) | (f2bf(bb.w * d) << 16);
      reinterpret_cast<uint4*>(xs16)[(size_t)n * 8 + oc] = pk;
    }
  }
}

// ---- layer-1 aggregation (bf16 gathers): AX16[n] = bf16(dinv[n]*(xs[n]+sum xs[s])) ----
// 32-edge steps: 4 uint4 gathers in flight per step.
__global__ __launch_bounds__(256) void k_agg1(const int* __restrict__ rowend,
    const int* __restrict__ cnt, const int* __restrict__ ssrc,
    const unsigned short* __restrict__ xs16, const float* __restrict__ dinv,
    unsigned short* __restrict__ AX16) {
  int gw = (blockIdx.x * 256 + threadIdx.x) >> 6;   // node (one wave each)
  int lane = threadIdx.x & 63;
  if (gw >= N) return;
  int end   = __builtin_amdgcn_readfirstlane(rowend[gw]);
  int deg   = __builtin_amdgcn_readfirstlane(cnt[gw]);
  int start = end - deg;
  const int g = lane >> 3, fl = lane & 7;           // edge slot, feat octet
  const uint4* xsv = reinterpret_cast<const uint4*>(xs16);
  float acc[8];
  #pragma unroll
  for (int k = 0; k < 8; ++k) acc[k] = 0.f;
  for (int e0 = start; e0 < end; e0 += 32) {
    if (e0 + 32 <= end) {
      int s0 = ssrc[e0 + g];
      int s1 = ssrc[e0 + 8 + g];
      int s2 = ssrc[e0 + 16 + g];
      int s3 = ssrc[e0 + 24 + g];
      uint4 u0 = xsv[(size_t)s0 * 8 + fl];
      uint4 u1 = xsv[(size_t)s1 * 8 + fl];
      uint4 u2 = xsv[(size_t)s2 * 8 + fl];
      uint4 u3 = xsv[(size_t)s3 * 8 + fl];
      acc[0] += bflo(u0.x); acc[1] += bfhi(u0.x);
      acc[2] += bflo(u0.y); acc[3] += bfhi(u0.y);
      acc[4] += bflo(u0.z); acc[5] += bfhi(u0.z);
      acc[6] += bflo(u0.w); acc[7] += bfhi(u0.w);
      acc[0] += bflo(u1.x); acc[1] += bfhi(u1.x);
      acc[2] += bflo(u1.y); acc[3] += bfhi(u1.y);
      acc[4] += bflo(u1.z); acc[5] += bfhi(u1.z);
      acc[6] += bflo(u1.w); acc[7] += bfhi(u1.w);
      acc[0] += bflo(u2.x); acc[1] += bfhi(u2.x);
      acc[2] += bflo(u2.y); acc[3] += bfhi(u2.y);
      acc[4] += bflo(u2.z); acc[5] += bfhi(u2.z);
      acc[6] += bflo(u2.w); acc[7] += bfhi(u2.w);
      acc[0] += bflo(u3.x); acc[1] += bfhi(u3.x);
      acc[2] += bflo(u3.y); acc[3] += bfhi(u3.y);
      acc[4] += bflo(u3.z); acc[5] += bfhi(u3.z);
      acc[6] += bflo(u3.w); acc[7] += bfhi(u3.w);
    } else {
      #pragma unroll
      for (int q = 0; q < 4; ++q) {
        int j = e0 + 8 * q + g;
        int s = ssrc[(j < end) ? j : start];
        float mm = (j < end) ? 1.f : 0.f;
        uint4 u = xsv[(size_t)s * 8 + fl];
        acc[0] = fmaf(bflo(u.x), mm, acc[0]); acc[1] = fmaf(bfhi(u.x), mm, acc[1]);
        acc[2] = fmaf(bflo(u.y), mm, acc[2]); acc[3] = fmaf(bfhi(u.y), mm, acc[3]);
        acc[4] = fmaf(bflo(u.z), mm, acc[4]); acc[5] = fmaf(bfhi(u.z), mm, acc[5]);
        acc[6] = fmaf(bflo(u.w), mm, acc[6]); acc[7] = fmaf(bfhi(u.w), mm, acc[7]);
      }
    }
  }
  #pragma unroll
  for (int r = 8; r < 64; r <<= 1) {
    #pragma unroll
    for (int k = 0; k < 8; ++k) acc[k] += __shfl_xor(acc[k], r);
  }
  if (lane < 8) {
    uint4 su = xsv[(size_t)gw * 8 + fl];
    float dv = dinv[gw];
    float o[8];
    o[0] = (acc[0] + bflo(su.x)) * dv; o[1] = (acc[1] + bfhi(su.x)) * dv;
    o[2] = (acc[2] + bflo(su.y)) * dv; o[3] = (acc[3] + bfhi(su.y)) * dv;
    o[4] = (acc[4] + bflo(su.z)) * dv; o[5] = (acc[5] + bfhi(su.z)) * dv;
    o[6] = (acc[6] + bflo(su.w)) * dv; o[7] = (acc[7] + bfhi(su.w)) * dv;
    uint4 pk;
    pk.x = f2bf(o[0]) | (f2bf(o[1]) << 16);
    pk.y = f2bf(o[2]) | (f2bf(o[3]) << 16);
    pk.z = f2bf(o[4]) | (f2bf(o[5]) << 16);
    pk.w = f2bf(o[6]) | (f2bf(o[7]) << 16);
    reinterpret_cast<uint4*>(AX16)[(size_t)gw * 8 + fl] = pk;
  }
}

// ---- fused GEMM1(MFMA)+relu+GEMM2(MFMA): H2s16 = bf16(relu(AX@W1+b1)@W2*dinv) ----
__global__ __launch_bounds__(256) void k_gemm12(const unsigned short* __restrict__ AX16,
    const float* __restrict__ W1, const float* __restrict__ b1,
    const float* __restrict__ W2, const float* __restrict__ dinv,
    unsigned short* __restrict__ H2s16) {
  __shared__ float arena[6656];            // 26624 B -> 6 blocks/CU
  unsigned int* Wfu = reinterpret_cast<unsigned int*>(arena);
  const short8v* Wf8 = reinterpret_cast<const short8v*>(arena);
  unsigned short* H1b = reinterpret_cast<unsigned short*>(arena);
  unsigned int* Wf2u = reinterpret_cast<unsigned int*>(arena + 4608);
  const short8v* Wf2_8 = reinterpret_cast<const short8v*>(arena + 4608);
  const short8v* H1b8 = reinterpret_cast<const short8v*>(arena);
  const int tid = threadIdx.x;
  const int row0 = blockIdx.x * 64;
  // stage W1 -> bf16 fragment order: frag f=ct*2+ks: k=ks*32+(l>>4)*8+j, col=ct*16+(l&15)
  for (int i = tid; i < 4096; i += 256) {
    int jh = i & 3, l = (i >> 2) & 63, f = i >> 8;
    int k0  = (f & 1) * 32 + ((l >> 4) << 3) + jh * 2;
    int col = (f >> 1) * 16 + (l & 15);
    float w0 = W1[k0 * F1 + col];
    float w1 = W1[(k0 + 1) * F1 + col];
    Wfu[i] = f2bf(w0) | (f2bf(w1) << 16);
  }
  __syncthreads();
  // phase A: MFMA
  const int w = tid >> 6, l = tid & 63;
  const int nrow = row0 + w * 16 + (l & 15);        // may read past N (masked later)
  const short8v* axv8 = reinterpret_cast<const short8v*>(AX16);
  short8v A0 = axv8[(size_t)nrow * 8 + (l >> 4)];
  short8v A1 = axv8[(size_t)nrow * 8 + 4 + (l >> 4)];
  float4v acc[8];
  #pragma unroll
  for (int ct = 0; ct < 8; ++ct)
    #pragma unroll
    for (int r = 0; r < 4; ++r) acc[ct][r] = 0.f;
  #pragma unroll
  for (int ct = 0; ct < 8; ++ct) {
    short8v B0 = Wf8[(ct * 2 + 0) * 64 + l];
    short8v B1 = Wf8[(ct * 2 + 1) * 64 + l];
    acc[ct] = __builtin_amdgcn_mfma_f32_16x16x32_bf16(A0, B0, acc[ct], 0, 0, 0);
    acc[ct] = __builtin_amdgcn_mfma_f32_16x16x32_bf16(A1, B1, acc[ct], 0, 0, 0);
  }
  __syncthreads();                                   // all Wf reads done
  // handoff: bias+relu -> H1b bf16 [64][136]; co-stage W2 frags
  #pragma unroll
  for (int ct = 0; ct < 8; ++ct) {
    int col = ct * 16 + (l & 15);
    float bb = b1[col];
    #pragma unroll
    for (int r = 0; r < 4; ++r) {
      int row = w * 16 + ((l >> 4) << 2) + r;
      H1b[row * 136 + col] = (unsigned short)f2bf(fmaxf(acc[ct][r] + bb, 0.f));
    }
  }
  for (int i = tid; i < 2048; i += 256) {
    int jh = i & 3, ll = (i >> 2) & 63, f = i >> 8;  // f = ctB*4 + ks
    int ks = f & 3, ctB = f >> 2;
    int k0  = ks * 32 + ((ll >> 4) << 3) + jh * 2;
    int col = ctB * 16 + (ll & 15);
    float w0 = W2[k0 * F2 + col];
    float w1 = W2[(k0 + 1) * F2 + col];
    Wf2u[i] = f2bf(w0) | (f2bf(w1) << 16);
  }
  __syncthreads();
  // phase B: MFMA over H1b
  float4v acc2[2];
  #pragma unroll
  for (int i = 0; i < 2; ++i)
    #pragma unroll
    for (int r = 0; r < 4; ++r) acc2[i][r] = 0.f;
  #pragma unroll
  for (int ks = 0; ks < 4; ++ks) {
    short8v Af = H1b8[(w * 16 + (l & 15)) * 17 + ks * 4 + (l >> 4)];
    acc2[0] = __builtin_amdgcn_mfma_f32_16x16x32_bf16(Af, Wf2_8[(0 * 4 + ks) * 64 + l], acc2[0], 0, 0, 0);
    acc2[1] = __builtin_amdgcn_mfma_f32_16x16x32_bf16(Af, Wf2_8[(1 * 4 + ks) * 64 + l], acc2[1], 0, 0, 0);
  }
  #pragma unroll
  for (int r = 0; r < 4; ++r) {
    int n = row0 + w * 16 + ((l >> 4) << 2) + r;
    if (n < N) {
      float d = dinv[n];
      H2s16[(size_t)n * F2 + (l & 15)]      = (unsigned short)f2bf(acc2[0][r] * d);
      H2s16[(size_t)n * F2 + 16 + (l & 15)] = (unsigned short)f2bf(acc2[1][r] * d);
    }
  }
}

// ---- fused layer-2 aggregation + bias + head (bf16 gathers, 32-edge steps) ----
__global__ __launch_bounds__(256) void k_agg2h(const int* __restrict__ rowend,
    const int* __restrict__ cnt, const int* __restrict__ ssrc,
    const unsigned short* __restrict__ H2s16, const float* __restrict__ dinv,
    const float* __restrict__ b2, const float* __restrict__ Wc,
    const float* __restrict__ bc, float* __restrict__ h2,
    float* __restrict__ out) {
  __shared__ float Wcs[F2][F2];   // 4 KB
  __shared__ float h2row[4][F2];  // per-wave h2 row
  const int tid = threadIdx.x;
  for (int i = tid; i < F2 * F2; i += 256) Wcs[i >> 5][i & 31] = Wc[i];
  __syncthreads();
  int gw = (blockIdx.x * 256 + tid) >> 6;           // node (one wave each)
  int lane = tid & 63;
  int w = tid >> 6;                                 // wave slot in block
  if (gw >= N) return;
  int end   = __builtin_amdgcn_readfirstlane(rowend[gw]);
  int deg   = __builtin_amdgcn_readfirstlane(cnt[gw]);
  int start = end - deg;
  const int g = lane >> 2, fl = lane & 3;           // edge slot (16), feat octet
  const uint4* hv = reinterpret_cast<const uint4*>(H2s16);
  float acc[8];
  #pragma unroll
  for (int k = 0; k < 8; ++k) acc[k] = 0.f;
  for (int e0 = start; e0 < end; e0 += 32) {
    if (e0 + 32 <= end) {
      int s0 = ssrc[e0 + g];
      int s1 = ssrc[e0 + 16 + g];
      uint4 u0 = hv[(size_t)s0 * 4 + fl];
      uint4 u1 = hv[(size_t)s1 * 4 + fl];
      acc[0] += bflo(u0.x); acc[1] += bfhi(u0.x);
      acc[2] += bflo(u0.y); acc[3] += bfhi(u0.y);
      acc[4] += bflo(u0.z); acc[5] += bfhi(u0.z);
      acc[6] += bflo(u0.w); acc[7] += bfhi(u0.w);
      acc[0] += bflo(u1.x); acc[1] += bfhi(u1.x);
      acc[2] += bflo(u1.y); acc[3] += bfhi(u1.y);
      acc[4] += bflo(u1.z); acc[5] += bfhi(u1.z);
      acc[6] += bflo(u1.w); acc[7] += bfhi(u1.w);
    } else {
      #pragma unroll
      for (int q = 0; q < 2; ++q) {
        int j = e0 + 16 * q + g;
        int s = ssrc[(j < end) ? j : start];
        float mm = (j < end) ? 1.f : 0.f;
        uint4 u = hv[(size_t)s * 4 + fl];
        acc[0] = fmaf(bflo(u.x), mm, acc[0]); acc[1] = fmaf(bfhi(u.x), mm, acc[1]);
        acc[2] = fmaf(bflo(u.y), mm, acc[2]); acc[3] = fmaf(bfhi(u.y), mm, acc[3]);
        acc[4] = fmaf(bflo(u.z), mm, acc[4]); acc[5] = fmaf(bfhi(u.z), mm, acc[5]);
        acc[6] = fmaf(bflo(u.w), mm, acc[6]); acc[7] = fmaf(bfhi(u.w), mm, acc[7]);
      }
    }
  }
  #pragma unroll
  for (int r = 4; r < 64; r <<= 1) {
    #pragma unroll
    for (int k = 0; k < 8; ++k) acc[k] += __shfl_xor(acc[k], r);
  }
  float dv = dinv[gw];
  if (lane < 4) {
    uint4 su = hv[(size_t)gw * 4 + fl];
    float o[8];
    o[0] = dv * (acc[0] + bflo(su.x)) + b2[fl * 8 + 0];
    o[1] = dv * (acc[1] + bfhi(su.x)) + b2[fl * 8 + 1];
    o[2] = dv * (acc[2] + bflo(su.y)) + b2[fl * 8 + 2];
    o[3] = dv * (acc[3] + bfhi(su.y)) + b2[fl * 8 + 3];
    o[4] = dv * (acc[4] + bflo(su.z)) + b2[fl * 8 + 4];
    o[5] = dv * (acc[5] + bfhi(su.z)) + b2[fl * 8 + 5];
    o[6] = dv * (acc[6] + bflo(su.w)) + b2[fl * 8 + 6];
    o[7] = dv * (acc[7] + bfhi(su.w)) + b2[fl * 8 + 7];
    *reinterpret_cast<float4*>(&h2[(size_t)gw * F2 + fl * 8])     = *reinterpret_cast<float4*>(o);
    *reinterpret_cast<float4*>(&h2[(size_t)gw * F2 + fl * 8 + 4]) = *reinterpret_cast<float4*>(o + 4);
    #pragma unroll
    for (int k = 0; k < 8; ++k) h2row[w][fl * 8 + k] = o[k];
  }
  int f = lane & 31, half = lane >> 5;
  float acco = 0.f;
  #pragma unroll
  for (int kk = 0; kk < 16; ++kk) {
    int k = kk + 16 * half;
    acco = fmaf(h2row[w][k], Wcs[k][f], acco);
  }
  acco += __shfl_xor(acco, 32);
  if (half == 0) out[(size_t)gw * F2 + f] = acco + bc[f];
}

extern "C" void kernel_launch(void* const* d_in, const int* in_sizes, int n_in,
                              void* d_out, int out_size, void* d_ws, size_t ws_size,
                              hipStream_t stream) {
  const float* x  = (const float*)d_in[0];
  const int*   ei = (const int*)d_in[1];
  const int*   src = ei;                 // edge_index[0]
  const int*   dst = ei + E;             // edge_index[1]
  const float* W1 = (const float*)d_in[2];
  const float* b1 = (const float*)d_in[3];
  const float* W2 = (const float*)d_in[4];
  const float* b2 = (const float*)d_in[5];
  const float* Wc = (const float*)d_in[6];
  const float* bc = (const float*)d_in[7];

  float* out = (float*)d_out;                    // [N, 32] logits
  float* h2  = out + (size_t)N * F2;             // [N, 32] hidden output

  // workspace layout (~45 MB of 256 MB) — all disjoint, no aliasing
  int*   cnt     = (int*)d_ws;                   // N
  int*   rowend  = cnt + N;                      // N
  int*   hist    = rowend + N;                   // NBUK*NCHUNK counts
  float* dinv    = (float*)(hist + NBUK * NCHUNK); // N
  int*   ssrc    = (int*)(dinv + N);             // NBUK*BCAP (padded)
  unsigned int* ebuf = (unsigned int*)(ssrc + NBUK * BCAP); // NBUK*NCHUNK*CCAP
  unsigned short* xs16 = (unsigned short*)(ebuf + (size_t)NBUK * NCHUNK * CCAP); // N*64 bf16
  unsigned short* AX16 = xs16 + (size_t)N * F0;  // N*64 bf16
  unsigned short* H2s16 = AX16 + (size_t)N * F0; // N*32 bf16

  k_bucket<<<NCHUNK, 512, 0, stream>>>(src, dst, hist, ebuf);
  k_csr   <<<NBUK,   512, 0, stream>>>(ebuf, hist, x, cnt, rowend, dinv, ssrc, xs16);

  k_agg1  <<<(N + 3) / 4, 256, 0, stream>>>(rowend, cnt, ssrc, xs16, dinv, AX16);
  k_gemm12<<<(N + 63) / 64, 256, 0, stream>>>(AX16, W1, b1, W2, dinv, H2s16);
  k_agg2h <<<(N + 3) / 4, 256, 0, stream>>>(rowend, cnt, ssrc, H2s16, dinv, b2, Wc, bc, h2, out);
}